// Round 1
// baseline (772.625 us; speedup 1.0000x reference)
//
#include <hip/hip_runtime.h>
#include <hip/hip_bf16.h>
#include <math.h>

#define B_   2
#define ND_  2048
#define NE_  2048
#define D_   1024
#define H_   16
#define HD_  64
#define DFF_ 4096
#define T_   4096   // B_*ND_ tokens

typedef __attribute__((ext_vector_type(8))) short bf16x8;
typedef __attribute__((ext_vector_type(4))) float f32x4;

__device__ __forceinline__ short f2bf(float f) {
  union { float f; unsigned u; } v; v.f = f;
  return (short)((v.u + 0x7FFFu + ((v.u >> 16) & 1u)) >> 16);
}

typedef const __attribute__((address_space(1))) void gvoid_t;
typedef __attribute__((address_space(3))) void lvoid_t;

__device__ __forceinline__ void gload16(const void* src, void* dst) {
  __builtin_amdgcn_global_load_lds((gvoid_t*)src, (lvoid_t*)dst, 16, 0, 0);
}

// ---------------- weight transpose + cast: fp32 (K x N) -> bf16 (N x K) ------
__global__ __launch_bounds__(256) void wt_cast(const float* __restrict__ in,
                                               short* __restrict__ out,
                                               int K, int N) {
  __shared__ float t[32][33];
  const int tx = threadIdx.x, ty = threadIdx.y;
  const int n0 = blockIdx.x * 32, k0 = blockIdx.y * 32;
#pragma unroll
  for (int i = 0; i < 4; ++i)
    t[ty + i * 8][tx] = in[(size_t)(k0 + ty + i * 8) * N + n0 + tx];
  __syncthreads();
#pragma unroll
  for (int i = 0; i < 4; ++i)
    out[(size_t)(n0 + ty + i * 8) * K + k0 + tx] = f2bf(t[tx][ty + i * 8]);
}

// ---------------- elementwise cast fp32 -> bf16 ------------------------------
__global__ __launch_bounds__(256) void castf2b(const float* __restrict__ in,
                                               short* __restrict__ out) {
  const int i = blockIdx.x * 256 + threadIdx.x;
  float4 v = ((const float4*)in)[i];
  short4 o;
  o.x = f2bf(v.x); o.y = f2bf(v.y); o.z = f2bf(v.z); o.w = f2bf(v.w);
  ((short4*)out)[i] = o;
}

// ---------------- LayerNorm (row of 1024) fp32 -> bf16 -----------------------
__global__ __launch_bounds__(256) void ln_kernel(const float* __restrict__ x,
                                                 const float* __restrict__ g,
                                                 const float* __restrict__ b,
                                                 short* __restrict__ out) {
  const int row = blockIdx.x;
  const int tid = threadIdx.x;
  const float* xr = x + (size_t)row * D_;
  float4 v = reinterpret_cast<const float4*>(xr)[tid];
  float s  = v.x + v.y + v.z + v.w;
  float s2 = v.x * v.x + v.y * v.y + v.z * v.z + v.w * v.w;
#pragma unroll
  for (int m = 1; m < 64; m <<= 1) {
    s  += __shfl_xor(s, m);
    s2 += __shfl_xor(s2, m);
  }
  __shared__ float ss[4], ss2[4];
  const int w = tid >> 6;
  if ((tid & 63) == 0) { ss[w] = s; ss2[w] = s2; }
  __syncthreads();
  s  = ss[0] + ss[1] + ss[2] + ss[3];
  s2 = ss2[0] + ss2[1] + ss2[2] + ss2[3];
  const float mu   = s * (1.0f / D_);
  const float var  = s2 * (1.0f / D_) - mu * mu;
  const float rstd = rsqrtf(var + 1e-5f);
  float4 gv = reinterpret_cast<const float4*>(g)[tid];
  float4 bv = reinterpret_cast<const float4*>(b)[tid];
  short4 o;
  o.x = f2bf((v.x - mu) * rstd * gv.x + bv.x);
  o.y = f2bf((v.y - mu) * rstd * gv.y + bv.y);
  o.z = f2bf((v.z - mu) * rstd * gv.z + bv.z);
  o.w = f2bf((v.w - mu) * rstd * gv.w + bv.w);
  reinterpret_cast<short4*>(out + (size_t)row * D_)[tid] = o;
}

// ---------------- GEMM: C(MxN) = A(MxK,bf16) * Bt(NxK,bf16)^T ----------------
// MODE 0: store bf16.  MODE 1: fp32 out = resid + acc + bias.
// MODE 2: bf16 out = gelu(acc + bias).
template <int MODE>
__global__ __launch_bounds__(256) void gemm_bt(const short* __restrict__ A,
                                               const short* __restrict__ Bt,
                                               const float* __restrict__ bias,
                                               const float* __restrict__ resid,
                                               void* __restrict__ Cout,
                                               int M, int N, int K) {
  __shared__ short As[128 * 32];
  __shared__ short Bs[128 * 32];
  const int tid = threadIdx.x;
  const int m0 = blockIdx.y * 128, n0 = blockIdx.x * 128;
  const int wave = tid >> 6, lane = tid & 63;
  const int wm = (wave >> 1) * 64, wn = (wave & 1) * 64;
  const int lr = lane & 15, lg = lane >> 4;

  f32x4 acc[4][4];
#pragma unroll
  for (int i = 0; i < 4; ++i)
#pragma unroll
    for (int j = 0; j < 4; ++j) acc[i][j] = f32x4{0.f, 0.f, 0.f, 0.f};

  const int e0 = tid * 8, e1 = 2048 + tid * 8;
  const int r0 = e0 >> 5, c0 = e0 & 31;
  const int r1 = e1 >> 5, c1 = e1 & 31;
  const size_t ar0 = (size_t)(m0 + r0) * K, ar1 = (size_t)(m0 + r1) * K;
  const size_t br0 = (size_t)(n0 + r0) * K, br1 = (size_t)(n0 + r1) * K;

  for (int k0 = 0; k0 < K; k0 += 32) {
    gload16(A + ar0 + k0 + c0, As + e0);
    gload16(A + ar1 + k0 + c1, As + e1);
    gload16(Bt + br0 + k0 + c0, Bs + e0);
    gload16(Bt + br1 + k0 + c1, Bs + e1);
    __syncthreads();
    bf16x8 af[4], bfr[4];
#pragma unroll
    for (int mi = 0; mi < 4; ++mi)
      af[mi] = *(const bf16x8*)(As + (wm + mi * 16 + lr) * 32 + lg * 8);
#pragma unroll
    for (int ni = 0; ni < 4; ++ni)
      bfr[ni] = *(const bf16x8*)(Bs + (wn + ni * 16 + lr) * 32 + lg * 8);
#pragma unroll
    for (int mi = 0; mi < 4; ++mi)
#pragma unroll
      for (int ni = 0; ni < 4; ++ni)
        acc[mi][ni] = __builtin_amdgcn_mfma_f32_16x16x32_bf16(
            af[mi], bfr[ni], acc[mi][ni], 0, 0, 0);
    __syncthreads();
  }

#pragma unroll
  for (int mi = 0; mi < 4; ++mi) {
    const int row = m0 + wm + mi * 16 + lg * 4;
#pragma unroll
    for (int ni = 0; ni < 4; ++ni) {
      const int col = n0 + wn + ni * 16 + lr;
#pragma unroll
      for (int r = 0; r < 4; ++r) {
        const size_t idx = (size_t)(row + r) * N + col;
        const float v = acc[mi][ni][r];
        if (MODE == 0) {
          ((short*)Cout)[idx] = f2bf(v);
        } else if (MODE == 1) {
          ((float*)Cout)[idx] = resid[idx] + v + bias[col];
        } else {
          const float t = v + bias[col];
          ((short*)Cout)[idx] = f2bf(0.5f * t * (1.0f + erff(t * 0.70710678f)));
        }
      }
    }
  }
}

// ---------------- per-head V transpose (bf16): (N x HD) -> (HD x N) ----------
__global__ __launch_bounds__(256) void vtrans(const short* __restrict__ in,
                                              short* __restrict__ out,
                                              int ldi, int N) {
  const int bh = blockIdx.z;
  const int b = bh >> 4, h = bh & 15;
  const short* ib = in + (size_t)b * N * ldi + h * HD_;
  short* ob = out + (size_t)bh * HD_ * N;
  __shared__ short t[32][33];
  const int tx = threadIdx.x, ty = threadIdx.y;
  const int n0 = blockIdx.x * 32, d0 = blockIdx.y * 32;
#pragma unroll
  for (int i = 0; i < 4; ++i)
    t[ty + i * 8][tx] = ib[(size_t)(n0 + ty + i * 8) * ldi + d0 + tx];
  __syncthreads();
#pragma unroll
  for (int i = 0; i < 4; ++i)
    ob[(size_t)(d0 + ty + i * 8) * N + n0 + tx] = t[tx][ty + i * 8];
}

// ---------------- flash attention: 64 q-rows/block, KBLK=64 ------------------
// Q (row-stride ldq), K (row-stride ldk), Vt ((B*H) x HD x NK), O (row-stride ldo)
__global__ __launch_bounds__(256) void flash(const short* __restrict__ Q,
                                             const short* __restrict__ Kp,
                                             const short* __restrict__ Vt,
                                             short* __restrict__ O,
                                             int ldq, int ldk, int ldo,
                                             int NK, int causal) {
  const int bh = blockIdx.y;
  const int b = bh >> 4, h = bh & 15;
  const int q0 = blockIdx.x * 64;
  const int tid = threadIdx.x, wave = tid >> 6, lane = tid & 63;
  const int lr = lane & 15, lg = lane >> 4;

  const short* Qb = Q + (size_t)b * ND_ * ldq + h * HD_;
  const short* Kb = Kp + (size_t)b * NK * ldk + h * HD_;
  const short* Vb = Vt + (size_t)bh * HD_ * NK;
  short* Ob = O + (size_t)b * ND_ * ldo + h * HD_;

  __shared__ short Ks[64 * 64];
  __shared__ short Vs[64 * 64];
  __shared__ short Ps[4][16 * 64];

  const int qrow = q0 + wave * 16 + lr;
  const bf16x8 qf0 = *(const bf16x8*)(Qb + (size_t)qrow * ldq + lg * 8);
  const bf16x8 qf1 = *(const bf16x8*)(Qb + (size_t)qrow * ldq + 32 + lg * 8);

  f32x4 oacc[4];
  float m[4], lsum[4];
#pragma unroll
  for (int i = 0; i < 4; ++i) {
    oacc[i] = f32x4{0.f, 0.f, 0.f, 0.f};
    m[i] = -1e30f;
    lsum[i] = 0.f;
  }

  const int e0 = tid * 8, e1 = 2048 + tid * 8;
  const int kr0 = e0 >> 6, kc0 = e0 & 63;
  const int kr1 = e1 >> 6, kc1 = e1 & 63;

  const int nkt = causal ? (q0 / 64 + 1) : (NK / 64);
  for (int t = 0; t < nkt; ++t) {
    const int k0 = t * 64;
    gload16(Kb + (size_t)(k0 + kr0) * ldk + kc0, Ks + e0);
    gload16(Kb + (size_t)(k0 + kr1) * ldk + kc1, Ks + e1);
    gload16(Vb + (size_t)kr0 * NK + k0 + kc0, Vs + e0);
    gload16(Vb + (size_t)kr1 * NK + k0 + kc1, Vs + e1);
    __syncthreads();

    f32x4 s[4];
#pragma unroll
    for (int kb = 0; kb < 4; ++kb) {
      const bf16x8 kf0 = *(const bf16x8*)(Ks + (kb * 16 + lr) * 64 + lg * 8);
      const bf16x8 kf1 = *(const bf16x8*)(Ks + (kb * 16 + lr) * 64 + 32 + lg * 8);
      s[kb] = f32x4{0.f, 0.f, 0.f, 0.f};
      s[kb] = __builtin_amdgcn_mfma_f32_16x16x32_bf16(qf0, kf0, s[kb], 0, 0, 0);
      s[kb] = __builtin_amdgcn_mfma_f32_16x16x32_bf16(qf1, kf1, s[kb], 0, 0, 0);
    }
#pragma unroll
    for (int kb = 0; kb < 4; ++kb)
#pragma unroll
      for (int r = 0; r < 4; ++r) {
        float v = s[kb][r] * 0.125f;
        if (causal && (k0 + kb * 16 + lr) > (q0 + wave * 16 + lg * 4 + r))
          v = -3.0e38f;
        s[kb][r] = v;
      }
    float rm[4];
#pragma unroll
    for (int r = 0; r < 4; ++r)
      rm[r] = fmaxf(fmaxf(s[0][r], s[1][r]), fmaxf(s[2][r], s[3][r]));
#pragma unroll
    for (int msk = 1; msk < 16; msk <<= 1)
#pragma unroll
      for (int r = 0; r < 4; ++r)
        rm[r] = fmaxf(rm[r], __shfl_xor(rm[r], msk));
    float fac[4];
#pragma unroll
    for (int r = 0; r < 4; ++r) {
      const float mn = fmaxf(m[r], rm[r]);
      fac[r] = expf(m[r] - mn);
      m[r] = mn;
    }
#pragma unroll
    for (int kb = 0; kb < 4; ++kb)
#pragma unroll
      for (int r = 0; r < 4; ++r) s[kb][r] = expf(s[kb][r] - m[r]);
    float rs[4];
#pragma unroll
    for (int r = 0; r < 4; ++r)
      rs[r] = s[0][r] + s[1][r] + s[2][r] + s[3][r];
#pragma unroll
    for (int msk = 1; msk < 16; msk <<= 1)
#pragma unroll
      for (int r = 0; r < 4; ++r) rs[r] += __shfl_xor(rs[r], msk);
#pragma unroll
    for (int r = 0; r < 4; ++r) lsum[r] = lsum[r] * fac[r] + rs[r];
#pragma unroll
    for (int db = 0; db < 4; ++db)
#pragma unroll
      for (int r = 0; r < 4; ++r) oacc[db][r] *= fac[r];

    short* Pw = &Ps[wave][0];
#pragma unroll
    for (int kb = 0; kb < 4; ++kb)
#pragma unroll
      for (int r = 0; r < 4; ++r)
        Pw[(lg * 4 + r) * 64 + kb * 16 + lr] = f2bf(s[kb][r]);
    const bf16x8 pf0 = *(const bf16x8*)(Pw + lr * 64 + lg * 8);
    const bf16x8 pf1 = *(const bf16x8*)(Pw + lr * 64 + 32 + lg * 8);
#pragma unroll
    for (int db = 0; db < 4; ++db) {
      const bf16x8 vf0 = *(const bf16x8*)(Vs + (db * 16 + lr) * 64 + lg * 8);
      const bf16x8 vf1 = *(const bf16x8*)(Vs + (db * 16 + lr) * 64 + 32 + lg * 8);
      oacc[db] = __builtin_amdgcn_mfma_f32_16x16x32_bf16(pf0, vf0, oacc[db], 0, 0, 0);
      oacc[db] = __builtin_amdgcn_mfma_f32_16x16x32_bf16(pf1, vf1, oacc[db], 0, 0, 0);
    }
    __syncthreads();
  }
#pragma unroll
  for (int db = 0; db < 4; ++db)
#pragma unroll
    for (int r = 0; r < 4; ++r) {
      const int q = q0 + wave * 16 + lg * 4 + r;
      Ob[(size_t)q * ldo + db * 16 + lr] = f2bf(oacc[db][r] / lsum[r]);
    }
}

// ---------------------------------------------------------------------------
extern "C" void kernel_launch(void* const* d_in, const int* in_sizes, int n_in,
                              void* d_out, int out_size, void* d_ws, size_t ws_size,
                              hipStream_t stream) {
  const float* x      = (const float*)d_in[0];
  const float* memory = (const float*)d_in[1];
  const float* ln1_g  = (const float*)d_in[2];
  const float* ln1_b  = (const float*)d_in[3];
  const float* Wqkv   = (const float*)d_in[4];
  const float* Wo_sa  = (const float*)d_in[5];
  const float* bo_sa  = (const float*)d_in[6];
  const float* ln2_g  = (const float*)d_in[7];
  const float* ln2_b  = (const float*)d_in[8];
  const float* Wq     = (const float*)d_in[9];
  const float* Wk     = (const float*)d_in[10];
  const float* Wv     = (const float*)d_in[11];
  const float* Wo_ca  = (const float*)d_in[12];
  const float* bo_ca  = (const float*)d_in[13];
  const float* ln3_g  = (const float*)d_in[14];
  const float* ln3_b  = (const float*)d_in[15];
  const float* W1     = (const float*)d_in[16];
  const float* b1     = (const float*)d_in[17];
  const float* W2     = (const float*)d_in[18];
  const float* b2     = (const float*)d_in[19];

  char* ws = (char*)d_ws;
  size_t o = 0;
  auto alloc = [&](size_t bytes) { char* p = ws + o; o += bytes; return p; };
  short* wqkv_t = (short*)alloc((size_t)3072 * 1024 * 2);
  short* wosa_t = (short*)alloc((size_t)1024 * 1024 * 2);
  short* wq_t   = (short*)alloc((size_t)1024 * 1024 * 2);
  short* wk_t   = (short*)alloc((size_t)1024 * 1024 * 2);
  short* wv_t   = (short*)alloc((size_t)1024 * 1024 * 2);
  short* woca_t = (short*)alloc((size_t)1024 * 1024 * 2);
  short* w1_t   = (short*)alloc((size_t)4096 * 1024 * 2);
  short* w2_t   = (short*)alloc((size_t)1024 * 4096 * 2);
  short* hbf    = (short*)alloc((size_t)T_ * 1024 * 2);
  short* bufa   = (short*)alloc((size_t)T_ * 3072 * 2);  // qkv, later q/k/v_ca, later ffn
  short* vt     = (short*)alloc((size_t)32 * 64 * 2048 * 2);
  short* attn   = (short*)alloc((size_t)T_ * 1024 * 2);
  short* membf  = (short*)alloc((size_t)T_ * 1024 * 2);
  float* x1     = (float*)alloc((size_t)T_ * 1024 * 4);
  float* x2     = (float*)alloc((size_t)T_ * 1024 * 4);
  if (o > ws_size) return;  // workspace too small — bail rather than corrupt

  short* ffn = bufa;  // spans bufa(24MB)+vt(8MB) = 32MB, both dead by then
  short* qca = bufa;
  short* kca = bufa + (size_t)T_ * 1024;
  short* vca = bufa + (size_t)2 * T_ * 1024;

  const dim3 tb(32, 8);

  // weight transposes (fp32 -> bf16, K x N -> N x K)
  wt_cast<<<dim3(3072 / 32, 1024 / 32), tb, 0, stream>>>(Wqkv, wqkv_t, 1024, 3072);
  wt_cast<<<dim3(1024 / 32, 1024 / 32), tb, 0, stream>>>(Wo_sa, wosa_t, 1024, 1024);
  wt_cast<<<dim3(1024 / 32, 1024 / 32), tb, 0, stream>>>(Wq, wq_t, 1024, 1024);
  wt_cast<<<dim3(1024 / 32, 1024 / 32), tb, 0, stream>>>(Wk, wk_t, 1024, 1024);
  wt_cast<<<dim3(1024 / 32, 1024 / 32), tb, 0, stream>>>(Wv, wv_t, 1024, 1024);
  wt_cast<<<dim3(1024 / 32, 1024 / 32), tb, 0, stream>>>(Wo_ca, woca_t, 1024, 1024);
  wt_cast<<<dim3(4096 / 32, 1024 / 32), tb, 0, stream>>>(W1, w1_t, 1024, 4096);
  wt_cast<<<dim3(1024 / 32, 4096 / 32), tb, 0, stream>>>(W2, w2_t, 4096, 1024);
  castf2b<<<dim3((T_ * 1024) / (256 * 4)), 256, 0, stream>>>(memory, membf);

  // --- self-attention block ---
  ln_kernel<<<dim3(T_), 256, 0, stream>>>(x, ln1_g, ln1_b, hbf);
  gemm_bt<0><<<dim3(3072 / 128, T_ / 128), 256, 0, stream>>>(
      hbf, wqkv_t, nullptr, nullptr, bufa, T_, 3072, 1024);
  vtrans<<<dim3(ND_ / 32, HD_ / 32, 32), tb, 0, stream>>>(bufa + 2048, vt, 3072, ND_);
  flash<<<dim3(ND_ / 64, 32), 256, 0, stream>>>(
      bufa, bufa + 1024, vt, attn, 3072, 3072, 1024, ND_, 1);
  gemm_bt<1><<<dim3(1024 / 128, T_ / 128), 256, 0, stream>>>(
      attn, wosa_t, bo_sa, x, x1, T_, 1024, 1024);

  // --- cross-attention block ---
  ln_kernel<<<dim3(T_), 256, 0, stream>>>(x1, ln2_g, ln2_b, hbf);
  gemm_bt<0><<<dim3(1024 / 128, T_ / 128), 256, 0, stream>>>(
      hbf, wq_t, nullptr, nullptr, qca, T_, 1024, 1024);
  gemm_bt<0><<<dim3(1024 / 128, T_ / 128), 256, 0, stream>>>(
      membf, wk_t, nullptr, nullptr, kca, T_, 1024, 1024);
  gemm_bt<0><<<dim3(1024 / 128, T_ / 128), 256, 0, stream>>>(
      membf, wv_t, nullptr, nullptr, vca, T_, 1024, 1024);
  vtrans<<<dim3(NE_ / 32, HD_ / 32, 32), tb, 0, stream>>>(vca, vt, 1024, NE_);
  flash<<<dim3(ND_ / 64, 32), 256, 0, stream>>>(
      qca, kca, vt, attn, 1024, 1024, 1024, NE_, 0);
  gemm_bt<1><<<dim3(1024 / 128, T_ / 128), 256, 0, stream>>>(
      attn, woca_t, bo_ca, x1, x2, T_, 1024, 1024);

  // --- FFN block ---
  ln_kernel<<<dim3(T_), 256, 0, stream>>>(x2, ln3_g, ln3_b, hbf);
  gemm_bt<2><<<dim3(4096 / 128, T_ / 128), 256, 0, stream>>>(
      hbf, w1_t, b1, nullptr, ffn, T_, 4096, 1024);
  gemm_bt<1><<<dim3(1024 / 128, T_ / 128), 256, 0, stream>>>(
      ffn, w2_t, b2, x2, d_out, T_, 1024, 4096);
}

// Round 2
// 587.001 us; speedup vs baseline: 1.3162x; 1.3162x over previous
//
#include <hip/hip_runtime.h>
#include <hip/hip_bf16.h>
#include <math.h>

#define B_   2
#define ND_  2048
#define NE_  2048
#define D_   1024
#define H_   16
#define HD_  64
#define DFF_ 4096
#define T_   4096   // B_*ND_ tokens

typedef __attribute__((ext_vector_type(8))) short bf16x8;
typedef __attribute__((ext_vector_type(4))) float f32x4;

#if __has_builtin(__builtin_amdgcn_exp2f)
#define EXP2(x) __builtin_amdgcn_exp2f(x)
#else
#define EXP2(x) exp2f(x)
#endif

__device__ __forceinline__ short f2bf(float f) {
  union { float f; unsigned u; } v; v.f = f;
  return (short)((v.u + 0x7FFFu + ((v.u >> 16) & 1u)) >> 16);
}

typedef const __attribute__((address_space(1))) void gvoid_t;
typedef __attribute__((address_space(3))) void lvoid_t;

__device__ __forceinline__ void gload16(const void* src, void* dst) {
  __builtin_amdgcn_global_load_lds((gvoid_t*)src, (lvoid_t*)dst, 16, 0, 0);
}

// ---------------- weight transpose + cast: fp32 (K x N) -> bf16 (N x K) ------
__global__ __launch_bounds__(256) void wt_cast(const float* __restrict__ in,
                                               short* __restrict__ out,
                                               int K, int N) {
  __shared__ float t[32][33];
  const int tx = threadIdx.x, ty = threadIdx.y;
  const int n0 = blockIdx.x * 32, k0 = blockIdx.y * 32;
#pragma unroll
  for (int i = 0; i < 4; ++i)
    t[ty + i * 8][tx] = in[(size_t)(k0 + ty + i * 8) * N + n0 + tx];
  __syncthreads();
#pragma unroll
  for (int i = 0; i < 4; ++i)
    out[(size_t)(n0 + ty + i * 8) * K + k0 + tx] = f2bf(t[tx][ty + i * 8]);
}

// ---------------- elementwise cast fp32 -> bf16 ------------------------------
__global__ __launch_bounds__(256) void castf2b(const float* __restrict__ in,
                                               short* __restrict__ out) {
  const int i = blockIdx.x * 256 + threadIdx.x;
  float4 v = ((const float4*)in)[i];
  short4 o;
  o.x = f2bf(v.x); o.y = f2bf(v.y); o.z = f2bf(v.z); o.w = f2bf(v.w);
  ((short4*)out)[i] = o;
}

// ---------------- LayerNorm (row of 1024) fp32 -> bf16 -----------------------
__global__ __launch_bounds__(256) void ln_kernel(const float* __restrict__ x,
                                                 const float* __restrict__ g,
                                                 const float* __restrict__ b,
                                                 short* __restrict__ out) {
  const int row = blockIdx.x;
  const int tid = threadIdx.x;
  const float* xr = x + (size_t)row * D_;
  float4 v = reinterpret_cast<const float4*>(xr)[tid];
  float s  = v.x + v.y + v.z + v.w;
  float s2 = v.x * v.x + v.y * v.y + v.z * v.z + v.w * v.w;
#pragma unroll
  for (int m = 1; m < 64; m <<= 1) {
    s  += __shfl_xor(s, m);
    s2 += __shfl_xor(s2, m);
  }
  __shared__ float ss[4], ss2[4];
  const int w = tid >> 6;
  if ((tid & 63) == 0) { ss[w] = s; ss2[w] = s2; }
  __syncthreads();
  s  = ss[0] + ss[1] + ss[2] + ss[3];
  s2 = ss2[0] + ss2[1] + ss2[2] + ss2[3];
  const float mu   = s * (1.0f / D_);
  const float var  = s2 * (1.0f / D_) - mu * mu;
  const float rstd = rsqrtf(var + 1e-5f);
  float4 gv = reinterpret_cast<const float4*>(g)[tid];
  float4 bv = reinterpret_cast<const float4*>(b)[tid];
  short4 o;
  o.x = f2bf((v.x - mu) * rstd * gv.x + bv.x);
  o.y = f2bf((v.y - mu) * rstd * gv.y + bv.y);
  o.z = f2bf((v.z - mu) * rstd * gv.z + bv.z);
  o.w = f2bf((v.w - mu) * rstd * gv.w + bv.w);
  reinterpret_cast<short4*>(out + (size_t)row * D_)[tid] = o;
}

// ---------------- GEMM 128x128: C(MxN) = A(MxK,bf16) * Bt(NxK,bf16)^T --------
// MODE 0: store bf16.  MODE 1: fp32 out = resid + acc + bias.
// MODE 2: bf16 out = gelu(acc + bias).
template <int MODE>
__global__ __launch_bounds__(256) void gemm_bt(const short* __restrict__ A,
                                               const short* __restrict__ Bt,
                                               const float* __restrict__ bias,
                                               const float* __restrict__ resid,
                                               void* __restrict__ Cout,
                                               int M, int N, int K) {
  __shared__ short As[128 * 32];
  __shared__ short Bs[128 * 32];
  const int tid = threadIdx.x;
  const int m0 = blockIdx.y * 128, n0 = blockIdx.x * 128;
  const int wave = tid >> 6, lane = tid & 63;
  const int wm = (wave >> 1) * 64, wn = (wave & 1) * 64;
  const int lr = lane & 15, lg = lane >> 4;

  f32x4 acc[4][4];
#pragma unroll
  for (int i = 0; i < 4; ++i)
#pragma unroll
    for (int j = 0; j < 4; ++j) acc[i][j] = f32x4{0.f, 0.f, 0.f, 0.f};

  const int e0 = tid * 8, e1 = 2048 + tid * 8;
  const int r0 = e0 >> 5, c0 = e0 & 31;
  const int r1 = e1 >> 5, c1 = e1 & 31;
  const size_t ar0 = (size_t)(m0 + r0) * K, ar1 = (size_t)(m0 + r1) * K;
  const size_t br0 = (size_t)(n0 + r0) * K, br1 = (size_t)(n0 + r1) * K;

  for (int k0 = 0; k0 < K; k0 += 32) {
    gload16(A + ar0 + k0 + c0, As + e0);
    gload16(A + ar1 + k0 + c1, As + e1);
    gload16(Bt + br0 + k0 + c0, Bs + e0);
    gload16(Bt + br1 + k0 + c1, Bs + e1);
    __syncthreads();
    bf16x8 af[4], bfr[4];
#pragma unroll
    for (int mi = 0; mi < 4; ++mi)
      af[mi] = *(const bf16x8*)(As + (wm + mi * 16 + lr) * 32 + lg * 8);
#pragma unroll
    for (int ni = 0; ni < 4; ++ni)
      bfr[ni] = *(const bf16x8*)(Bs + (wn + ni * 16 + lr) * 32 + lg * 8);
#pragma unroll
    for (int mi = 0; mi < 4; ++mi)
#pragma unroll
      for (int ni = 0; ni < 4; ++ni)
        acc[mi][ni] = __builtin_amdgcn_mfma_f32_16x16x32_bf16(
            af[mi], bfr[ni], acc[mi][ni], 0, 0, 0);
    __syncthreads();
  }

#pragma unroll
  for (int mi = 0; mi < 4; ++mi) {
    const int row = m0 + wm + mi * 16 + lg * 4;
#pragma unroll
    for (int ni = 0; ni < 4; ++ni) {
      const int col = n0 + wn + ni * 16 + lr;
#pragma unroll
      for (int r = 0; r < 4; ++r) {
        const size_t idx = (size_t)(row + r) * N + col;
        const float v = acc[mi][ni][r];
        if (MODE == 0) {
          ((short*)Cout)[idx] = f2bf(v);
        } else if (MODE == 1) {
          ((float*)Cout)[idx] = resid[idx] + v + bias[col];
        } else {
          const float t = v + bias[col];
          ((short*)Cout)[idx] = f2bf(0.5f * t * (1.0f + erff(t * 0.70710678f)));
        }
      }
    }
  }
}

// ---------------- batched-3 GEMM 128x128, MODE0 (cross-attn q/k/v) -----------
__global__ __launch_bounds__(256) void gemm_bt3(const short* __restrict__ A0,
                                                const short* __restrict__ A1,
                                                const short* __restrict__ A2,
                                                const short* __restrict__ B0,
                                                const short* __restrict__ B1,
                                                const short* __restrict__ B2,
                                                short* __restrict__ C0,
                                                short* __restrict__ C1,
                                                short* __restrict__ C2,
                                                int M, int N, int K) {
  const int z = blockIdx.z;
  const short* A  = z == 0 ? A0 : (z == 1 ? A1 : A2);
  const short* Bt = z == 0 ? B0 : (z == 1 ? B1 : B2);
  short* C        = z == 0 ? C0 : (z == 1 ? C1 : C2);

  __shared__ short As[128 * 32];
  __shared__ short Bs[128 * 32];
  const int tid = threadIdx.x;
  const int m0 = blockIdx.y * 128, n0 = blockIdx.x * 128;
  const int wave = tid >> 6, lane = tid & 63;
  const int wm = (wave >> 1) * 64, wn = (wave & 1) * 64;
  const int lr = lane & 15, lg = lane >> 4;

  f32x4 acc[4][4];
#pragma unroll
  for (int i = 0; i < 4; ++i)
#pragma unroll
    for (int j = 0; j < 4; ++j) acc[i][j] = f32x4{0.f, 0.f, 0.f, 0.f};

  const int e0 = tid * 8, e1 = 2048 + tid * 8;
  const int r0 = e0 >> 5, c0 = e0 & 31;
  const int r1 = e1 >> 5, c1 = e1 & 31;
  const size_t ar0 = (size_t)(m0 + r0) * K, ar1 = (size_t)(m0 + r1) * K;
  const size_t br0 = (size_t)(n0 + r0) * K, br1 = (size_t)(n0 + r1) * K;

  for (int k0 = 0; k0 < K; k0 += 32) {
    gload16(A + ar0 + k0 + c0, As + e0);
    gload16(A + ar1 + k0 + c1, As + e1);
    gload16(Bt + br0 + k0 + c0, Bs + e0);
    gload16(Bt + br1 + k0 + c1, Bs + e1);
    __syncthreads();
    bf16x8 af[4], bfr[4];
#pragma unroll
    for (int mi = 0; mi < 4; ++mi)
      af[mi] = *(const bf16x8*)(As + (wm + mi * 16 + lr) * 32 + lg * 8);
#pragma unroll
    for (int ni = 0; ni < 4; ++ni)
      bfr[ni] = *(const bf16x8*)(Bs + (wn + ni * 16 + lr) * 32 + lg * 8);
#pragma unroll
    for (int mi = 0; mi < 4; ++mi)
#pragma unroll
      for (int ni = 0; ni < 4; ++ni)
        acc[mi][ni] = __builtin_amdgcn_mfma_f32_16x16x32_bf16(
            af[mi], bfr[ni], acc[mi][ni], 0, 0, 0);
    __syncthreads();
  }

#pragma unroll
  for (int mi = 0; mi < 4; ++mi) {
    const int row = m0 + wm + mi * 16 + lg * 4;
#pragma unroll
    for (int ni = 0; ni < 4; ++ni) {
      const int col = n0 + wn + ni * 16 + lr;
#pragma unroll
      for (int r = 0; r < 4; ++r)
        C[(size_t)(row + r) * N + col] = f2bf(acc[mi][ni][r]);
    }
  }
}

// ---------------- GEMM 64x128 tile (for N=1024 shapes: 512 blocks, 2/CU) -----
// MODE 1 only: fp32 out = resid + acc + bias.
__global__ __launch_bounds__(256) void gemm_bt64(const short* __restrict__ A,
                                                 const short* __restrict__ Bt,
                                                 const float* __restrict__ bias,
                                                 const float* __restrict__ resid,
                                                 float* __restrict__ Cout,
                                                 int M, int N, int K) {
  __shared__ short As[64 * 32];
  __shared__ short Bs[128 * 32];
  const int tid = threadIdx.x;
  const int m0 = blockIdx.y * 64, n0 = blockIdx.x * 128;
  const int wave = tid >> 6, lane = tid & 63;
  const int wn = wave * 32;
  const int lr = lane & 15, lg = lane >> 4;

  f32x4 acc[4][2];
#pragma unroll
  for (int i = 0; i < 4; ++i)
#pragma unroll
    for (int j = 0; j < 2; ++j) acc[i][j] = f32x4{0.f, 0.f, 0.f, 0.f};

  const int ea = tid * 8;                    // A: 64x32 = one pass
  const int ra = ea >> 5, ca = ea & 31;
  const int e0 = tid * 8, e1 = 2048 + tid * 8;   // B: two passes
  const int r0 = e0 >> 5, c0 = e0 & 31;
  const int r1 = e1 >> 5, c1 = e1 & 31;
  const size_t ar = (size_t)(m0 + ra) * K;
  const size_t br0 = (size_t)(n0 + r0) * K, br1 = (size_t)(n0 + r1) * K;

  for (int k0 = 0; k0 < K; k0 += 32) {
    gload16(A + ar + k0 + ca, As + ea);
    gload16(Bt + br0 + k0 + c0, Bs + e0);
    gload16(Bt + br1 + k0 + c1, Bs + e1);
    __syncthreads();
    bf16x8 af[4], bfr[2];
#pragma unroll
    for (int mi = 0; mi < 4; ++mi)
      af[mi] = *(const bf16x8*)(As + (mi * 16 + lr) * 32 + lg * 8);
#pragma unroll
    for (int ni = 0; ni < 2; ++ni)
      bfr[ni] = *(const bf16x8*)(Bs + (wn + ni * 16 + lr) * 32 + lg * 8);
#pragma unroll
    for (int mi = 0; mi < 4; ++mi)
#pragma unroll
      for (int ni = 0; ni < 2; ++ni)
        acc[mi][ni] = __builtin_amdgcn_mfma_f32_16x16x32_bf16(
            af[mi], bfr[ni], acc[mi][ni], 0, 0, 0);
    __syncthreads();
  }

#pragma unroll
  for (int mi = 0; mi < 4; ++mi) {
    const int row = m0 + mi * 16 + lg * 4;
#pragma unroll
    for (int ni = 0; ni < 2; ++ni) {
      const int col = n0 + wn + ni * 16 + lr;
#pragma unroll
      for (int r = 0; r < 4; ++r) {
        const size_t idx = (size_t)(row + r) * N + col;
        Cout[idx] = resid[idx] + acc[mi][ni][r] + bias[col];
      }
    }
  }
}

// ---------------- per-head V transpose (bf16): (N x HD) -> (HD x N) ----------
__global__ __launch_bounds__(256) void vtrans(const short* __restrict__ in,
                                              short* __restrict__ out,
                                              int ldi, int N) {
  const int bh = blockIdx.z;
  const int b = bh >> 4, h = bh & 15;
  const short* ib = in + (size_t)b * N * ldi + h * HD_;
  short* ob = out + (size_t)bh * HD_ * N;
  __shared__ short t[32][33];
  const int tx = threadIdx.x, ty = threadIdx.y;
  const int n0 = blockIdx.x * 32, d0 = blockIdx.y * 32;
#pragma unroll
  for (int i = 0; i < 4; ++i)
    t[ty + i * 8][tx] = ib[(size_t)(n0 + ty + i * 8) * ldi + d0 + tx];
  __syncthreads();
#pragma unroll
  for (int i = 0; i < 4; ++i)
    ob[(size_t)(d0 + ty + i * 8) * N + n0 + tx] = t[tx][ty + i * 8];
}

// ---------------- flash attention: 64 q-rows/block, KBLK=64 ------------------
// XOR-swizzled LDS tiles (rule #21: linear gload_lds dest + pre-swizzled
// global source col + same-involution swizzled ds_read).
// Softmax in exp2 domain (scale folded with log2e).
__global__ __launch_bounds__(256) void flash(const short* __restrict__ Q,
                                             const short* __restrict__ Kp,
                                             const short* __restrict__ Vt,
                                             short* __restrict__ O,
                                             int ldq, int ldk, int ldo,
                                             int NK, int causal) {
  const int bh = blockIdx.y;
  const int b = bh >> 4, h = bh & 15;
  const int q0 = blockIdx.x * 64;
  const int tid = threadIdx.x, wave = tid >> 6, lane = tid & 63;
  const int lr = lane & 15, lg = lane >> 4;
  const int lx = lr & 7;  // swizzle key for fragment reads (row & 7 == lr & 7)

  const short* Qb = Q + (size_t)b * ND_ * ldq + h * HD_;
  const short* Kb = Kp + (size_t)b * NK * ldk + h * HD_;
  const short* Vb = Vt + (size_t)bh * HD_ * NK;
  short* Ob = O + (size_t)b * ND_ * ldo + h * HD_;

  __shared__ short Ks[64 * 64];
  __shared__ short Vs[64 * 64];
  __shared__ short Ps[4][16 * 64];

  const int qrow = q0 + wave * 16 + lr;
  const bf16x8 qf0 = *(const bf16x8*)(Qb + (size_t)qrow * ldq + lg * 8);
  const bf16x8 qf1 = *(const bf16x8*)(Qb + (size_t)qrow * ldq + 32 + lg * 8);

  f32x4 oacc[4];
  float m[4], lsum[4];
#pragma unroll
  for (int i = 0; i < 4; ++i) {
    oacc[i] = f32x4{0.f, 0.f, 0.f, 0.f};
    m[i] = -1e30f;
    lsum[i] = 0.f;
  }

  // staging geometry: LDS dest linear (tid*16B); source col slot XOR'd by row
  const int sr0 = tid >> 3;             // rows 0..31 (pass 0), +32 (pass 1)
  const int ssw = ((tid & 7) ^ (sr0 & 7)) * 8;  // (32+sr0)&7 == sr0&7
  const int e0 = tid * 8, e1 = 2048 + tid * 8;

  const float SC = 0.18033688011112042f;  // 1/sqrt(64) * log2(e)

  const int nkt = causal ? (q0 / 64 + 1) : (NK / 64);
  for (int t = 0; t < nkt; ++t) {
    const int k0 = t * 64;
    gload16(Kb + (size_t)(k0 + sr0) * ldk + ssw, Ks + e0);
    gload16(Kb + (size_t)(k0 + 32 + sr0) * ldk + ssw, Ks + e1);
    gload16(Vb + (size_t)sr0 * NK + k0 + ssw, Vs + e0);
    gload16(Vb + (size_t)(32 + sr0) * NK + k0 + ssw, Vs + e1);
    __syncthreads();

    f32x4 s[4];
#pragma unroll
    for (int kb = 0; kb < 4; ++kb) {
      const bf16x8 kf0 = *(const bf16x8*)(Ks + (kb * 16 + lr) * 64 + ((lg ^ lx) * 8));
      const bf16x8 kf1 = *(const bf16x8*)(Ks + (kb * 16 + lr) * 64 + (((4 + lg) ^ lx) * 8));
      s[kb] = f32x4{0.f, 0.f, 0.f, 0.f};
      s[kb] = __builtin_amdgcn_mfma_f32_16x16x32_bf16(qf0, kf0, s[kb], 0, 0, 0);
      s[kb] = __builtin_amdgcn_mfma_f32_16x16x32_bf16(qf1, kf1, s[kb], 0, 0, 0);
    }
#pragma unroll
    for (int kb = 0; kb < 4; ++kb)
#pragma unroll
      for (int r = 0; r < 4; ++r) {
        float v = s[kb][r] * SC;
        if (causal && (k0 + kb * 16 + lr) > (q0 + wave * 16 + lg * 4 + r))
          v = -3.0e38f;
        s[kb][r] = v;
      }
    float rm[4];
#pragma unroll
    for (int r = 0; r < 4; ++r)
      rm[r] = fmaxf(fmaxf(s[0][r], s[1][r]), fmaxf(s[2][r], s[3][r]));
#pragma unroll
    for (int msk = 1; msk < 16; msk <<= 1)
#pragma unroll
      for (int r = 0; r < 4; ++r)
        rm[r] = fmaxf(rm[r], __shfl_xor(rm[r], msk));
    float fac[4];
#pragma unroll
    for (int r = 0; r < 4; ++r) {
      const float mn = fmaxf(m[r], rm[r]);
      fac[r] = EXP2(m[r] - mn);
      m[r] = mn;
    }
#pragma unroll
    for (int kb = 0; kb < 4; ++kb)
#pragma unroll
      for (int r = 0; r < 4; ++r) s[kb][r] = EXP2(s[kb][r] - m[r]);
    float rs[4];
#pragma unroll
    for (int r = 0; r < 4; ++r)
      rs[r] = s[0][r] + s[1][r] + s[2][r] + s[3][r];
#pragma unroll
    for (int msk = 1; msk < 16; msk <<= 1)
#pragma unroll
      for (int r = 0; r < 4; ++r) rs[r] += __shfl_xor(rs[r], msk);
#pragma unroll
    for (int r = 0; r < 4; ++r) lsum[r] = lsum[r] * fac[r] + rs[r];
#pragma unroll
    for (int db = 0; db < 4; ++db)
#pragma unroll
      for (int r = 0; r < 4; ++r) oacc[db][r] *= fac[r];

    // P bounce through per-wave LDS, swizzled on both sides
    short* Pw = &Ps[wave][0];
#pragma unroll
    for (int kb = 0; kb < 4; ++kb) {
      const int cs = kb * 2 + (lr >> 3);
#pragma unroll
      for (int r = 0; r < 4; ++r) {
        const int q = lg * 4 + r;
        Pw[q * 64 + ((cs ^ (q & 7)) * 8) + (lr & 7)] = f2bf(s[kb][r]);
      }
    }
    const bf16x8 pf0 = *(const bf16x8*)(Pw + lr * 64 + ((lg ^ lx) * 8));
    const bf16x8 pf1 = *(const bf16x8*)(Pw + lr * 64 + (((4 + lg) ^ lx) * 8));
#pragma unroll
    for (int db = 0; db < 4; ++db) {
      const bf16x8 vf0 = *(const bf16x8*)(Vs + (db * 16 + lr) * 64 + ((lg ^ lx) * 8));
      const bf16x8 vf1 = *(const bf16x8*)(Vs + (db * 16 + lr) * 64 + (((4 + lg) ^ lx) * 8));
      oacc[db] = __builtin_amdgcn_mfma_f32_16x16x32_bf16(pf0, vf0, oacc[db], 0, 0, 0);
      oacc[db] = __builtin_amdgcn_mfma_f32_16x16x32_bf16(pf1, vf1, oacc[db], 0, 0, 0);
    }
    __syncthreads();
  }
#pragma unroll
  for (int db = 0; db < 4; ++db)
#pragma unroll
    for (int r = 0; r < 4; ++r) {
      const int q = q0 + wave * 16 + lg * 4 + r;
      Ob[(size_t)q * ldo + db * 16 + lr] = f2bf(oacc[db][r] / lsum[r]);
    }
}

// ---------------------------------------------------------------------------
extern "C" void kernel_launch(void* const* d_in, const int* in_sizes, int n_in,
                              void* d_out, int out_size, void* d_ws, size_t ws_size,
                              hipStream_t stream) {
  const float* x      = (const float*)d_in[0];
  const float* memory = (const float*)d_in[1];
  const float* ln1_g  = (const float*)d_in[2];
  const float* ln1_b  = (const float*)d_in[3];
  const float* Wqkv   = (const float*)d_in[4];
  const float* Wo_sa  = (const float*)d_in[5];
  const float* bo_sa  = (const float*)d_in[6];
  const float* ln2_g  = (const float*)d_in[7];
  const float* ln2_b  = (const float*)d_in[8];
  const float* Wq     = (const float*)d_in[9];
  const float* Wk     = (const float*)d_in[10];
  const float* Wv     = (const float*)d_in[11];
  const float* Wo_ca  = (const float*)d_in[12];
  const float* bo_ca  = (const float*)d_in[13];
  const float* ln3_g  = (const float*)d_in[14];
  const float* ln3_b  = (const float*)d_in[15];
  const float* W1     = (const float*)d_in[16];
  const float* b1     = (const float*)d_in[17];
  const float* W2     = (const float*)d_in[18];
  const float* b2     = (const float*)d_in[19];

  char* ws = (char*)d_ws;
  size_t o = 0;
  auto alloc = [&](size_t bytes) { char* p = ws + o; o += bytes; return p; };
  short* wqkv_t = (short*)alloc((size_t)3072 * 1024 * 2);
  short* wosa_t = (short*)alloc((size_t)1024 * 1024 * 2);
  short* wq_t   = (short*)alloc((size_t)1024 * 1024 * 2);
  short* wk_t   = (short*)alloc((size_t)1024 * 1024 * 2);
  short* wv_t   = (short*)alloc((size_t)1024 * 1024 * 2);
  short* woca_t = (short*)alloc((size_t)1024 * 1024 * 2);
  short* w1_t   = (short*)alloc((size_t)4096 * 1024 * 2);
  short* w2_t   = (short*)alloc((size_t)1024 * 4096 * 2);
  short* hbf    = (short*)alloc((size_t)T_ * 1024 * 2);
  short* bufa   = (short*)alloc((size_t)T_ * 3072 * 2);  // qkv, later q/k/v_ca, later ffn
  short* vt     = (short*)alloc((size_t)32 * 64 * 2048 * 2);
  short* attn   = (short*)alloc((size_t)T_ * 1024 * 2);
  short* membf  = (short*)alloc((size_t)T_ * 1024 * 2);
  float* x1     = (float*)alloc((size_t)T_ * 1024 * 4);
  float* x2     = (float*)alloc((size_t)T_ * 1024 * 4);
  if (o > ws_size) return;  // workspace too small — bail rather than corrupt

  short* ffn = bufa;  // spans bufa(24MB)+vt(8MB) = 32MB, both dead by then
  short* qca = bufa;
  short* kca = bufa + (size_t)T_ * 1024;
  short* vca = bufa + (size_t)2 * T_ * 1024;

  const dim3 tb(32, 8);

  // weight transposes (fp32 -> bf16, K x N -> N x K)
  wt_cast<<<dim3(3072 / 32, 1024 / 32), tb, 0, stream>>>(Wqkv, wqkv_t, 1024, 3072);
  wt_cast<<<dim3(1024 / 32, 1024 / 32), tb, 0, stream>>>(Wo_sa, wosa_t, 1024, 1024);
  wt_cast<<<dim3(1024 / 32, 1024 / 32), tb, 0, stream>>>(Wq, wq_t, 1024, 1024);
  wt_cast<<<dim3(1024 / 32, 1024 / 32), tb, 0, stream>>>(Wk, wk_t, 1024, 1024);
  wt_cast<<<dim3(1024 / 32, 1024 / 32), tb, 0, stream>>>(Wv, wv_t, 1024, 1024);
  wt_cast<<<dim3(1024 / 32, 1024 / 32), tb, 0, stream>>>(Wo_ca, woca_t, 1024, 1024);
  wt_cast<<<dim3(4096 / 32, 1024 / 32), tb, 0, stream>>>(W1, w1_t, 1024, 4096);
  wt_cast<<<dim3(1024 / 32, 4096 / 32), tb, 0, stream>>>(W2, w2_t, 4096, 1024);
  castf2b<<<dim3((T_ * 1024) / (256 * 4)), 256, 0, stream>>>(memory, membf);

  // --- self-attention block ---
  ln_kernel<<<dim3(T_), 256, 0, stream>>>(x, ln1_g, ln1_b, hbf);
  gemm_bt<0><<<dim3(3072 / 128, T_ / 128), 256, 0, stream>>>(
      hbf, wqkv_t, nullptr, nullptr, bufa, T_, 3072, 1024);
  vtrans<<<dim3(ND_ / 32, HD_ / 32, 32), tb, 0, stream>>>(bufa + 2048, vt, 3072, ND_);
  flash<<<dim3(ND_ / 64, 32), 256, 0, stream>>>(
      bufa, bufa + 1024, vt, attn, 3072, 3072, 1024, ND_, 1);
  gemm_bt64<<<dim3(1024 / 128, T_ / 64), 256, 0, stream>>>(
      attn, wosa_t, bo_sa, x, x1, T_, 1024, 1024);

  // --- cross-attention block ---
  ln_kernel<<<dim3(T_), 256, 0, stream>>>(x1, ln2_g, ln2_b, hbf);
  gemm_bt3<<<dim3(1024 / 128, T_ / 128, 3), 256, 0, stream>>>(
      hbf, membf, membf, wq_t, wk_t, wv_t, qca, kca, vca, T_, 1024, 1024);
  vtrans<<<dim3(NE_ / 32, HD_ / 32, 32), tb, 0, stream>>>(vca, vt, 1024, NE_);
  flash<<<dim3(ND_ / 64, 32), 256, 0, stream>>>(
      qca, kca, vt, attn, 1024, 1024, 1024, NE_, 0);
  gemm_bt64<<<dim3(1024 / 128, T_ / 64), 256, 0, stream>>>(
      attn, woca_t, bo_ca, x1, x2, T_, 1024, 1024);

  // --- FFN block ---
  ln_kernel<<<dim3(T_), 256, 0, stream>>>(x2, ln3_g, ln3_b, hbf);
  gemm_bt<2><<<dim3(4096 / 128, T_ / 128), 256, 0, stream>>>(
      hbf, w1_t, b1, nullptr, ffn, T_, 4096, 1024);
  gemm_bt64<<<dim3(1024 / 128, T_ / 64), 256, 0, stream>>>(
      ffn, w2_t, b2, x2, (float*)d_out, T_, 1024, 4096);
}

// Round 4
// 459.711 us; speedup vs baseline: 1.6807x; 1.2769x over previous
//
#include <hip/hip_runtime.h>
#include <hip/hip_bf16.h>
#include <math.h>

#define B_   2
#define ND_  2048
#define NE_  2048
#define D_   1024
#define H_   16
#define HD_  64
#define DFF_ 4096
#define T_   4096   // B_*ND_ tokens

typedef __attribute__((ext_vector_type(8))) short bf16x8;
typedef __attribute__((ext_vector_type(4))) float f32x4;

#if __has_builtin(__builtin_amdgcn_exp2f)
#define EXP2(x) __builtin_amdgcn_exp2f(x)
#else
#define EXP2(x) exp2f(x)
#endif

__device__ __forceinline__ short f2bf(float f) {
  union { float f; unsigned u; } v; v.f = f;
  return (short)((v.u + 0x7FFFu + ((v.u >> 16) & 1u)) >> 16);
}

typedef const __attribute__((address_space(1))) void gvoid_t;
typedef __attribute__((address_space(3))) void lvoid_t;

__device__ __forceinline__ void gload16(const void* src, void* dst) {
  __builtin_amdgcn_global_load_lds((gvoid_t*)src, (lvoid_t*)dst, 16, 0, 0);
}

// ---------------- weight transpose + cast: fp32 (K x N) -> bf16 (N x K) ------
__global__ __launch_bounds__(256) void wt_cast(const float* __restrict__ in,
                                               short* __restrict__ out,
                                               int K, int N) {
  __shared__ float t[32][33];
  const int tx = threadIdx.x, ty = threadIdx.y;
  const int n0 = blockIdx.x * 32, k0 = blockIdx.y * 32;
#pragma unroll
  for (int i = 0; i < 4; ++i)
    t[ty + i * 8][tx] = in[(size_t)(k0 + ty + i * 8) * N + n0 + tx];
  __syncthreads();
#pragma unroll
  for (int i = 0; i < 4; ++i)
    out[(size_t)(n0 + ty + i * 8) * K + k0 + tx] = f2bf(t[tx][ty + i * 8]);
}

// ---------------- elementwise cast fp32 -> bf16 ------------------------------
__global__ __launch_bounds__(256) void castf2b(const float* __restrict__ in,
                                               short* __restrict__ out) {
  const int i = blockIdx.x * 256 + threadIdx.x;
  float4 v = ((const float4*)in)[i];
  short4 o;
  o.x = f2bf(v.x); o.y = f2bf(v.y); o.z = f2bf(v.z); o.w = f2bf(v.w);
  ((short4*)out)[i] = o;
}

// ---------------- LayerNorm (row of 1024) fp32 -> bf16 -----------------------
__global__ __launch_bounds__(256) void ln_kernel(const float* __restrict__ x,
                                                 const float* __restrict__ g,
                                                 const float* __restrict__ b,
                                                 short* __restrict__ out) {
  const int row = blockIdx.x;
  const int tid = threadIdx.x;
  const float* xr = x + (size_t)row * D_;
  float4 v = reinterpret_cast<const float4*>(xr)[tid];
  float s  = v.x + v.y + v.z + v.w;
  float s2 = v.x * v.x + v.y * v.y + v.z * v.z + v.w * v.w;
#pragma unroll
  for (int m = 1; m < 64; m <<= 1) {
    s  += __shfl_xor(s, m);
    s2 += __shfl_xor(s2, m);
  }
  __shared__ float ss[4], ss2[4];
  const int w = tid >> 6;
  if ((tid & 63) == 0) { ss[w] = s; ss2[w] = s2; }
  __syncthreads();
  s  = ss[0] + ss[1] + ss[2] + ss[3];
  s2 = ss2[0] + ss2[1] + ss2[2] + ss2[3];
  const float mu   = s * (1.0f / D_);
  const float var  = s2 * (1.0f / D_) - mu * mu;
  const float rstd = rsqrtf(var + 1e-5f);
  float4 gv = reinterpret_cast<const float4*>(g)[tid];
  float4 bv = reinterpret_cast<const float4*>(b)[tid];
  short4 o;
  o.x = f2bf((v.x - mu) * rstd * gv.x + bv.x);
  o.y = f2bf((v.y - mu) * rstd * gv.y + bv.y);
  o.z = f2bf((v.z - mu) * rstd * gv.z + bv.z);
  o.w = f2bf((v.w - mu) * rstd * gv.w + bv.w);
  reinterpret_cast<short4*>(out + (size_t)row * D_)[tid] = o;
}

// ---------------- GEMM 128x128: C(MxN) = A(MxK,bf16) * Bt(NxK,bf16)^T --------
// MODE 0: store bf16.  MODE 1: fp32 out = resid + acc + bias.
// MODE 2: bf16 out = gelu(acc + bias)  (tanh-sigmoid approx).
template <int MODE>
__global__ __launch_bounds__(256) void gemm_bt(const short* __restrict__ A,
                                               const short* __restrict__ Bt,
                                               const float* __restrict__ bias,
                                               const float* __restrict__ resid,
                                               void* __restrict__ Cout,
                                               int M, int N, int K) {
  __shared__ short As[128 * 32];
  __shared__ short Bs[128 * 32];
  const int tid = threadIdx.x;
  // XCD-aware swizzle (nwg % 8 == 0 for all launches)
  const int gx = gridDim.x;
  const int nwg = gx * gridDim.y;
  int lin = blockIdx.y * gx + blockIdx.x;
  lin = (lin & 7) * (nwg >> 3) + (lin >> 3);
  const int m0 = (lin / gx) * 128, n0 = (lin % gx) * 128;
  const int wave = tid >> 6, lane = tid & 63;
  const int wm = (wave >> 1) * 64, wn = (wave & 1) * 64;
  const int lr = lane & 15, lg = lane >> 4;

  f32x4 acc[4][4];
#pragma unroll
  for (int i = 0; i < 4; ++i)
#pragma unroll
    for (int j = 0; j < 4; ++j) acc[i][j] = f32x4{0.f, 0.f, 0.f, 0.f};

  const int e0 = tid * 8, e1 = 2048 + tid * 8;
  const int r0 = e0 >> 5, c0 = e0 & 31;
  const int r1 = e1 >> 5, c1 = e1 & 31;
  const size_t ar0 = (size_t)(m0 + r0) * K, ar1 = (size_t)(m0 + r1) * K;
  const size_t br0 = (size_t)(n0 + r0) * K, br1 = (size_t)(n0 + r1) * K;

  for (int k0 = 0; k0 < K; k0 += 32) {
    gload16(A + ar0 + k0 + c0, As + e0);
    gload16(A + ar1 + k0 + c1, As + e1);
    gload16(Bt + br0 + k0 + c0, Bs + e0);
    gload16(Bt + br1 + k0 + c1, Bs + e1);
    __syncthreads();
    bf16x8 af[4], bfr[4];
#pragma unroll
    for (int mi = 0; mi < 4; ++mi)
      af[mi] = *(const bf16x8*)(As + (wm + mi * 16 + lr) * 32 + lg * 8);
#pragma unroll
    for (int ni = 0; ni < 4; ++ni)
      bfr[ni] = *(const bf16x8*)(Bs + (wn + ni * 16 + lr) * 32 + lg * 8);
#pragma unroll
    for (int mi = 0; mi < 4; ++mi)
#pragma unroll
      for (int ni = 0; ni < 4; ++ni)
        acc[mi][ni] = __builtin_amdgcn_mfma_f32_16x16x32_bf16(
            af[mi], bfr[ni], acc[mi][ni], 0, 0, 0);
    __syncthreads();
  }

#pragma unroll
  for (int mi = 0; mi < 4; ++mi) {
    const int row = m0 + wm + mi * 16 + lg * 4;
#pragma unroll
    for (int ni = 0; ni < 4; ++ni) {
      const int col = n0 + wn + ni * 16 + lr;
#pragma unroll
      for (int r = 0; r < 4; ++r) {
        const size_t idx = (size_t)(row + r) * N + col;
        const float v = acc[mi][ni][r];
        if (MODE == 0) {
          ((short*)Cout)[idx] = f2bf(v);
        } else if (MODE == 1) {
          ((float*)Cout)[idx] = resid[idx] + v + bias[col];
        } else {
          const float tt = v + bias[col];
          const float yy = fmaf(tt * tt * tt, 0.044715f, tt);
          const float e = EXP2(yy * -2.3022343813918633f);
          ((short*)Cout)[idx] = f2bf(tt / (1.0f + e));
        }
      }
    }
  }
}

// ---------------- batched-3 GEMM 128x128, MODE0 (cross-attn q/k/v) -----------
__global__ __launch_bounds__(256) void gemm_bt3(const short* __restrict__ A0,
                                                const short* __restrict__ A1,
                                                const short* __restrict__ A2,
                                                const short* __restrict__ B0,
                                                const short* __restrict__ B1,
                                                const short* __restrict__ B2,
                                                short* __restrict__ C0,
                                                short* __restrict__ C1,
                                                short* __restrict__ C2,
                                                int M, int N, int K) {
  const int z = blockIdx.z;
  const short* A  = z == 0 ? A0 : (z == 1 ? A1 : A2);
  const short* Bt = z == 0 ? B0 : (z == 1 ? B1 : B2);
  short* C        = z == 0 ? C0 : (z == 1 ? C1 : C2);

  __shared__ short As[128 * 32];
  __shared__ short Bs[128 * 32];
  const int tid = threadIdx.x;
  const int gx = gridDim.x;
  const int nwg = gx * gridDim.y;
  int lin = blockIdx.y * gx + blockIdx.x;
  lin = (lin & 7) * (nwg >> 3) + (lin >> 3);
  const int m0 = (lin / gx) * 128, n0 = (lin % gx) * 128;
  const int wave = tid >> 6, lane = tid & 63;
  const int wm = (wave >> 1) * 64, wn = (wave & 1) * 64;
  const int lr = lane & 15, lg = lane >> 4;

  f32x4 acc[4][4];
#pragma unroll
  for (int i = 0; i < 4; ++i)
#pragma unroll
    for (int j = 0; j < 4; ++j) acc[i][j] = f32x4{0.f, 0.f, 0.f, 0.f};

  const int e0 = tid * 8, e1 = 2048 + tid * 8;
  const int r0 = e0 >> 5, c0 = e0 & 31;
  const int r1 = e1 >> 5, c1 = e1 & 31;
  const size_t ar0 = (size_t)(m0 + r0) * K, ar1 = (size_t)(m0 + r1) * K;
  const size_t br0 = (size_t)(n0 + r0) * K, br1 = (size_t)(n0 + r1) * K;

  for (int k0 = 0; k0 < K; k0 += 32) {
    gload16(A + ar0 + k0 + c0, As + e0);
    gload16(A + ar1 + k0 + c1, As + e1);
    gload16(Bt + br0 + k0 + c0, Bs + e0);
    gload16(Bt + br1 + k0 + c1, Bs + e1);
    __syncthreads();
    bf16x8 af[4], bfr[4];
#pragma unroll
    for (int mi = 0; mi < 4; ++mi)
      af[mi] = *(const bf16x8*)(As + (wm + mi * 16 + lr) * 32 + lg * 8);
#pragma unroll
    for (int ni = 0; ni < 4; ++ni)
      bfr[ni] = *(const bf16x8*)(Bs + (wn + ni * 16 + lr) * 32 + lg * 8);
#pragma unroll
    for (int mi = 0; mi < 4; ++mi)
#pragma unroll
      for (int ni = 0; ni < 4; ++ni)
        acc[mi][ni] = __builtin_amdgcn_mfma_f32_16x16x32_bf16(
            af[mi], bfr[ni], acc[mi][ni], 0, 0, 0);
    __syncthreads();
  }

#pragma unroll
  for (int mi = 0; mi < 4; ++mi) {
    const int row = m0 + wm + mi * 16 + lg * 4;
#pragma unroll
    for (int ni = 0; ni < 4; ++ni) {
      const int col = n0 + wn + ni * 16 + lr;
#pragma unroll
      for (int r = 0; r < 4; ++r)
        C[(size_t)(row + r) * N + col] = f2bf(acc[mi][ni][r]);
    }
  }
}

// ---------------- GEMM 64x128 tile (for N=1024 shapes: 512 blocks, 2/CU) -----
// MODE 1 only: fp32 out = resid + acc + bias.
__global__ __launch_bounds__(256) void gemm_bt64(const short* __restrict__ A,
                                                 const short* __restrict__ Bt,
                                                 const float* __restrict__ bias,
                                                 const float* __restrict__ resid,
                                                 float* __restrict__ Cout,
                                                 int M, int N, int K) {
  __shared__ short As[64 * 32];
  __shared__ short Bs[128 * 32];
  const int tid = threadIdx.x;
  const int gx = gridDim.x;
  const int nwg = gx * gridDim.y;
  int lin = blockIdx.y * gx + blockIdx.x;
  lin = (lin & 7) * (nwg >> 3) + (lin >> 3);
  const int m0 = (lin / gx) * 64, n0 = (lin % gx) * 128;
  const int wave = tid >> 6, lane = tid & 63;
  const int wn = wave * 32;
  const int lr = lane & 15, lg = lane >> 4;

  f32x4 acc[4][2];
#pragma unroll
  for (int i = 0; i < 4; ++i)
#pragma unroll
    for (int j = 0; j < 2; ++j) acc[i][j] = f32x4{0.f, 0.f, 0.f, 0.f};

  const int ea = tid * 8;
  const int ra = ea >> 5, ca = ea & 31;
  const int e0 = tid * 8, e1 = 2048 + tid * 8;
  const int r0 = e0 >> 5, c0 = e0 & 31;
  const int r1 = e1 >> 5, c1 = e1 & 31;
  const size_t ar = (size_t)(m0 + ra) * K;
  const size_t br0 = (size_t)(n0 + r0) * K, br1 = (size_t)(n0 + r1) * K;

  for (int k0 = 0; k0 < K; k0 += 32) {
    gload16(A + ar + k0 + ca, As + ea);
    gload16(Bt + br0 + k0 + c0, Bs + e0);
    gload16(Bt + br1 + k0 + c1, Bs + e1);
    __syncthreads();
    bf16x8 af[4], bfr[2];
#pragma unroll
    for (int mi = 0; mi < 4; ++mi)
      af[mi] = *(const bf16x8*)(As + (mi * 16 + lr) * 32 + lg * 8);
#pragma unroll
    for (int ni = 0; ni < 2; ++ni)
      bfr[ni] = *(const bf16x8*)(Bs + (wn + ni * 16 + lr) * 32 + lg * 8);
#pragma unroll
    for (int mi = 0; mi < 4; ++mi)
#pragma unroll
      for (int ni = 0; ni < 2; ++ni)
        acc[mi][ni] = __builtin_amdgcn_mfma_f32_16x16x32_bf16(
            af[mi], bfr[ni], acc[mi][ni], 0, 0, 0);
    __syncthreads();
  }

#pragma unroll
  for (int mi = 0; mi < 4; ++mi) {
    const int row = m0 + mi * 16 + lg * 4;
#pragma unroll
    for (int ni = 0; ni < 2; ++ni) {
      const int col = n0 + wn + ni * 16 + lr;
#pragma unroll
      for (int r = 0; r < 4; ++r) {
        const size_t idx = (size_t)(row + r) * N + col;
        Cout[idx] = resid[idx] + acc[mi][ni][r] + bias[col];
      }
    }
  }
}

// ---------------- per-head V transpose (bf16): (N x HD) -> (HD x N) ----------
__global__ __launch_bounds__(256) void vtrans(const short* __restrict__ in,
                                              short* __restrict__ out,
                                              int ldi, int N) {
  const int bh = blockIdx.z;
  const int b = bh >> 4, h = bh & 15;
  const short* ib = in + (size_t)b * N * ldi + h * HD_;
  short* ob = out + (size_t)bh * HD_ * N;
  __shared__ short t[32][33];
  const int tx = threadIdx.x, ty = threadIdx.y;
  const int n0 = blockIdx.x * 32, d0 = blockIdx.y * 32;
#pragma unroll
  for (int i = 0; i < 4; ++i)
    t[ty + i * 8][tx] = ib[(size_t)(n0 + ty + i * 8) * ldi + d0 + tx];
  __syncthreads();
#pragma unroll
  for (int i = 0; i < 4; ++i)
    ob[(size_t)(d0 + ty + i * 8) * N + n0 + tx] = t[tx][ty + i * 8];
}

// ---------------- flash attention: 64 q-rows/block, KBLK=64 ------------------
// grid = (bh=32, qb=32). Causal: qb remapped so consecutive blocks pair long
// and short diagonals (equal work) and share a head (K/V L2 reuse).
// Raw-domain scores; scale folded into exp2. Mask only on diagonal tile.
// Row-sum via ones-MFMA; defer-max rescale (THR=44 raw ~ P<=2^8).
// P bounce through per-wave swizzled LDS (round-2-proven path).
__global__ __launch_bounds__(256) void flash(const short* __restrict__ Q,
                                             const short* __restrict__ Kp,
                                             const short* __restrict__ Vt,
                                             short* __restrict__ O,
                                             int ldq, int ldk, int ldo,
                                             int NK, int causal) {
  const int bh = blockIdx.x;
  int qb = blockIdx.y;
  if (causal) qb = (qb < 16) ? (2 * qb) : (63 - 2 * qb);
  const int b = bh >> 4, h = bh & 15;
  const int q0 = qb * 64;
  const int tid = threadIdx.x, wave = tid >> 6, lane = tid & 63;
  const int lr = lane & 15, lg = lane >> 4;
  const int lx = lr & 7;

  const short* Qb = Q + (size_t)b * ND_ * ldq + h * HD_;
  const short* Kb = Kp + (size_t)b * NK * ldk + h * HD_;
  const short* Vb = Vt + (size_t)bh * HD_ * NK;
  short* Ob = O + (size_t)b * ND_ * ldo + h * HD_;

  __shared__ short Ks[64 * 64];
  __shared__ short Vs[64 * 64];
  __shared__ short Ps[4][16 * 64];   // per-wave P tile, [q][k] swizzled

  const int qrow = q0 + wave * 16 + lr;
  const bf16x8 qf0 = *(const bf16x8*)(Qb + (size_t)qrow * ldq + lg * 8);
  const bf16x8 qf1 = *(const bf16x8*)(Qb + (size_t)qrow * ldq + 32 + lg * 8);

  const bf16x8 ONES = {0x3F80, 0x3F80, 0x3F80, 0x3F80,
                       0x3F80, 0x3F80, 0x3F80, 0x3F80};  // bf16 1.0 x8

  f32x4 oacc[4];
  f32x4 lacc = f32x4{0.f, 0.f, 0.f, 0.f};
  float m[4];
#pragma unroll
  for (int i = 0; i < 4; ++i) {
    oacc[i] = f32x4{0.f, 0.f, 0.f, 0.f};
    m[i] = -1e30f;
  }

  // staging geometry: LDS dest linear (tid*16B); source col slot XOR'd by row
  const int sr0 = tid >> 3;
  const int ssw = ((tid & 7) ^ (sr0 & 7)) * 8;
  const int e0 = tid * 8, e1 = 2048 + tid * 8;

  const float SC = 0.18033688011112042f;  // 1/sqrt(64) * log2(e)

  short* Pw = &Ps[wave][0];

  const int nkt = causal ? (qb + 1) : (NK / 64);
  for (int t = 0; t < nkt; ++t) {
    const int k0 = t * 64;
    gload16(Kb + (size_t)(k0 + sr0) * ldk + ssw, Ks + e0);
    gload16(Kb + (size_t)(k0 + 32 + sr0) * ldk + ssw, Ks + e1);
    gload16(Vb + (size_t)sr0 * NK + k0 + ssw, Vs + e0);
    gload16(Vb + (size_t)(32 + sr0) * NK + k0 + ssw, Vs + e1);
    __syncthreads();

    f32x4 s[4];
#pragma unroll
    for (int kb = 0; kb < 4; ++kb) {
      const bf16x8 kf0 = *(const bf16x8*)(Ks + (kb * 16 + lr) * 64 + ((lg ^ lx) * 8));
      const bf16x8 kf1 = *(const bf16x8*)(Ks + (kb * 16 + lr) * 64 + (((4 + lg) ^ lx) * 8));
      s[kb] = f32x4{0.f, 0.f, 0.f, 0.f};
      s[kb] = __builtin_amdgcn_mfma_f32_16x16x32_bf16(qf0, kf0, s[kb], 0, 0, 0);
      s[kb] = __builtin_amdgcn_mfma_f32_16x16x32_bf16(qf1, kf1, s[kb], 0, 0, 0);
    }
    if (causal && t == nkt - 1) {  // mask only the diagonal tile
#pragma unroll
      for (int kb = 0; kb < 4; ++kb)
#pragma unroll
        for (int r = 0; r < 4; ++r)
          if ((k0 + kb * 16 + lr) > (q0 + wave * 16 + lg * 4 + r))
            s[kb][r] = -3.0e38f;
    }
    float rm[4];
#pragma unroll
    for (int r = 0; r < 4; ++r)
      rm[r] = fmaxf(fmaxf(s[0][r], s[1][r]), fmaxf(s[2][r], s[3][r]));
#pragma unroll
    for (int msk = 1; msk < 16; msk <<= 1)
#pragma unroll
      for (int r = 0; r < 4; ++r)
        rm[r] = fmaxf(rm[r], __shfl_xor(rm[r], msk));

    // defer-max: only rescale when max grew enough to matter (P <= 2^8)
    const int ok = (rm[0] - m[0] <= 44.f) & (rm[1] - m[1] <= 44.f) &
                   (rm[2] - m[2] <= 44.f) & (rm[3] - m[3] <= 44.f);
    if (!__all(ok)) {
#pragma unroll
      for (int r = 0; r < 4; ++r) {
        const float nm = fmaxf(m[r], rm[r]);
        const float fac = EXP2((m[r] - nm) * SC);
        m[r] = nm;
#pragma unroll
        for (int db = 0; db < 4; ++db) oacc[db][r] *= fac;
        lacc[r] *= fac;
      }
    }
    float msc[4];
#pragma unroll
    for (int r = 0; r < 4; ++r) msc[r] = m[r] * SC;
#pragma unroll
    for (int kb = 0; kb < 4; ++kb)
#pragma unroll
      for (int r = 0; r < 4; ++r)
        s[kb][r] = EXP2(fmaf(s[kb][r], SC, -msc[r]));

    // P bounce through per-wave LDS, swizzled on both sides (proven path)
#pragma unroll
    for (int kb = 0; kb < 4; ++kb) {
      const int cs = kb * 2 + (lr >> 3);
#pragma unroll
      for (int r = 0; r < 4; ++r) {
        const int q = lg * 4 + r;
        Pw[q * 64 + ((cs ^ (q & 7)) * 8) + (lr & 7)] = f2bf(s[kb][r]);
      }
    }
    const bf16x8 pf0 = *(const bf16x8*)(Pw + lr * 64 + ((lg ^ lx) * 8));
    const bf16x8 pf1 = *(const bf16x8*)(Pw + lr * 64 + (((4 + lg) ^ lx) * 8));

#pragma unroll
    for (int db = 0; db < 4; ++db) {
      const bf16x8 vf0 = *(const bf16x8*)(Vs + (db * 16 + lr) * 64 + ((lg ^ lx) * 8));
      const bf16x8 vf1 = *(const bf16x8*)(Vs + (db * 16 + lr) * 64 + (((4 + lg) ^ lx) * 8));
      oacc[db] = __builtin_amdgcn_mfma_f32_16x16x32_bf16(pf0, vf0, oacc[db], 0, 0, 0);
      oacc[db] = __builtin_amdgcn_mfma_f32_16x16x32_bf16(pf1, vf1, oacc[db], 0, 0, 0);
    }
    // row-sum of P via ones-MFMA (layout matches oacc rows exactly)
    lacc = __builtin_amdgcn_mfma_f32_16x16x32_bf16(pf0, ONES, lacc, 0, 0, 0);
    lacc = __builtin_amdgcn_mfma_f32_16x16x32_bf16(pf1, ONES, lacc, 0, 0, 0);
    __syncthreads();
  }
#pragma unroll
  for (int db = 0; db < 4; ++db)
#pragma unroll
    for (int r = 0; r < 4; ++r) {
      const int q = q0 + wave * 16 + lg * 4 + r;
      Ob[(size_t)q * ldo + db * 16 + lr] = f2bf(oacc[db][r] / lacc[r]);
    }
}

// ---------------------------------------------------------------------------
extern "C" void kernel_launch(void* const* d_in, const int* in_sizes, int n_in,
                              void* d_out, int out_size, void* d_ws, size_t ws_size,
                              hipStream_t stream) {
  const float* x      = (const float*)d_in[0];
  const float* memory = (const float*)d_in[1];
  const float* ln1_g  = (const float*)d_in[2];
  const float* ln1_b  = (const float*)d_in[3];
  const float* Wqkv   = (const float*)d_in[4];
  const float* Wo_sa  = (const float*)d_in[5];
  const float* bo_sa  = (const float*)d_in[6];
  const float* ln2_g  = (const float*)d_in[7];
  const float* ln2_b  = (const float*)d_in[8];
  const float* Wq     = (const float*)d_in[9];
  const float* Wk     = (const float*)d_in[10];
  const float* Wv     = (const float*)d_in[11];
  const float* Wo_ca  = (const float*)d_in[12];
  const float* bo_ca  = (const float*)d_in[13];
  const float* ln3_g  = (const float*)d_in[14];
  const float* ln3_b  = (const float*)d_in[15];
  const float* W1     = (const float*)d_in[16];
  const float* b1     = (const float*)d_in[17];
  const float* W2     = (const float*)d_in[18];
  const float* b2     = (const float*)d_in[19];

  char* ws = (char*)d_ws;
  size_t o = 0;
  auto alloc = [&](size_t bytes) { char* p = ws + o; o += bytes; return p; };
  short* wqkv_t = (short*)alloc((size_t)3072 * 1024 * 2);
  short* wosa_t = (short*)alloc((size_t)1024 * 1024 * 2);
  short* wq_t   = (short*)alloc((size_t)1024 * 1024 * 2);
  short* wk_t   = (short*)alloc((size_t)1024 * 1024 * 2);
  short* wv_t   = (short*)alloc((size_t)1024 * 1024 * 2);
  short* woca_t = (short*)alloc((size_t)1024 * 1024 * 2);
  short* w1_t   = (short*)alloc((size_t)4096 * 1024 * 2);
  short* w2_t   = (short*)alloc((size_t)1024 * 4096 * 2);
  short* hbf    = (short*)alloc((size_t)T_ * 1024 * 2);
  short* bufa   = (short*)alloc((size_t)T_ * 3072 * 2);  // qkv, later q/k/v_ca, later ffn
  short* vt     = (short*)alloc((size_t)32 * 64 * 2048 * 2);
  short* attn   = (short*)alloc((size_t)T_ * 1024 * 2);
  short* membf  = (short*)alloc((size_t)T_ * 1024 * 2);
  float* x1     = (float*)alloc((size_t)T_ * 1024 * 4);
  float* x2     = (float*)alloc((size_t)T_ * 1024 * 4);
  if (o > ws_size) return;  // workspace too small — bail rather than corrupt

  short* ffn = bufa;  // spans bufa(24MB)+vt(8MB) = 32MB, both dead by then
  short* qca = bufa;
  short* kca = bufa + (size_t)T_ * 1024;
  short* vca = bufa + (size_t)2 * T_ * 1024;

  const dim3 tb(32, 8);

  // weight transposes (fp32 -> bf16, K x N -> N x K)
  wt_cast<<<dim3(3072 / 32, 1024 / 32), tb, 0, stream>>>(Wqkv, wqkv_t, 1024, 3072);
  wt_cast<<<dim3(1024 / 32, 1024 / 32), tb, 0, stream>>>(Wo_sa, wosa_t, 1024, 1024);
  wt_cast<<<dim3(1024 / 32, 1024 / 32), tb, 0, stream>>>(Wq, wq_t, 1024, 1024);
  wt_cast<<<dim3(1024 / 32, 1024 / 32), tb, 0, stream>>>(Wk, wk_t, 1024, 1024);
  wt_cast<<<dim3(1024 / 32, 1024 / 32), tb, 0, stream>>>(Wv, wv_t, 1024, 1024);
  wt_cast<<<dim3(1024 / 32, 1024 / 32), tb, 0, stream>>>(Wo_ca, woca_t, 1024, 1024);
  wt_cast<<<dim3(4096 / 32, 1024 / 32), tb, 0, stream>>>(W1, w1_t, 1024, 4096);
  wt_cast<<<dim3(1024 / 32, 4096 / 32), tb, 0, stream>>>(W2, w2_t, 4096, 1024);
  castf2b<<<dim3((T_ * 1024) / (256 * 4)), 256, 0, stream>>>(memory, membf);

  // --- self-attention block ---
  ln_kernel<<<dim3(T_), 256, 0, stream>>>(x, ln1_g, ln1_b, hbf);
  gemm_bt<0><<<dim3(3072 / 128, T_ / 128), 256, 0, stream>>>(
      hbf, wqkv_t, nullptr, nullptr, bufa, T_, 3072, 1024);
  vtrans<<<dim3(ND_ / 32, HD_ / 32, 32), tb, 0, stream>>>(bufa + 2048, vt, 3072, ND_);
  flash<<<dim3(32, ND_ / 64), 256, 0, stream>>>(
      bufa, bufa + 1024, vt, attn, 3072, 3072, 1024, ND_, 1);
  gemm_bt64<<<dim3(1024 / 128, T_ / 64), 256, 0, stream>>>(
      attn, wosa_t, bo_sa, x, x1, T_, 1024, 1024);

  // --- cross-attention block ---
  ln_kernel<<<dim3(T_), 256, 0, stream>>>(x1, ln2_g, ln2_b, hbf);
  gemm_bt3<<<dim3(1024 / 128, T_ / 128, 3), 256, 0, stream>>>(
      hbf, membf, membf, wq_t, wk_t, wv_t, qca, kca, vca, T_, 1024, 1024);
  vtrans<<<dim3(NE_ / 32, HD_ / 32, 32), tb, 0, stream>>>(vca, vt, 1024, NE_);
  flash<<<dim3(32, ND_ / 64), 256, 0, stream>>>(
      qca, kca, vt, attn, 1024, 1024, 1024, NE_, 0);
  gemm_bt64<<<dim3(1024 / 128, T_ / 64), 256, 0, stream>>>(
      attn, woca_t, bo_ca, x1, x2, T_, 1024, 1024);

  // --- FFN block ---
  ln_kernel<<<dim3(T_), 256, 0, stream>>>(x2, ln3_g, ln3_b, hbf);
  gemm_bt<2><<<dim3(4096 / 128, T_ / 128), 256, 0, stream>>>(
      hbf, w1_t, b1, nullptr, ffn, T_, 4096, 1024);
  gemm_bt64<<<dim3(1024 / 128, T_ / 64), 256, 0, stream>>>(
      ffn, w2_t, b2, x2, (float*)d_out, T_, 1024, 4096);
}

// Round 6
// 427.018 us; speedup vs baseline: 1.8093x; 1.0766x over previous
//
#include <hip/hip_runtime.h>
#include <hip/hip_bf16.h>
#include <math.h>

#define B_   2
#define ND_  2048
#define NE_  2048
#define D_   1024
#define H_   16
#define HD_  64
#define DFF_ 4096
#define T_   4096   // B_*ND_ tokens

typedef __attribute__((ext_vector_type(8))) short bf16x8;
typedef __attribute__((ext_vector_type(4))) float f32x4;

#if __has_builtin(__builtin_amdgcn_exp2f)
#define EXP2(x) __builtin_amdgcn_exp2f(x)
#else
#define EXP2(x) exp2f(x)
#endif

__device__ __forceinline__ short f2bf(float f) {
  union { float f; unsigned u; } v; v.f = f;
  return (short)((v.u + 0x7FFFu + ((v.u >> 16) & 1u)) >> 16);
}

typedef const __attribute__((address_space(1))) void gvoid_t;
typedef __attribute__((address_space(3))) void lvoid_t;

__device__ __forceinline__ void gload16(const void* src, void* dst) {
  __builtin_amdgcn_global_load_lds((gvoid_t*)src, (lvoid_t*)dst, 16, 0, 0);
}

// ---------------- weight transpose + cast: fp32 (K x N) -> bf16 (N x K) ------
__global__ __launch_bounds__(256) void wt_cast(const float* __restrict__ in,
                                               short* __restrict__ out,
                                               int K, int N) {
  __shared__ float t[32][33];
  const int tx = threadIdx.x, ty = threadIdx.y;
  const int n0 = blockIdx.x * 32, k0 = blockIdx.y * 32;
#pragma unroll
  for (int i = 0; i < 4; ++i)
    t[ty + i * 8][tx] = in[(size_t)(k0 + ty + i * 8) * N + n0 + tx];
  __syncthreads();
#pragma unroll
  for (int i = 0; i < 4; ++i)
    out[(size_t)(n0 + ty + i * 8) * K + k0 + tx] = f2bf(t[tx][ty + i * 8]);
}

// ---------------- elementwise cast fp32 -> bf16 ------------------------------
__global__ __launch_bounds__(256) void castf2b(const float* __restrict__ in,
                                               short* __restrict__ out) {
  const int i = blockIdx.x * 256 + threadIdx.x;
  float4 v = ((const float4*)in)[i];
  short4 o;
  o.x = f2bf(v.x); o.y = f2bf(v.y); o.z = f2bf(v.z); o.w = f2bf(v.w);
  ((short4*)out)[i] = o;
}

// ---------------- LayerNorm (row of 1024) fp32 -> bf16 -----------------------
__global__ __launch_bounds__(256) void ln_kernel(const float* __restrict__ x,
                                                 const float* __restrict__ g,
                                                 const float* __restrict__ b,
                                                 short* __restrict__ out) {
  const int row = blockIdx.x;
  const int tid = threadIdx.x;
  const float* xr = x + (size_t)row * D_;
  float4 v = reinterpret_cast<const float4*>(xr)[tid];
  float s  = v.x + v.y + v.z + v.w;
  float s2 = v.x * v.x + v.y * v.y + v.z * v.z + v.w * v.w;
#pragma unroll
  for (int m = 1; m < 64; m <<= 1) {
    s  += __shfl_xor(s, m);
    s2 += __shfl_xor(s2, m);
  }
  __shared__ float ss[4], ss2[4];
  const int w = tid >> 6;
  if ((tid & 63) == 0) { ss[w] = s; ss2[w] = s2; }
  __syncthreads();
  s  = ss[0] + ss[1] + ss[2] + ss[3];
  s2 = ss2[0] + ss2[1] + ss2[2] + ss2[3];
  const float mu   = s * (1.0f / D_);
  const float var  = s2 * (1.0f / D_) - mu * mu;
  const float rstd = rsqrtf(var + 1e-5f);
  float4 gv = reinterpret_cast<const float4*>(g)[tid];
  float4 bv = reinterpret_cast<const float4*>(b)[tid];
  short4 o;
  o.x = f2bf((v.x - mu) * rstd * gv.x + bv.x);
  o.y = f2bf((v.y - mu) * rstd * gv.y + bv.y);
  o.z = f2bf((v.z - mu) * rstd * gv.z + bv.z);
  o.w = f2bf((v.w - mu) * rstd * gv.w + bv.w);
  reinterpret_cast<short4*>(out + (size_t)row * D_)[tid] = o;
}

// ---------------- GEMM 128x128: C(MxN) = A(MxK,bf16) * Bt(NxK,bf16)^T --------
// MODE 0: store bf16.  MODE 1: fp32 out = resid + acc + bias.
// MODE 2: bf16 out = gelu(acc + bias)  (tanh-sigmoid approx).
template <int MODE>
__global__ __launch_bounds__(256) void gemm_bt(const short* __restrict__ A,
                                               const short* __restrict__ Bt,
                                               const float* __restrict__ bias,
                                               const float* __restrict__ resid,
                                               void* __restrict__ Cout,
                                               int M, int N, int K) {
  __shared__ short As[128 * 32];
  __shared__ short Bs[128 * 32];
  const int tid = threadIdx.x;
  // XCD-aware swizzle (nwg % 8 == 0 for all launches)
  const int gx = gridDim.x;
  const int nwg = gx * gridDim.y;
  int lin = blockIdx.y * gx + blockIdx.x;
  lin = (lin & 7) * (nwg >> 3) + (lin >> 3);
  const int m0 = (lin / gx) * 128, n0 = (lin % gx) * 128;
  const int wave = tid >> 6, lane = tid & 63;
  const int wm = (wave >> 1) * 64, wn = (wave & 1) * 64;
  const int lr = lane & 15, lg = lane >> 4;

  f32x4 acc[4][4];
#pragma unroll
  for (int i = 0; i < 4; ++i)
#pragma unroll
    for (int j = 0; j < 4; ++j) acc[i][j] = f32x4{0.f, 0.f, 0.f, 0.f};

  const int e0 = tid * 8, e1 = 2048 + tid * 8;
  const int r0 = e0 >> 5, c0 = e0 & 31;
  const int r1 = e1 >> 5, c1 = e1 & 31;
  const size_t ar0 = (size_t)(m0 + r0) * K, ar1 = (size_t)(m0 + r1) * K;
  const size_t br0 = (size_t)(n0 + r0) * K, br1 = (size_t)(n0 + r1) * K;

  for (int k0 = 0; k0 < K; k0 += 32) {
    gload16(A + ar0 + k0 + c0, As + e0);
    gload16(A + ar1 + k0 + c1, As + e1);
    gload16(Bt + br0 + k0 + c0, Bs + e0);
    gload16(Bt + br1 + k0 + c1, Bs + e1);
    __syncthreads();
    bf16x8 af[4], bfr[4];
#pragma unroll
    for (int mi = 0; mi < 4; ++mi)
      af[mi] = *(const bf16x8*)(As + (wm + mi * 16 + lr) * 32 + lg * 8);
#pragma unroll
    for (int ni = 0; ni < 4; ++ni)
      bfr[ni] = *(const bf16x8*)(Bs + (wn + ni * 16 + lr) * 32 + lg * 8);
#pragma unroll
    for (int mi = 0; mi < 4; ++mi)
#pragma unroll
      for (int ni = 0; ni < 4; ++ni)
        acc[mi][ni] = __builtin_amdgcn_mfma_f32_16x16x32_bf16(
            af[mi], bfr[ni], acc[mi][ni], 0, 0, 0);
    __syncthreads();
  }

#pragma unroll
  for (int mi = 0; mi < 4; ++mi) {
    const int row = m0 + wm + mi * 16 + lg * 4;
#pragma unroll
    for (int ni = 0; ni < 4; ++ni) {
      const int col = n0 + wn + ni * 16 + lr;
#pragma unroll
      for (int r = 0; r < 4; ++r) {
        const size_t idx = (size_t)(row + r) * N + col;
        const float v = acc[mi][ni][r];
        if (MODE == 0) {
          ((short*)Cout)[idx] = f2bf(v);
        } else if (MODE == 1) {
          ((float*)Cout)[idx] = resid[idx] + v + bias[col];
        } else {
          const float tt = v + bias[col];
          const float yy = fmaf(tt * tt * tt, 0.044715f, tt);
          const float e = EXP2(yy * -2.3022343813918633f);
          ((short*)Cout)[idx] = f2bf(tt / (1.0f + e));
        }
      }
    }
  }
}

// ---------------- batched-3 GEMM 128x128, MODE0 (cross-attn q/k/v) -----------
__global__ __launch_bounds__(256) void gemm_bt3(const short* __restrict__ A0,
                                                const short* __restrict__ A1,
                                                const short* __restrict__ A2,
                                                const short* __restrict__ B0,
                                                const short* __restrict__ B1,
                                                const short* __restrict__ B2,
                                                short* __restrict__ C0,
                                                short* __restrict__ C1,
                                                short* __restrict__ C2,
                                                int M, int N, int K) {
  const int z = blockIdx.z;
  const short* A  = z == 0 ? A0 : (z == 1 ? A1 : A2);
  const short* Bt = z == 0 ? B0 : (z == 1 ? B1 : B2);
  short* C        = z == 0 ? C0 : (z == 1 ? C1 : C2);

  __shared__ short As[128 * 32];
  __shared__ short Bs[128 * 32];
  const int tid = threadIdx.x;
  const int gx = gridDim.x;
  const int nwg = gx * gridDim.y;
  int lin = blockIdx.y * gx + blockIdx.x;
  lin = (lin & 7) * (nwg >> 3) + (lin >> 3);
  const int m0 = (lin / gx) * 128, n0 = (lin % gx) * 128;
  const int wave = tid >> 6, lane = tid & 63;
  const int wm = (wave >> 1) * 64, wn = (wave & 1) * 64;
  const int lr = lane & 15, lg = lane >> 4;

  f32x4 acc[4][4];
#pragma unroll
  for (int i = 0; i < 4; ++i)
#pragma unroll
    for (int j = 0; j < 4; ++j) acc[i][j] = f32x4{0.f, 0.f, 0.f, 0.f};

  const int e0 = tid * 8, e1 = 2048 + tid * 8;
  const int r0 = e0 >> 5, c0 = e0 & 31;
  const int r1 = e1 >> 5, c1 = e1 & 31;
  const size_t ar0 = (size_t)(m0 + r0) * K, ar1 = (size_t)(m0 + r1) * K;
  const size_t br0 = (size_t)(n0 + r0) * K, br1 = (size_t)(n0 + r1) * K;

  for (int k0 = 0; k0 < K; k0 += 32) {
    gload16(A + ar0 + k0 + c0, As + e0);
    gload16(A + ar1 + k0 + c1, As + e1);
    gload16(Bt + br0 + k0 + c0, Bs + e0);
    gload16(Bt + br1 + k0 + c1, Bs + e1);
    __syncthreads();
    bf16x8 af[4], bfr[4];
#pragma unroll
    for (int mi = 0; mi < 4; ++mi)
      af[mi] = *(const bf16x8*)(As + (wm + mi * 16 + lr) * 32 + lg * 8);
#pragma unroll
    for (int ni = 0; ni < 4; ++ni)
      bfr[ni] = *(const bf16x8*)(Bs + (wn + ni * 16 + lr) * 32 + lg * 8);
#pragma unroll
    for (int mi = 0; mi < 4; ++mi)
#pragma unroll
      for (int ni = 0; ni < 4; ++ni)
        acc[mi][ni] = __builtin_amdgcn_mfma_f32_16x16x32_bf16(
            af[mi], bfr[ni], acc[mi][ni], 0, 0, 0);
    __syncthreads();
  }

#pragma unroll
  for (int mi = 0; mi < 4; ++mi) {
    const int row = m0 + wm + mi * 16 + lg * 4;
#pragma unroll
    for (int ni = 0; ni < 4; ++ni) {
      const int col = n0 + wn + ni * 16 + lr;
#pragma unroll
      for (int r = 0; r < 4; ++r)
        C[(size_t)(row + r) * N + col] = f2bf(acc[mi][ni][r]);
    }
  }
}

// ---------------- GEMM 64x128 tile (for N=1024 shapes: 512 blocks, 2/CU) -----
// MODE 1 only: fp32 out = resid + acc + bias.
__global__ __launch_bounds__(256) void gemm_bt64(const short* __restrict__ A,
                                                 const short* __restrict__ Bt,
                                                 const float* __restrict__ bias,
                                                 const float* __restrict__ resid,
                                                 float* __restrict__ Cout,
                                                 int M, int N, int K) {
  __shared__ short As[64 * 32];
  __shared__ short Bs[128 * 32];
  const int tid = threadIdx.x;
  const int gx = gridDim.x;
  const int nwg = gx * gridDim.y;
  int lin = blockIdx.y * gx + blockIdx.x;
  lin = (lin & 7) * (nwg >> 3) + (lin >> 3);
  const int m0 = (lin / gx) * 64, n0 = (lin % gx) * 128;
  const int wave = tid >> 6, lane = tid & 63;
  const int wn = wave * 32;
  const int lr = lane & 15, lg = lane >> 4;

  f32x4 acc[4][2];
#pragma unroll
  for (int i = 0; i < 4; ++i)
#pragma unroll
    for (int j = 0; j < 2; ++j) acc[i][j] = f32x4{0.f, 0.f, 0.f, 0.f};

  const int ea = tid * 8;
  const int ra = ea >> 5, ca = ea & 31;
  const int e0 = tid * 8, e1 = 2048 + tid * 8;
  const int r0 = e0 >> 5, c0 = e0 & 31;
  const int r1 = e1 >> 5, c1 = e1 & 31;
  const size_t ar = (size_t)(m0 + ra) * K;
  const size_t br0 = (size_t)(n0 + r0) * K, br1 = (size_t)(n0 + r1) * K;

  for (int k0 = 0; k0 < K; k0 += 32) {
    gload16(A + ar + k0 + ca, As + ea);
    gload16(Bt + br0 + k0 + c0, Bs + e0);
    gload16(Bt + br1 + k0 + c1, Bs + e1);
    __syncthreads();
    bf16x8 af[4], bfr[2];
#pragma unroll
    for (int mi = 0; mi < 4; ++mi)
      af[mi] = *(const bf16x8*)(As + (mi * 16 + lr) * 32 + lg * 8);
#pragma unroll
    for (int ni = 0; ni < 2; ++ni)
      bfr[ni] = *(const bf16x8*)(Bs + (wn + ni * 16 + lr) * 32 + lg * 8);
#pragma unroll
    for (int mi = 0; mi < 4; ++mi)
#pragma unroll
      for (int ni = 0; ni < 2; ++ni)
        acc[mi][ni] = __builtin_amdgcn_mfma_f32_16x16x32_bf16(
            af[mi], bfr[ni], acc[mi][ni], 0, 0, 0);
    __syncthreads();
  }

#pragma unroll
  for (int mi = 0; mi < 4; ++mi) {
    const int row = m0 + mi * 16 + lg * 4;
#pragma unroll
    for (int ni = 0; ni < 2; ++ni) {
      const int col = n0 + wn + ni * 16 + lr;
#pragma unroll
      for (int r = 0; r < 4; ++r) {
        const size_t idx = (size_t)(row + r) * N + col;
        Cout[idx] = resid[idx] + acc[mi][ni][r] + bias[col];
      }
    }
  }
}

// ---------------- per-head V transpose (bf16): (N x HD) -> (HD x N) ----------
__global__ __launch_bounds__(256) void vtrans(const short* __restrict__ in,
                                              short* __restrict__ out,
                                              int ldi, int N) {
  const int bh = blockIdx.z;
  const int b = bh >> 4, h = bh & 15;
  const short* ib = in + (size_t)b * N * ldi + h * HD_;
  short* ob = out + (size_t)bh * HD_ * N;
  __shared__ short t[32][33];
  const int tx = threadIdx.x, ty = threadIdx.y;
  const int n0 = blockIdx.x * 32, d0 = blockIdx.y * 32;
#pragma unroll
  for (int i = 0; i < 4; ++i)
    t[ty + i * 8][tx] = ib[(size_t)(n0 + ty + i * 8) * ldi + d0 + tx];
  __syncthreads();
#pragma unroll
  for (int i = 0; i < 4; ++i)
    ob[(size_t)(d0 + ty + i * 8) * N + n0 + tx] = t[tx][ty + i * 8];
}

// ---------------- flash attention: 64 q-rows/block, KBLK=64 ------------------
// Swapped QK^T: st = mfma(K, Q) = S^T; lane (lr,lg) holds S[q=q0+wave*16+lr]
// [k=k0+kb*16+lg*4+r] -> row-max is 15 in-lane fmax + 2 shfl_xor; running max
// is a scalar. P goes through the r4-PROVEN per-wave swizzled LDS bounce, but
// the swapped layout makes each lane's 4 values contiguous in k -> one
// ds_write_b64 per kb (4 writes vs 16). Fragment reads identical to r4.
// Row-sum via ones-MFMA; defer-max rescale (raw THR=44 ~ P<=2^8).
__global__ __launch_bounds__(256) void flash(const short* __restrict__ Q,
                                             const short* __restrict__ Kp,
                                             const short* __restrict__ Vt,
                                             short* __restrict__ O,
                                             int ldq, int ldk, int ldo,
                                             int NK, int causal) {
  const int bh = blockIdx.x;
  int qb = blockIdx.y;
  if (causal) qb = (qb < 16) ? (2 * qb) : (63 - 2 * qb);
  const int b = bh >> 4, h = bh & 15;
  const int q0 = qb * 64;
  const int tid = threadIdx.x, wave = tid >> 6, lane = tid & 63;
  const int lr = lane & 15, lg = lane >> 4;
  const int lx = lr & 7;

  const short* Qb = Q + (size_t)b * ND_ * ldq + h * HD_;
  const short* Kb = Kp + (size_t)b * NK * ldk + h * HD_;
  const short* Vb = Vt + (size_t)bh * HD_ * NK;
  short* Ob = O + (size_t)b * ND_ * ldo + h * HD_;

  __shared__ short Ks[64 * 64];
  __shared__ short Vs[64 * 64];
  __shared__ short Ps[4][16 * 64];   // per-wave P tile, [q][k] swizzled

  const int qrow = q0 + wave * 16 + lr;   // own q (B-operand col AND P row)
  const bf16x8 qf0 = *(const bf16x8*)(Qb + (size_t)qrow * ldq + lg * 8);
  const bf16x8 qf1 = *(const bf16x8*)(Qb + (size_t)qrow * ldq + 32 + lg * 8);

  const bf16x8 ONES = {0x3F80, 0x3F80, 0x3F80, 0x3F80,
                       0x3F80, 0x3F80, 0x3F80, 0x3F80};  // bf16 1.0 x8

  f32x4 oacc[4];
  f32x4 lacc = f32x4{0.f, 0.f, 0.f, 0.f};
  float m_own = -1e30f;   // running max for own q-row (q = lr within wave tile)
#pragma unroll
  for (int i = 0; i < 4; ++i) oacc[i] = f32x4{0.f, 0.f, 0.f, 0.f};

  // staging geometry: LDS dest linear (tid*16B); source col slot XOR'd by row
  const int sr0 = tid >> 3;
  const int ssw = ((tid & 7) ^ (sr0 & 7)) * 8;
  const int e0 = tid * 8, e1 = 2048 + tid * 8;

  const float SC = 0.18033688011112042f;  // 1/sqrt(64) * log2(e)

  short* Pw = &Ps[wave][0];
  // P write: row lr, logical slot cs = kb*2 + (lg>>1), half (lg&1)*4;
  // physical slot = cs ^ lx (same involution as the b128 read).
  const int pbase = lr * 64 + (lg & 1) * 4;

  const int nkt = causal ? (qb + 1) : (NK / 64);
  for (int t = 0; t < nkt; ++t) {
    const int k0 = t * 64;
    gload16(Kb + (size_t)(k0 + sr0) * ldk + ssw, Ks + e0);
    gload16(Kb + (size_t)(k0 + 32 + sr0) * ldk + ssw, Ks + e1);
    gload16(Vb + (size_t)sr0 * NK + k0 + ssw, Vs + e0);
    gload16(Vb + (size_t)(32 + sr0) * NK + k0 + ssw, Vs + e1);
    __syncthreads();

    // S^T: lane (lr,lg) gets S[q=qrow][k = k0 + kb*16 + lg*4 + r]
    f32x4 st[4];
#pragma unroll
    for (int kb = 0; kb < 4; ++kb) {
      const bf16x8 kf0 = *(const bf16x8*)(Ks + (kb * 16 + lr) * 64 + ((lg ^ lx) * 8));
      const bf16x8 kf1 = *(const bf16x8*)(Ks + (kb * 16 + lr) * 64 + (((4 + lg) ^ lx) * 8));
      st[kb] = f32x4{0.f, 0.f, 0.f, 0.f};
      st[kb] = __builtin_amdgcn_mfma_f32_16x16x32_bf16(kf0, qf0, st[kb], 0, 0, 0);
      st[kb] = __builtin_amdgcn_mfma_f32_16x16x32_bf16(kf1, qf1, st[kb], 0, 0, 0);
    }
    if (causal && t == nkt - 1) {  // mask only the diagonal tile
#pragma unroll
      for (int kb = 0; kb < 4; ++kb)
#pragma unroll
        for (int r = 0; r < 4; ++r)
          if ((k0 + kb * 16 + lg * 4 + r) > qrow) st[kb][r] = -3.0e38f;
    }

    // row max: 15 in-lane fmax + reduce across the 4 same-lr lanes
    float rm = st[0][0];
#pragma unroll
    for (int kb = 0; kb < 4; ++kb)
#pragma unroll
      for (int r = 0; r < 4; ++r)
        if (kb || r) rm = fmaxf(rm, st[kb][r]);
    rm = fmaxf(rm, __shfl_xor(rm, 16));
    rm = fmaxf(rm, __shfl_xor(rm, 32));

    // defer-max: rescale only when max grew enough to matter (P <= 2^8)
    if (!__all(rm - m_own <= 44.f)) {
      const float nm = fmaxf(m_own, rm);
      const float fac = EXP2((m_own - nm) * SC);
      m_own = nm;
      const float fr0 = __shfl(fac, (lg << 2) + 0);
      const float fr1 = __shfl(fac, (lg << 2) + 1);
      const float fr2 = __shfl(fac, (lg << 2) + 2);
      const float fr3 = __shfl(fac, (lg << 2) + 3);
#pragma unroll
      for (int db = 0; db < 4; ++db) {
        oacc[db][0] *= fr0; oacc[db][1] *= fr1;
        oacc[db][2] *= fr2; oacc[db][3] *= fr3;
      }
      lacc[0] *= fr0; lacc[1] *= fr1; lacc[2] *= fr2; lacc[3] *= fr3;
    }
    const float nmsc = m_own * SC;
#pragma unroll
    for (int kb = 0; kb < 4; ++kb)
#pragma unroll
      for (int r = 0; r < 4; ++r)
        st[kb][r] = EXP2(fmaf(st[kb][r], SC, -nmsc));

    // P bounce: one b64 write per kb (4 contiguous k), both-sides swizzled
#pragma unroll
    for (int kb = 0; kb < 4; ++kb) {
      const unsigned long long pk =
          (unsigned long long)(unsigned short)f2bf(st[kb][0]) |
          ((unsigned long long)(unsigned short)f2bf(st[kb][1]) << 16) |
          ((unsigned long long)(unsigned short)f2bf(st[kb][2]) << 32) |
          ((unsigned long long)(unsigned short)f2bf(st[kb][3]) << 48);
      const int cs = kb * 2 + (lg >> 1);
      *(unsigned long long*)(Pw + pbase + ((cs ^ lx) * 8)) = pk;
    }
    // fragment reads identical to the r4-proven path
    const bf16x8 pf0 = *(const bf16x8*)(Pw + lr * 64 + ((lg ^ lx) * 8));
    const bf16x8 pf1 = *(const bf16x8*)(Pw + lr * 64 + (((4 + lg) ^ lx) * 8));

#pragma unroll
    for (int db = 0; db < 4; ++db) {
      const bf16x8 vf0 = *(const bf16x8*)(Vs + (db * 16 + lr) * 64 + ((lg ^ lx) * 8));
      const bf16x8 vf1 = *(const bf16x8*)(Vs + (db * 16 + lr) * 64 + (((4 + lg) ^ lx) * 8));
      oacc[db] = __builtin_amdgcn_mfma_f32_16x16x32_bf16(pf0, vf0, oacc[db], 0, 0, 0);
      oacc[db] = __builtin_amdgcn_mfma_f32_16x16x32_bf16(pf1, vf1, oacc[db], 0, 0, 0);
    }
    // row-sum of P via ones-MFMA (same C layout as oacc)
    lacc = __builtin_amdgcn_mfma_f32_16x16x32_bf16(pf0, ONES, lacc, 0, 0, 0);
    lacc = __builtin_amdgcn_mfma_f32_16x16x32_bf16(pf1, ONES, lacc, 0, 0, 0);
    __syncthreads();
  }
#pragma unroll
  for (int db = 0; db < 4; ++db)
#pragma unroll
    for (int r = 0; r < 4; ++r) {
      const int q = q0 + wave * 16 + lg * 4 + r;
      Ob[(size_t)q * ldo + db * 16 + lr] = f2bf(oacc[db][r] / lacc[r]);
    }
}

// ---------------------------------------------------------------------------
extern "C" void kernel_launch(void* const* d_in, const int* in_sizes, int n_in,
                              void* d_out, int out_size, void* d_ws, size_t ws_size,
                              hipStream_t stream) {
  const float* x      = (const float*)d_in[0];
  const float* memory = (const float*)d_in[1];
  const float* ln1_g  = (const float*)d_in[2];
  const float* ln1_b  = (const float*)d_in[3];
  const float* Wqkv   = (const float*)d_in[4];
  const float* Wo_sa  = (const float*)d_in[5];
  const float* bo_sa  = (const float*)d_in[6];
  const float* ln2_g  = (const float*)d_in[7];
  const float* ln2_b  = (const float*)d_in[8];
  const float* Wq     = (const float*)d_in[9];
  const float* Wk     = (const float*)d_in[10];
  const float* Wv     = (const float*)d_in[11];
  const float* Wo_ca  = (const float*)d_in[12];
  const float* bo_ca  = (const float*)d_in[13];
  const float* ln3_g  = (const float*)d_in[14];
  const float* ln3_b  = (const float*)d_in[15];
  const float* W1     = (const float*)d_in[16];
  const float* b1     = (const float*)d_in[17];
  const float* W2     = (const float*)d_in[18];
  const float* b2     = (const float*)d_in[19];

  char* ws = (char*)d_ws;
  size_t o = 0;
  auto alloc = [&](size_t bytes) { char* p = ws + o; o += bytes; return p; };
  short* wqkv_t = (short*)alloc((size_t)3072 * 1024 * 2);
  short* wosa_t = (short*)alloc((size_t)1024 * 1024 * 2);
  short* wq_t   = (short*)alloc((size_t)1024 * 1024 * 2);
  short* wk_t   = (short*)alloc((size_t)1024 * 1024 * 2);
  short* wv_t   = (short*)alloc((size_t)1024 * 1024 * 2);
  short* woca_t = (short*)alloc((size_t)1024 * 1024 * 2);
  short* w1_t   = (short*)alloc((size_t)4096 * 1024 * 2);
  short* w2_t   = (short*)alloc((size_t)1024 * 4096 * 2);
  short* hbf    = (short*)alloc((size_t)T_ * 1024 * 2);
  short* bufa   = (short*)alloc((size_t)T_ * 3072 * 2);  // qkv, later q/k/v_ca, later ffn
  short* vt     = (short*)alloc((size_t)32 * 64 * 2048 * 2);
  short* attn   = (short*)alloc((size_t)T_ * 1024 * 2);
  short* membf  = (short*)alloc((size_t)T_ * 1024 * 2);
  float* x1     = (float*)alloc((size_t)T_ * 1024 * 4);
  float* x2     = (float*)alloc((size_t)T_ * 1024 * 4);
  if (o > ws_size) return;  // workspace too small — bail rather than corrupt

  short* ffn = bufa;  // spans bufa(24MB)+vt(8MB) = 32MB, both dead by then
  short* qca = bufa;
  short* kca = bufa + (size_t)T_ * 1024;
  short* vca = bufa + (size_t)2 * T_ * 1024;

  const dim3 tb(32, 8);

  // weight transposes (fp32 -> bf16, K x N -> N x K)
  wt_cast<<<dim3(3072 / 32, 1024 / 32), tb, 0, stream>>>(Wqkv, wqkv_t, 1024, 3072);
  wt_cast<<<dim3(1024 / 32, 1024 / 32), tb, 0, stream>>>(Wo_sa, wosa_t, 1024, 1024);
  wt_cast<<<dim3(1024 / 32, 1024 / 32), tb, 0, stream>>>(Wq, wq_t, 1024, 1024);
  wt_cast<<<dim3(1024 / 32, 1024 / 32), tb, 0, stream>>>(Wk, wk_t, 1024, 1024);
  wt_cast<<<dim3(1024 / 32, 1024 / 32), tb, 0, stream>>>(Wv, wv_t, 1024, 1024);
  wt_cast<<<dim3(1024 / 32, 1024 / 32), tb, 0, stream>>>(Wo_ca, woca_t, 1024, 1024);
  wt_cast<<<dim3(4096 / 32, 1024 / 32), tb, 0, stream>>>(W1, w1_t, 1024, 4096);
  wt_cast<<<dim3(1024 / 32, 4096 / 32), tb, 0, stream>>>(W2, w2_t, 4096, 1024);
  castf2b<<<dim3((T_ * 1024) / (256 * 4)), 256, 0, stream>>>(memory, membf);

  // --- self-attention block ---
  ln_kernel<<<dim3(T_), 256, 0, stream>>>(x, ln1_g, ln1_b, hbf);
  gemm_bt<0><<<dim3(3072 / 128, T_ / 128), 256, 0, stream>>>(
      hbf, wqkv_t, nullptr, nullptr, bufa, T_, 3072, 1024);
  vtrans<<<dim3(ND_ / 32, HD_ / 32, 32), tb, 0, stream>>>(bufa + 2048, vt, 3072, ND_);
  flash<<<dim3(32, ND_ / 64), 256, 0, stream>>>(
      bufa, bufa + 1024, vt, attn, 3072, 3072, 1024, ND_, 1);
  gemm_bt64<<<dim3(1024 / 128, T_ / 64), 256, 0, stream>>>(
      attn, wosa_t, bo_sa, x, x1, T_, 1024, 1024);

  // --- cross-attention block ---
  ln_kernel<<<dim3(T_), 256, 0, stream>>>(x1, ln2_g, ln2_b, hbf);
  gemm_bt3<<<dim3(1024 / 128, T_ / 128, 3), 256, 0, stream>>>(
      hbf, membf, membf, wq_t, wk_t, wv_t, qca, kca, vca, T_, 1024, 1024);
  vtrans<<<dim3(NE_ / 32, HD_ / 32, 32), tb, 0, stream>>>(vca, vt, 1024, NE_);
  flash<<<dim3(32, ND_ / 64), 256, 0, stream>>>(
      qca, kca, vt, attn, 1024, 1024, 1024, NE_, 0);
  gemm_bt64<<<dim3(1024 / 128, T_ / 64), 256, 0, stream>>>(
      attn, woca_t, bo_ca, x1, x2, T_, 1024, 1024);

  // --- FFN block ---
  ln_kernel<<<dim3(T_), 256, 0, stream>>>(x2, ln3_g, ln3_b, hbf);
  gemm_bt<2><<<dim3(4096 / 128, T_ / 128), 256, 0, stream>>>(
      hbf, w1_t, b1, nullptr, ffn, T_, 4096, 1024);
  gemm_bt64<<<dim3(1024 / 128, T_ / 64), 256, 0, stream>>>(
      ffn, w2_t, b2, x2, (float*)d_out, T_, 1024, 4096);
}

// Round 7
// 421.126 us; speedup vs baseline: 1.8347x; 1.0140x over previous
//
#include <hip/hip_runtime.h>
#include <hip/hip_bf16.h>
#include <math.h>

#define B_   2
#define ND_  2048
#define NE_  2048
#define D_   1024
#define H_   16
#define HD_  64
#define DFF_ 4096
#define T_   4096   // B_*ND_ tokens

typedef __attribute__((ext_vector_type(8))) short bf16x8;
typedef __attribute__((ext_vector_type(4))) float f32x4;

#if __has_builtin(__builtin_amdgcn_exp2f)
#define EXP2(x) __builtin_amdgcn_exp2f(x)
#else
#define EXP2(x) exp2f(x)
#endif

__device__ __forceinline__ short f2bf(float f) {
  union { float f; unsigned u; } v; v.f = f;
  return (short)((v.u + 0x7FFFu + ((v.u >> 16) & 1u)) >> 16);
}
__device__ __forceinline__ float bf2f(short s) {
  union { unsigned u; float f; } v; v.u = ((unsigned)(unsigned short)s) << 16;
  return v.f;
}

typedef const __attribute__((address_space(1))) void gvoid_t;
typedef __attribute__((address_space(3))) void lvoid_t;

__device__ __forceinline__ void gload16(const void* src, void* dst) {
  __builtin_amdgcn_global_load_lds((gvoid_t*)src, (lvoid_t*)dst, 16, 0, 0);
}

// ---------------- weight transpose + cast: fp32 (K x N) -> bf16 (N x K) ------
__global__ __launch_bounds__(256) void wt_cast(const float* __restrict__ in,
                                               short* __restrict__ out,
                                               int K, int N) {
  __shared__ float t[32][33];
  const int tx = threadIdx.x, ty = threadIdx.y;
  const int n0 = blockIdx.x * 32, k0 = blockIdx.y * 32;
#pragma unroll
  for (int i = 0; i < 4; ++i)
    t[ty + i * 8][tx] = in[(size_t)(k0 + ty + i * 8) * N + n0 + tx];
  __syncthreads();
#pragma unroll
  for (int i = 0; i < 4; ++i)
    out[(size_t)(n0 + ty + i * 8) * K + k0 + tx] = f2bf(t[tx][ty + i * 8]);
}

// ---------------- batched-5 1024x1024 weight transpose + cast ----------------
__global__ __launch_bounds__(256) void wt_cast5(const float* __restrict__ i0,
                                                const float* __restrict__ i1,
                                                const float* __restrict__ i2,
                                                const float* __restrict__ i3,
                                                const float* __restrict__ i4,
                                                short* __restrict__ o0,
                                                short* __restrict__ o1,
                                                short* __restrict__ o2,
                                                short* __restrict__ o3,
                                                short* __restrict__ o4) {
  const int z = blockIdx.z;
  const float* in = z == 0 ? i0 : z == 1 ? i1 : z == 2 ? i2 : z == 3 ? i3 : i4;
  short* out      = z == 0 ? o0 : z == 1 ? o1 : z == 2 ? o2 : z == 3 ? o3 : o4;
  __shared__ float t[32][33];
  const int tx = threadIdx.x, ty = threadIdx.y;
  const int n0 = blockIdx.x * 32, k0 = blockIdx.y * 32;
#pragma unroll
  for (int i = 0; i < 4; ++i)
    t[ty + i * 8][tx] = in[(size_t)(k0 + ty + i * 8) * 1024 + n0 + tx];
  __syncthreads();
#pragma unroll
  for (int i = 0; i < 4; ++i)
    out[(size_t)(n0 + ty + i * 8) * 1024 + k0 + tx] = f2bf(t[tx][ty + i * 8]);
}

// ---------------- elementwise cast fp32 -> bf16 ------------------------------
__global__ __launch_bounds__(256) void castf2b(const float* __restrict__ in,
                                               short* __restrict__ out) {
  const int i = blockIdx.x * 256 + threadIdx.x;
  float4 v = ((const float4*)in)[i];
  short4 o;
  o.x = f2bf(v.x); o.y = f2bf(v.y); o.z = f2bf(v.z); o.w = f2bf(v.w);
  ((short4*)out)[i] = o;
}

// ---------------- LayerNorm (row of 1024) fp32 -> bf16 -----------------------
__global__ __launch_bounds__(256) void ln_kernel(const float* __restrict__ x,
                                                 const float* __restrict__ g,
                                                 const float* __restrict__ b,
                                                 short* __restrict__ out) {
  const int row = blockIdx.x;
  const int tid = threadIdx.x;
  const float* xr = x + (size_t)row * D_;
  float4 v = reinterpret_cast<const float4*>(xr)[tid];
  float s  = v.x + v.y + v.z + v.w;
  float s2 = v.x * v.x + v.y * v.y + v.z * v.z + v.w * v.w;
#pragma unroll
  for (int m = 1; m < 64; m <<= 1) {
    s  += __shfl_xor(s, m);
    s2 += __shfl_xor(s2, m);
  }
  __shared__ float ss[4], ss2[4];
  const int w = tid >> 6;
  if ((tid & 63) == 0) { ss[w] = s; ss2[w] = s2; }
  __syncthreads();
  s  = ss[0] + ss[1] + ss[2] + ss[3];
  s2 = ss2[0] + ss2[1] + ss2[2] + ss2[3];
  const float mu   = s * (1.0f / D_);
  const float var  = s2 * (1.0f / D_) - mu * mu;
  const float rstd = rsqrtf(var + 1e-5f);
  float4 gv = reinterpret_cast<const float4*>(g)[tid];
  float4 bv = reinterpret_cast<const float4*>(b)[tid];
  short4 o;
  o.x = f2bf((v.x - mu) * rstd * gv.x + bv.x);
  o.y = f2bf((v.y - mu) * rstd * gv.y + bv.y);
  o.z = f2bf((v.z - mu) * rstd * gv.z + bv.z);
  o.w = f2bf((v.w - mu) * rstd * gv.w + bv.w);
  reinterpret_cast<short4*>(out + (size_t)row * D_)[tid] = o;
}

// ---------------- fused residual + bias + LayerNorm --------------------------
// xnew = xprev + delta(bf16) + pbias; writes xnew (fp32) and LN(xnew) (bf16).
// NOTE: delta may alias out_ln (per-thread read-then-write, same address).
__global__ __launch_bounds__(256) void ln_fused(const float* __restrict__ xprev,
                                                const short* delta,
                                                const float* __restrict__ pbias,
                                                const float* __restrict__ g,
                                                const float* __restrict__ b,
                                                short* out_ln,
                                                float* __restrict__ out_x) {
  const int row = blockIdx.x;
  const int tid = threadIdx.x;
  float4 v = reinterpret_cast<const float4*>(xprev + (size_t)row * D_)[tid];
  short4 dv = reinterpret_cast<const short4*>(delta + (size_t)row * D_)[tid];
  float4 pb = reinterpret_cast<const float4*>(pbias)[tid];
  v.x += bf2f(dv.x) + pb.x;
  v.y += bf2f(dv.y) + pb.y;
  v.z += bf2f(dv.z) + pb.z;
  v.w += bf2f(dv.w) + pb.w;
  float s  = v.x + v.y + v.z + v.w;
  float s2 = v.x * v.x + v.y * v.y + v.z * v.z + v.w * v.w;
#pragma unroll
  for (int m = 1; m < 64; m <<= 1) {
    s  += __shfl_xor(s, m);
    s2 += __shfl_xor(s2, m);
  }
  __shared__ float ss[4], ss2[4];
  const int w = tid >> 6;
  if ((tid & 63) == 0) { ss[w] = s; ss2[w] = s2; }
  __syncthreads();
  s  = ss[0] + ss[1] + ss[2] + ss[3];
  s2 = ss2[0] + ss2[1] + ss2[2] + ss2[3];
  const float mu   = s * (1.0f / D_);
  const float var  = s2 * (1.0f / D_) - mu * mu;
  const float rstd = rsqrtf(var + 1e-5f);
  reinterpret_cast<float4*>(out_x + (size_t)row * D_)[tid] = v;
  float4 gv = reinterpret_cast<const float4*>(g)[tid];
  float4 bv = reinterpret_cast<const float4*>(b)[tid];
  short4 o;
  o.x = f2bf((v.x - mu) * rstd * gv.x + bv.x);
  o.y = f2bf((v.y - mu) * rstd * gv.y + bv.y);
  o.z = f2bf((v.z - mu) * rstd * gv.z + bv.z);
  o.w = f2bf((v.w - mu) * rstd * gv.w + bv.w);
  reinterpret_cast<short4*>(out_ln + (size_t)row * D_)[tid] = o;
}

// ---------------- final residual + bias add: out = x + delta + bias ----------
__global__ __launch_bounds__(256) void addbias(const float* __restrict__ x,
                                               const short* __restrict__ delta,
                                               const float* __restrict__ bias,
                                               float* __restrict__ out) {
  const int i = blockIdx.x * 256 + threadIdx.x;
  float4 v = ((const float4*)x)[i];
  short4 dv = ((const short4*)delta)[i];
  const int col = (i * 4) & (D_ - 1);
  float4 pb = *(const float4*)(bias + col);
  v.x += bf2f(dv.x) + pb.x;
  v.y += bf2f(dv.y) + pb.y;
  v.z += bf2f(dv.z) + pb.z;
  v.w += bf2f(dv.w) + pb.w;
  ((float4*)out)[i] = v;
}

// ---------------- GEMM 128x128: C(MxN) = A(MxK,bf16) * Bt(NxK,bf16)^T --------
// MODE 0: store bf16.  MODE 2: bf16 out = gelu(acc + bias) (tanh-sigmoid).
template <int MODE>
__global__ __launch_bounds__(256) void gemm_bt(const short* __restrict__ A,
                                               const short* __restrict__ Bt,
                                               const float* __restrict__ bias,
                                               void* __restrict__ Cout,
                                               int M, int N, int K) {
  __shared__ short As[128 * 32];
  __shared__ short Bs[128 * 32];
  const int tid = threadIdx.x;
  const int gx = gridDim.x;
  const int nwg = gx * gridDim.y;
  int lin = blockIdx.y * gx + blockIdx.x;
  lin = (lin & 7) * (nwg >> 3) + (lin >> 3);
  const int m0 = (lin / gx) * 128, n0 = (lin % gx) * 128;
  const int wave = tid >> 6, lane = tid & 63;
  const int wm = (wave >> 1) * 64, wn = (wave & 1) * 64;
  const int lr = lane & 15, lg = lane >> 4;

  f32x4 acc[4][4];
#pragma unroll
  for (int i = 0; i < 4; ++i)
#pragma unroll
    for (int j = 0; j < 4; ++j) acc[i][j] = f32x4{0.f, 0.f, 0.f, 0.f};

  const int e0 = tid * 8, e1 = 2048 + tid * 8;
  const int r0 = e0 >> 5, c0 = e0 & 31;
  const int r1 = e1 >> 5, c1 = e1 & 31;
  const size_t ar0 = (size_t)(m0 + r0) * K, ar1 = (size_t)(m0 + r1) * K;
  const size_t br0 = (size_t)(n0 + r0) * K, br1 = (size_t)(n0 + r1) * K;

  for (int k0 = 0; k0 < K; k0 += 32) {
    gload16(A + ar0 + k0 + c0, As + e0);
    gload16(A + ar1 + k0 + c1, As + e1);
    gload16(Bt + br0 + k0 + c0, Bs + e0);
    gload16(Bt + br1 + k0 + c1, Bs + e1);
    __syncthreads();
    bf16x8 af[4], bfr[4];
#pragma unroll
    for (int mi = 0; mi < 4; ++mi)
      af[mi] = *(const bf16x8*)(As + (wm + mi * 16 + lr) * 32 + lg * 8);
#pragma unroll
    for (int ni = 0; ni < 4; ++ni)
      bfr[ni] = *(const bf16x8*)(Bs + (wn + ni * 16 + lr) * 32 + lg * 8);
#pragma unroll
    for (int mi = 0; mi < 4; ++mi)
#pragma unroll
      for (int ni = 0; ni < 4; ++ni)
        acc[mi][ni] = __builtin_amdgcn_mfma_f32_16x16x32_bf16(
            af[mi], bfr[ni], acc[mi][ni], 0, 0, 0);
    __syncthreads();
  }

#pragma unroll
  for (int mi = 0; mi < 4; ++mi) {
    const int row = m0 + wm + mi * 16 + lg * 4;
#pragma unroll
    for (int ni = 0; ni < 4; ++ni) {
      const int col = n0 + wn + ni * 16 + lr;
#pragma unroll
      for (int r = 0; r < 4; ++r) {
        const size_t idx = (size_t)(row + r) * N + col;
        const float v = acc[mi][ni][r];
        if (MODE == 0) {
          ((short*)Cout)[idx] = f2bf(v);
        } else {
          const float tt = v + bias[col];
          const float yy = fmaf(tt * tt * tt, 0.044715f, tt);
          const float e = EXP2(yy * -2.3022343813918633f);
          ((short*)Cout)[idx] = f2bf(tt / (1.0f + e));
        }
      }
    }
  }
}

// ---------------- batched-3 GEMM 128x128, MODE0 (cross-attn q/k/v) -----------
__global__ __launch_bounds__(256) void gemm_bt3(const short* __restrict__ A0,
                                                const short* __restrict__ A1,
                                                const short* __restrict__ A2,
                                                const short* __restrict__ B0,
                                                const short* __restrict__ B1,
                                                const short* __restrict__ B2,
                                                short* __restrict__ C0,
                                                short* __restrict__ C1,
                                                short* __restrict__ C2,
                                                int M, int N, int K) {
  const int z = blockIdx.z;
  const short* A  = z == 0 ? A0 : (z == 1 ? A1 : A2);
  const short* Bt = z == 0 ? B0 : (z == 1 ? B1 : B2);
  short* C        = z == 0 ? C0 : (z == 1 ? C1 : C2);

  __shared__ short As[128 * 32];
  __shared__ short Bs[128 * 32];
  const int tid = threadIdx.x;
  const int gx = gridDim.x;
  const int nwg = gx * gridDim.y;
  int lin = blockIdx.y * gx + blockIdx.x;
  lin = (lin & 7) * (nwg >> 3) + (lin >> 3);
  const int m0 = (lin / gx) * 128, n0 = (lin % gx) * 128;
  const int wave = tid >> 6, lane = tid & 63;
  const int wm = (wave >> 1) * 64, wn = (wave & 1) * 64;
  const int lr = lane & 15, lg = lane >> 4;

  f32x4 acc[4][4];
#pragma unroll
  for (int i = 0; i < 4; ++i)
#pragma unroll
    for (int j = 0; j < 4; ++j) acc[i][j] = f32x4{0.f, 0.f, 0.f, 0.f};

  const int e0 = tid * 8, e1 = 2048 + tid * 8;
  const int r0 = e0 >> 5, c0 = e0 & 31;
  const int r1 = e1 >> 5, c1 = e1 & 31;
  const size_t ar0 = (size_t)(m0 + r0) * K, ar1 = (size_t)(m0 + r1) * K;
  const size_t br0 = (size_t)(n0 + r0) * K, br1 = (size_t)(n0 + r1) * K;

  for (int k0 = 0; k0 < K; k0 += 32) {
    gload16(A + ar0 + k0 + c0, As + e0);
    gload16(A + ar1 + k0 + c1, As + e1);
    gload16(Bt + br0 + k0 + c0, Bs + e0);
    gload16(Bt + br1 + k0 + c1, Bs + e1);
    __syncthreads();
    bf16x8 af[4], bfr[4];
#pragma unroll
    for (int mi = 0; mi < 4; ++mi)
      af[mi] = *(const bf16x8*)(As + (wm + mi * 16 + lr) * 32 + lg * 8);
#pragma unroll
    for (int ni = 0; ni < 4; ++ni)
      bfr[ni] = *(const bf16x8*)(Bs + (wn + ni * 16 + lr) * 32 + lg * 8);
#pragma unroll
    for (int mi = 0; mi < 4; ++mi)
#pragma unroll
      for (int ni = 0; ni < 4; ++ni)
        acc[mi][ni] = __builtin_amdgcn_mfma_f32_16x16x32_bf16(
            af[mi], bfr[ni], acc[mi][ni], 0, 0, 0);
    __syncthreads();
  }

#pragma unroll
  for (int mi = 0; mi < 4; ++mi) {
    const int row = m0 + wm + mi * 16 + lg * 4;
#pragma unroll
    for (int ni = 0; ni < 4; ++ni) {
      const int col = n0 + wn + ni * 16 + lr;
#pragma unroll
      for (int r = 0; r < 4; ++r)
        C[(size_t)(row + r) * N + col] = f2bf(acc[mi][ni][r]);
    }
  }
}

// ---------------- GEMM 64x128 tile, bf16 delta out (512 blocks, 2/CU) --------
__global__ __launch_bounds__(256) void gemm_bt64(const short* __restrict__ A,
                                                 const short* __restrict__ Bt,
                                                 short* __restrict__ Cout,
                                                 int M, int N, int K) {
  __shared__ short As[64 * 32];
  __shared__ short Bs[128 * 32];
  const int tid = threadIdx.x;
  const int gx = gridDim.x;
  const int nwg = gx * gridDim.y;
  int lin = blockIdx.y * gx + blockIdx.x;
  lin = (lin & 7) * (nwg >> 3) + (lin >> 3);
  const int m0 = (lin / gx) * 64, n0 = (lin % gx) * 128;
  const int wave = tid >> 6, lane = tid & 63;
  const int wn = wave * 32;
  const int lr = lane & 15, lg = lane >> 4;

  f32x4 acc[4][2];
#pragma unroll
  for (int i = 0; i < 4; ++i)
#pragma unroll
    for (int j = 0; j < 2; ++j) acc[i][j] = f32x4{0.f, 0.f, 0.f, 0.f};

  const int ea = tid * 8;
  const int ra = ea >> 5, ca = ea & 31;
  const int e0 = tid * 8, e1 = 2048 + tid * 8;
  const int r0 = e0 >> 5, c0 = e0 & 31;
  const int r1 = e1 >> 5, c1 = e1 & 31;
  const size_t ar = (size_t)(m0 + ra) * K;
  const size_t br0 = (size_t)(n0 + r0) * K, br1 = (size_t)(n0 + r1) * K;

  for (int k0 = 0; k0 < K; k0 += 32) {
    gload16(A + ar + k0 + ca, As + ea);
    gload16(Bt + br0 + k0 + c0, Bs + e0);
    gload16(Bt + br1 + k0 + c1, Bs + e1);
    __syncthreads();
    bf16x8 af[4], bfr[2];
#pragma unroll
    for (int mi = 0; mi < 4; ++mi)
      af[mi] = *(const bf16x8*)(As + (mi * 16 + lr) * 32 + lg * 8);
#pragma unroll
    for (int ni = 0; ni < 2; ++ni)
      bfr[ni] = *(const bf16x8*)(Bs + (wn + ni * 16 + lr) * 32 + lg * 8);
#pragma unroll
    for (int mi = 0; mi < 4; ++mi)
#pragma unroll
      for (int ni = 0; ni < 2; ++ni)
        acc[mi][ni] = __builtin_amdgcn_mfma_f32_16x16x32_bf16(
            af[mi], bfr[ni], acc[mi][ni], 0, 0, 0);
    __syncthreads();
  }

#pragma unroll
  for (int mi = 0; mi < 4; ++mi) {
    const int row = m0 + mi * 16 + lg * 4;
#pragma unroll
    for (int ni = 0; ni < 2; ++ni) {
      const int col = n0 + wn + ni * 16 + lr;
#pragma unroll
      for (int r = 0; r < 4; ++r)
        Cout[(size_t)(row + r) * N + col] = f2bf(acc[mi][ni][r]);
    }
  }
}

// ---------------- per-head V transpose (bf16): (N x HD) -> (HD x N) ----------
__global__ __launch_bounds__(256) void vtrans(const short* __restrict__ in,
                                              short* __restrict__ out,
                                              int ldi, int N) {
  const int bh = blockIdx.z;
  const int b = bh >> 4, h = bh & 15;
  const short* ib = in + (size_t)b * N * ldi + h * HD_;
  short* ob = out + (size_t)bh * HD_ * N;
  __shared__ short t[32][33];
  const int tx = threadIdx.x, ty = threadIdx.y;
  const int n0 = blockIdx.x * 32, d0 = blockIdx.y * 32;
#pragma unroll
  for (int i = 0; i < 4; ++i)
    t[ty + i * 8][tx] = ib[(size_t)(n0 + ty + i * 8) * ldi + d0 + tx];
  __syncthreads();
#pragma unroll
  for (int i = 0; i < 4; ++i)
    ob[(size_t)(d0 + ty + i * 8) * N + n0 + tx] = t[tx][ty + i * 8];
}

// ---------------- flash attention: 64 q-rows/block, KBLK=64 ------------------
// Swapped QK^T (r6-proven): st = mfma(K,Q) = S^T; lane (lr,lg) holds
// S[q=q0+wave*16+lr][k=k0+kb*16+lg*4+r]. In-lane row-max + 2 shfl_xor.
// P->bf16 via v_cvt_pk_bf16_f32 pairs (T12 primitive; identical byte layout
// to the proven scalar pack) -> one ds_write_b64 per kb, swizzled both sides.
// Row-sum via ones-MFMA; defer-max rescale (raw THR=44 ~ P<=2^8).
__global__ __launch_bounds__(256) void flash(const short* __restrict__ Q,
                                             const short* __restrict__ Kp,
                                             const short* __restrict__ Vt,
                                             short* __restrict__ O,
                                             int ldq, int ldk, int ldo,
                                             int NK, int causal) {
  const int bh = blockIdx.x;
  int qb = blockIdx.y;
  if (causal) qb = (qb < 16) ? (2 * qb) : (63 - 2 * qb);
  const int b = bh >> 4, h = bh & 15;
  const int q0 = qb * 64;
  const int tid = threadIdx.x, wave = tid >> 6, lane = tid & 63;
  const int lr = lane & 15, lg = lane >> 4;
  const int lx = lr & 7;

  const short* Qb = Q + (size_t)b * ND_ * ldq + h * HD_;
  const short* Kb = Kp + (size_t)b * NK * ldk + h * HD_;
  const short* Vb = Vt + (size_t)bh * HD_ * NK;
  short* Ob = O + (size_t)b * ND_ * ldo + h * HD_;

  __shared__ short Ks[64 * 64];
  __shared__ short Vs[64 * 64];
  __shared__ short Ps[4][16 * 64];   // per-wave P tile, [q][k] swizzled

  const int qrow = q0 + wave * 16 + lr;
  const bf16x8 qf0 = *(const bf16x8*)(Qb + (size_t)qrow * ldq + lg * 8);
  const bf16x8 qf1 = *(const bf16x8*)(Qb + (size_t)qrow * ldq + 32 + lg * 8);

  const bf16x8 ONES = {0x3F80, 0x3F80, 0x3F80, 0x3F80,
                       0x3F80, 0x3F80, 0x3F80, 0x3F80};  // bf16 1.0 x8

  f32x4 oacc[4];
  f32x4 lacc = f32x4{0.f, 0.f, 0.f, 0.f};
  float m_own = -1e30f;
#pragma unroll
  for (int i = 0; i < 4; ++i) oacc[i] = f32x4{0.f, 0.f, 0.f, 0.f};

  const int sr0 = tid >> 3;
  const int ssw = ((tid & 7) ^ (sr0 & 7)) * 8;
  const int e0 = tid * 8, e1 = 2048 + tid * 8;

  const float SC = 0.18033688011112042f;  // 1/sqrt(64) * log2(e)

  short* Pw = &Ps[wave][0];
  const int pbase = lr * 64 + (lg & 1) * 4;

  const int nkt = causal ? (qb + 1) : (NK / 64);
  for (int t = 0; t < nkt; ++t) {
    const int k0 = t * 64;
    gload16(Kb + (size_t)(k0 + sr0) * ldk + ssw, Ks + e0);
    gload16(Kb + (size_t)(k0 + 32 + sr0) * ldk + ssw, Ks + e1);
    gload16(Vb + (size_t)sr0 * NK + k0 + ssw, Vs + e0);
    gload16(Vb + (size_t)(32 + sr0) * NK + k0 + ssw, Vs + e1);
    __syncthreads();

    f32x4 st[4];
#pragma unroll
    for (int kb = 0; kb < 4; ++kb) {
      const bf16x8 kf0 = *(const bf16x8*)(Ks + (kb * 16 + lr) * 64 + ((lg ^ lx) * 8));
      const bf16x8 kf1 = *(const bf16x8*)(Ks + (kb * 16 + lr) * 64 + (((4 + lg) ^ lx) * 8));
      st[kb] = f32x4{0.f, 0.f, 0.f, 0.f};
      st[kb] = __builtin_amdgcn_mfma_f32_16x16x32_bf16(kf0, qf0, st[kb], 0, 0, 0);
      st[kb] = __builtin_amdgcn_mfma_f32_16x16x32_bf16(kf1, qf1, st[kb], 0, 0, 0);
    }
    if (causal && t == nkt - 1) {
#pragma unroll
      for (int kb = 0; kb < 4; ++kb)
#pragma unroll
        for (int r = 0; r < 4; ++r)
          if ((k0 + kb * 16 + lg * 4 + r) > qrow) st[kb][r] = -3.0e38f;
    }

    float rm = st[0][0];
#pragma unroll
    for (int kb = 0; kb < 4; ++kb)
#pragma unroll
      for (int r = 0; r < 4; ++r)
        if (kb || r) rm = fmaxf(rm, st[kb][r]);
    rm = fmaxf(rm, __shfl_xor(rm, 16));
    rm = fmaxf(rm, __shfl_xor(rm, 32));

    if (!__all(rm - m_own <= 44.f)) {
      const float nm = fmaxf(m_own, rm);
      const float fac = EXP2((m_own - nm) * SC);
      m_own = nm;
      const float fr0 = __shfl(fac, (lg << 2) + 0);
      const float fr1 = __shfl(fac, (lg << 2) + 1);
      const float fr2 = __shfl(fac, (lg << 2) + 2);
      const float fr3 = __shfl(fac, (lg << 2) + 3);
#pragma unroll
      for (int db = 0; db < 4; ++db) {
        oacc[db][0] *= fr0; oacc[db][1] *= fr1;
        oacc[db][2] *= fr2; oacc[db][3] *= fr3;
      }
      lacc[0] *= fr0; lacc[1] *= fr1; lacc[2] *= fr2; lacc[3] *= fr3;
    }
    const float nmsc = m_own * SC;
#pragma unroll
    for (int kb = 0; kb < 4; ++kb)
#pragma unroll
      for (int r = 0; r < 4; ++r)
        st[kb][r] = EXP2(fmaf(st[kb][r], SC, -nmsc));

    // P pack via cvt_pk pairs (byte layout identical to scalar-pack path)
#pragma unroll
    for (int kb = 0; kb < 4; ++kb) {
      union { unsigned u[2]; unsigned long long ull; } pk;
      asm("v_cvt_pk_bf16_f32 %0, %1, %2"
          : "=v"(pk.u[0]) : "v"(st[kb][0]), "v"(st[kb][1]));
      asm("v_cvt_pk_bf16_f32 %0, %1, %2"
          : "=v"(pk.u[1]) : "v"(st[kb][2]), "v"(st[kb][3]));
      const int cs = kb * 2 + (lg >> 1);
      *(unsigned long long*)(Pw + pbase + ((cs ^ lx) * 8)) = pk.ull;
    }
    const bf16x8 pf0 = *(const bf16x8*)(Pw + lr * 64 + ((lg ^ lx) * 8));
    const bf16x8 pf1 = *(const bf16x8*)(Pw + lr * 64 + (((4 + lg) ^ lx) * 8));

#pragma unroll
    for (int db = 0; db < 4; ++db) {
      const bf16x8 vf0 = *(const bf16x8*)(Vs + (db * 16 + lr) * 64 + ((lg ^ lx) * 8));
      const bf16x8 vf1 = *(const bf16x8*)(Vs + (db * 16 + lr) * 64 + (((4 + lg) ^ lx) * 8));
      oacc[db] = __builtin_amdgcn_mfma_f32_16x16x32_bf16(pf0, vf0, oacc[db], 0, 0, 0);
      oacc[db] = __builtin_amdgcn_mfma_f32_16x16x32_bf16(pf1, vf1, oacc[db], 0, 0, 0);
    }
    lacc = __builtin_amdgcn_mfma_f32_16x16x32_bf16(pf0, ONES, lacc, 0, 0, 0);
    lacc = __builtin_amdgcn_mfma_f32_16x16x32_bf16(pf1, ONES, lacc, 0, 0, 0);
    __syncthreads();
  }
#pragma unroll
  for (int db = 0; db < 4; ++db)
#pragma unroll
    for (int r = 0; r < 4; ++r) {
      const int q = q0 + wave * 16 + lg * 4 + r;
      Ob[(size_t)q * ldo + db * 16 + lr] = f2bf(oacc[db][r] / lacc[r]);
    }
}

// ---------------------------------------------------------------------------
extern "C" void kernel_launch(void* const* d_in, const int* in_sizes, int n_in,
                              void* d_out, int out_size, void* d_ws, size_t ws_size,
                              hipStream_t stream) {
  const float* x      = (const float*)d_in[0];
  const float* memory = (const float*)d_in[1];
  const float* ln1_g  = (const float*)d_in[2];
  const float* ln1_b  = (const float*)d_in[3];
  const float* Wqkv   = (const float*)d_in[4];
  const float* Wo_sa  = (const float*)d_in[5];
  const float* bo_sa  = (const float*)d_in[6];
  const float* ln2_g  = (const float*)d_in[7];
  const float* ln2_b  = (const float*)d_in[8];
  const float* Wq     = (const float*)d_in[9];
  const float* Wk     = (const float*)d_in[10];
  const float* Wv     = (const float*)d_in[11];
  const float* Wo_ca  = (const float*)d_in[12];
  const float* bo_ca  = (const float*)d_in[13];
  const float* ln3_g  = (const float*)d_in[14];
  const float* ln3_b  = (const float*)d_in[15];
  const float* W1     = (const float*)d_in[16];
  const float* b1     = (const float*)d_in[17];
  const float* W2     = (const float*)d_in[18];
  const float* b2     = (const float*)d_in[19];

  char* ws = (char*)d_ws;
  size_t o = 0;
  auto alloc = [&](size_t bytes) { char* p = ws + o; o += bytes; return p; };
  short* wqkv_t = (short*)alloc((size_t)3072 * 1024 * 2);
  short* wosa_t = (short*)alloc((size_t)1024 * 1024 * 2);
  short* wq_t   = (short*)alloc((size_t)1024 * 1024 * 2);
  short* wk_t   = (short*)alloc((size_t)1024 * 1024 * 2);
  short* wv_t   = (short*)alloc((size_t)1024 * 1024 * 2);
  short* woca_t = (short*)alloc((size_t)1024 * 1024 * 2);
  short* w1_t   = (short*)alloc((size_t)4096 * 1024 * 2);
  short* w2_t   = (short*)alloc((size_t)1024 * 4096 * 2);
  short* hbf    = (short*)alloc((size_t)T_ * 1024 * 2);  // ln-out AND delta buf
  short* bufa   = (short*)alloc((size_t)T_ * 3072 * 2);
  short* vt     = (short*)alloc((size_t)32 * 64 * 2048 * 2);
  short* attn   = (short*)alloc((size_t)T_ * 1024 * 2);
  short* membf  = (short*)alloc((size_t)T_ * 1024 * 2);
  float* x1     = (float*)alloc((size_t)T_ * 1024 * 4);
  float* x2     = (float*)alloc((size_t)T_ * 1024 * 4);
  if (o > ws_size) return;

  short* ffn = bufa;  // spans bufa(24MB)+vt(8MB), both dead by then
  short* qca = bufa;
  short* kca = bufa + (size_t)T_ * 1024;
  short* vca = bufa + (size_t)2 * T_ * 1024;

  const dim3 tb(32, 8);

  // weight transposes (fp32 -> bf16, K x N -> N x K)
  wt_cast<<<dim3(3072 / 32, 1024 / 32), tb, 0, stream>>>(Wqkv, wqkv_t, 1024, 3072);
  wt_cast5<<<dim3(32, 32, 5), tb, 0, stream>>>(Wo_sa, Wq, Wk, Wv, Wo_ca,
                                               wosa_t, wq_t, wk_t, wv_t, woca_t);
  wt_cast<<<dim3(4096 / 32, 1024 / 32), tb, 0, stream>>>(W1, w1_t, 1024, 4096);
  wt_cast<<<dim3(1024 / 32, 4096 / 32), tb, 0, stream>>>(W2, w2_t, 4096, 1024);
  castf2b<<<dim3((T_ * 1024) / (256 * 4)), 256, 0, stream>>>(memory, membf);

  // --- self-attention block ---
  ln_kernel<<<dim3(T_), 256, 0, stream>>>(x, ln1_g, ln1_b, hbf);
  gemm_bt<0><<<dim3(3072 / 128, T_ / 128), 256, 0, stream>>>(
      hbf, wqkv_t, nullptr, bufa, T_, 3072, 1024);
  vtrans<<<dim3(ND_ / 32, HD_ / 32, 32), tb, 0, stream>>>(bufa + 2048, vt, 3072, ND_);
  flash<<<dim3(32, ND_ / 64), 256, 0, stream>>>(
      bufa, bufa + 1024, vt, attn, 3072, 3072, 1024, ND_, 1);
  gemm_bt64<<<dim3(1024 / 128, T_ / 64), 256, 0, stream>>>(
      attn, wosa_t, hbf, T_, 1024, 1024);                       // delta_sa -> hbf
  ln_fused<<<dim3(T_), 256, 0, stream>>>(x, hbf, bo_sa, ln2_g, ln2_b, hbf, x1);

  // --- cross-attention block ---
  gemm_bt3<<<dim3(1024 / 128, T_ / 128, 3), 256, 0, stream>>>(
      hbf, membf, membf, wq_t, wk_t, wv_t, qca, kca, vca, T_, 1024, 1024);
  vtrans<<<dim3(NE_ / 32, HD_ / 32, 32), tb, 0, stream>>>(vca, vt, 1024, NE_);
  flash<<<dim3(32, ND_ / 64), 256, 0, stream>>>(
      qca, kca, vt, attn, 1024, 1024, 1024, NE_, 0);
  gemm_bt64<<<dim3(1024 / 128, T_ / 64), 256, 0, stream>>>(
      attn, woca_t, hbf, T_, 1024, 1024);                       // delta_ca -> hbf
  ln_fused<<<dim3(T_), 256, 0, stream>>>(x1, hbf, bo_ca, ln3_g, ln3_b, hbf, x2);

  // --- FFN block ---
  gemm_bt<2><<<dim3(4096 / 128, T_ / 128), 256, 0, stream>>>(
      hbf, w1_t, b1, ffn, T_, 4096, 1024);
  gemm_bt64<<<dim3(1024 / 128, T_ / 64), 256, 0, stream>>>(
      ffn, w2_t, hbf, T_, 1024, 4096);                          // delta_ffn -> hbf
  addbias<<<dim3((T_ * 1024) / (256 * 4)), 256, 0, stream>>>(
      x2, hbf, b2, (float*)d_out);
}

// Round 8
// 411.618 us; speedup vs baseline: 1.8770x; 1.0231x over previous
//
#include <hip/hip_runtime.h>
#include <hip/hip_bf16.h>
#include <math.h>

#define B_   2
#define ND_  2048
#define NE_  2048
#define D_   1024
#define H_   16
#define HD_  64
#define DFF_ 4096
#define T_   4096   // B_*ND_ tokens

typedef __attribute__((ext_vector_type(8))) short bf16x8;
typedef __attribute__((ext_vector_type(4))) float f32x4;

#if __has_builtin(__builtin_amdgcn_exp2f)
#define EXP2(x) __builtin_amdgcn_exp2f(x)
#else
#define EXP2(x) exp2f(x)
#endif

__device__ __forceinline__ short f2bf(float f) {
  union { float f; unsigned u; } v; v.f = f;
  return (short)((v.u + 0x7FFFu + ((v.u >> 16) & 1u)) >> 16);
}
__device__ __forceinline__ float bf2f(short s) {
  union { unsigned u; float f; } v; v.u = ((unsigned)(unsigned short)s) << 16;
  return v.f;
}

typedef const __attribute__((address_space(1))) void gvoid_t;
typedef __attribute__((address_space(3))) void lvoid_t;

__device__ __forceinline__ void gload16(const void* src, void* dst) {
  __builtin_amdgcn_global_load_lds((gvoid_t*)src, (lvoid_t*)dst, 16, 0, 0);
}

// ---------------- weight transpose + cast: fp32 (K x N) -> bf16 (N x K) ------
__global__ __launch_bounds__(256) void wt_cast(const float* __restrict__ in,
                                               short* __restrict__ out,
                                               int K, int N) {
  __shared__ float t[32][33];
  const int tx = threadIdx.x, ty = threadIdx.y;
  const int n0 = blockIdx.x * 32, k0 = blockIdx.y * 32;
#pragma unroll
  for (int i = 0; i < 4; ++i)
    t[ty + i * 8][tx] = in[(size_t)(k0 + ty + i * 8) * N + n0 + tx];
  __syncthreads();
#pragma unroll
  for (int i = 0; i < 4; ++i)
    out[(size_t)(n0 + ty + i * 8) * K + k0 + tx] = f2bf(t[tx][ty + i * 8]);
}

// ---------------- batched-5 1024x1024 weight transpose + cast ----------------
__global__ __launch_bounds__(256) void wt_cast5(const float* __restrict__ i0,
                                                const float* __restrict__ i1,
                                                const float* __restrict__ i2,
                                                const float* __restrict__ i3,
                                                const float* __restrict__ i4,
                                                short* __restrict__ o0,
                                                short* __restrict__ o1,
                                                short* __restrict__ o2,
                                                short* __restrict__ o3,
                                                short* __restrict__ o4) {
  const int z = blockIdx.z;
  const float* in = z == 0 ? i0 : z == 1 ? i1 : z == 2 ? i2 : z == 3 ? i3 : i4;
  short* out      = z == 0 ? o0 : z == 1 ? o1 : z == 2 ? o2 : z == 3 ? o3 : o4;
  __shared__ float t[32][33];
  const int tx = threadIdx.x, ty = threadIdx.y;
  const int n0 = blockIdx.x * 32, k0 = blockIdx.y * 32;
#pragma unroll
  for (int i = 0; i < 4; ++i)
    t[ty + i * 8][tx] = in[(size_t)(k0 + ty + i * 8) * 1024 + n0 + tx];
  __syncthreads();
#pragma unroll
  for (int i = 0; i < 4; ++i)
    out[(size_t)(n0 + ty + i * 8) * 1024 + k0 + tx] = f2bf(t[tx][ty + i * 8]);
}

// ---------------- elementwise cast fp32 -> bf16 ------------------------------
__global__ __launch_bounds__(256) void castf2b(const float* __restrict__ in,
                                               short* __restrict__ out) {
  const int i = blockIdx.x * 256 + threadIdx.x;
  float4 v = ((const float4*)in)[i];
  short4 o;
  o.x = f2bf(v.x); o.y = f2bf(v.y); o.z = f2bf(v.z); o.w = f2bf(v.w);
  ((short4*)out)[i] = o;
}

// ---------------- LayerNorm (row of 1024) fp32 -> bf16 -----------------------
__global__ __launch_bounds__(256) void ln_kernel(const float* __restrict__ x,
                                                 const float* __restrict__ g,
                                                 const float* __restrict__ b,
                                                 short* __restrict__ out) {
  const int row = blockIdx.x;
  const int tid = threadIdx.x;
  const float* xr = x + (size_t)row * D_;
  float4 v = reinterpret_cast<const float4*>(xr)[tid];
  float s  = v.x + v.y + v.z + v.w;
  float s2 = v.x * v.x + v.y * v.y + v.z * v.z + v.w * v.w;
#pragma unroll
  for (int m = 1; m < 64; m <<= 1) {
    s  += __shfl_xor(s, m);
    s2 += __shfl_xor(s2, m);
  }
  __shared__ float ss[4], ss2[4];
  const int w = tid >> 6;
  if ((tid & 63) == 0) { ss[w] = s; ss2[w] = s2; }
  __syncthreads();
  s  = ss[0] + ss[1] + ss[2] + ss[3];
  s2 = ss2[0] + ss2[1] + ss2[2] + ss2[3];
  const float mu   = s * (1.0f / D_);
  const float var  = s2 * (1.0f / D_) - mu * mu;
  const float rstd = rsqrtf(var + 1e-5f);
  float4 gv = reinterpret_cast<const float4*>(g)[tid];
  float4 bv = reinterpret_cast<const float4*>(b)[tid];
  short4 o;
  o.x = f2bf((v.x - mu) * rstd * gv.x + bv.x);
  o.y = f2bf((v.y - mu) * rstd * gv.y + bv.y);
  o.z = f2bf((v.z - mu) * rstd * gv.z + bv.z);
  o.w = f2bf((v.w - mu) * rstd * gv.w + bv.w);
  reinterpret_cast<short4*>(out + (size_t)row * D_)[tid] = o;
}

// ---------------- fused residual + bias + LayerNorm --------------------------
// xnew = xprev + delta(bf16) + pbias; writes xnew (fp32) and LN(xnew) (bf16).
// NOTE: delta may alias out_ln (per-thread read-then-write, same address).
__global__ __launch_bounds__(256) void ln_fused(const float* __restrict__ xprev,
                                                const short* delta,
                                                const float* __restrict__ pbias,
                                                const float* __restrict__ g,
                                                const float* __restrict__ b,
                                                short* out_ln,
                                                float* __restrict__ out_x) {
  const int row = blockIdx.x;
  const int tid = threadIdx.x;
  float4 v = reinterpret_cast<const float4*>(xprev + (size_t)row * D_)[tid];
  short4 dv = reinterpret_cast<const short4*>(delta + (size_t)row * D_)[tid];
  float4 pb = reinterpret_cast<const float4*>(pbias)[tid];
  v.x += bf2f(dv.x) + pb.x;
  v.y += bf2f(dv.y) + pb.y;
  v.z += bf2f(dv.z) + pb.z;
  v.w += bf2f(dv.w) + pb.w;
  float s  = v.x + v.y + v.z + v.w;
  float s2 = v.x * v.x + v.y * v.y + v.z * v.z + v.w * v.w;
#pragma unroll
  for (int m = 1; m < 64; m <<= 1) {
    s  += __shfl_xor(s, m);
    s2 += __shfl_xor(s2, m);
  }
  __shared__ float ss[4], ss2[4];
  const int w = tid >> 6;
  if ((tid & 63) == 0) { ss[w] = s; ss2[w] = s2; }
  __syncthreads();
  s  = ss[0] + ss[1] + ss[2] + ss[3];
  s2 = ss2[0] + ss2[1] + ss2[2] + ss2[3];
  const float mu   = s * (1.0f / D_);
  const float var  = s2 * (1.0f / D_) - mu * mu;
  const float rstd = rsqrtf(var + 1e-5f);
  reinterpret_cast<float4*>(out_x + (size_t)row * D_)[tid] = v;
  float4 gv = reinterpret_cast<const float4*>(g)[tid];
  float4 bv = reinterpret_cast<const float4*>(b)[tid];
  short4 o;
  o.x = f2bf((v.x - mu) * rstd * gv.x + bv.x);
  o.y = f2bf((v.y - mu) * rstd * gv.y + bv.y);
  o.z = f2bf((v.z - mu) * rstd * gv.z + bv.z);
  o.w = f2bf((v.w - mu) * rstd * gv.w + bv.w);
  reinterpret_cast<short4*>(out_ln + (size_t)row * D_)[tid] = o;
}

// ---------------- final residual + bias add: out = x + delta + bias ----------
__global__ __launch_bounds__(256) void addbias(const float* __restrict__ x,
                                               const short* __restrict__ delta,
                                               const float* __restrict__ bias,
                                               float* __restrict__ out) {
  const int i = blockIdx.x * 256 + threadIdx.x;
  float4 v = ((const float4*)x)[i];
  short4 dv = ((const short4*)delta)[i];
  const int col = (i * 4) & (D_ - 1);
  float4 pb = *(const float4*)(bias + col);
  v.x += bf2f(dv.x) + pb.x;
  v.y += bf2f(dv.y) + pb.y;
  v.z += bf2f(dv.z) + pb.z;
  v.w += bf2f(dv.w) + pb.w;
  ((float4*)out)[i] = v;
}

// ---------------- GEMM 128x128: C(MxN) = A(MxK,bf16) * Bt(NxK,bf16)^T --------
// MODE 0: store bf16.  MODE 2: bf16 out = gelu(acc + bias) (tanh-sigmoid).
template <int MODE>
__global__ __launch_bounds__(256) void gemm_bt(const short* __restrict__ A,
                                               const short* __restrict__ Bt,
                                               const float* __restrict__ bias,
                                               void* __restrict__ Cout,
                                               int M, int N, int K) {
  __shared__ short As[128 * 32];
  __shared__ short Bs[128 * 32];
  const int tid = threadIdx.x;
  const int gx = gridDim.x;
  const int nwg = gx * gridDim.y;
  int lin = blockIdx.y * gx + blockIdx.x;
  lin = (lin & 7) * (nwg >> 3) + (lin >> 3);
  const int m0 = (lin / gx) * 128, n0 = (lin % gx) * 128;
  const int wave = tid >> 6, lane = tid & 63;
  const int wm = (wave >> 1) * 64, wn = (wave & 1) * 64;
  const int lr = lane & 15, lg = lane >> 4;

  f32x4 acc[4][4];
#pragma unroll
  for (int i = 0; i < 4; ++i)
#pragma unroll
    for (int j = 0; j < 4; ++j) acc[i][j] = f32x4{0.f, 0.f, 0.f, 0.f};

  const int e0 = tid * 8, e1 = 2048 + tid * 8;
  const int r0 = e0 >> 5, c0 = e0 & 31;
  const int r1 = e1 >> 5, c1 = e1 & 31;
  const size_t ar0 = (size_t)(m0 + r0) * K, ar1 = (size_t)(m0 + r1) * K;
  const size_t br0 = (size_t)(n0 + r0) * K, br1 = (size_t)(n0 + r1) * K;

  for (int k0 = 0; k0 < K; k0 += 32) {
    gload16(A + ar0 + k0 + c0, As + e0);
    gload16(A + ar1 + k0 + c1, As + e1);
    gload16(Bt + br0 + k0 + c0, Bs + e0);
    gload16(Bt + br1 + k0 + c1, Bs + e1);
    __syncthreads();
    bf16x8 af[4], bfr[4];
#pragma unroll
    for (int mi = 0; mi < 4; ++mi)
      af[mi] = *(const bf16x8*)(As + (wm + mi * 16 + lr) * 32 + lg * 8);
#pragma unroll
    for (int ni = 0; ni < 4; ++ni)
      bfr[ni] = *(const bf16x8*)(Bs + (wn + ni * 16 + lr) * 32 + lg * 8);
#pragma unroll
    for (int mi = 0; mi < 4; ++mi)
#pragma unroll
      for (int ni = 0; ni < 4; ++ni)
        acc[mi][ni] = __builtin_amdgcn_mfma_f32_16x16x32_bf16(
            af[mi], bfr[ni], acc[mi][ni], 0, 0, 0);
    __syncthreads();
  }

#pragma unroll
  for (int mi = 0; mi < 4; ++mi) {
    const int row = m0 + wm + mi * 16 + lg * 4;
#pragma unroll
    for (int ni = 0; ni < 4; ++ni) {
      const int col = n0 + wn + ni * 16 + lr;
#pragma unroll
      for (int r = 0; r < 4; ++r) {
        const size_t idx = (size_t)(row + r) * N + col;
        const float v = acc[mi][ni][r];
        if (MODE == 0) {
          ((short*)Cout)[idx] = f2bf(v);
        } else {
          const float tt = v + bias[col];
          const float yy = fmaf(tt * tt * tt, 0.044715f, tt);
          const float e = EXP2(yy * -2.3022343813918633f);
          ((short*)Cout)[idx] = f2bf(tt / (1.0f + e));
        }
      }
    }
  }
}

// ---------------- batched-3 GEMM 128x128, MODE0 (cross-attn q/k/v) -----------
__global__ __launch_bounds__(256) void gemm_bt3(const short* __restrict__ A0,
                                                const short* __restrict__ A1,
                                                const short* __restrict__ A2,
                                                const short* __restrict__ B0,
                                                const short* __restrict__ B1,
                                                const short* __restrict__ B2,
                                                short* __restrict__ C0,
                                                short* __restrict__ C1,
                                                short* __restrict__ C2,
                                                int M, int N, int K) {
  const int z = blockIdx.z;
  const short* A  = z == 0 ? A0 : (z == 1 ? A1 : A2);
  const short* Bt = z == 0 ? B0 : (z == 1 ? B1 : B2);
  short* C        = z == 0 ? C0 : (z == 1 ? C1 : C2);

  __shared__ short As[128 * 32];
  __shared__ short Bs[128 * 32];
  const int tid = threadIdx.x;
  const int gx = gridDim.x;
  const int nwg = gx * gridDim.y;
  int lin = blockIdx.y * gx + blockIdx.x;
  lin = (lin & 7) * (nwg >> 3) + (lin >> 3);
  const int m0 = (lin / gx) * 128, n0 = (lin % gx) * 128;
  const int wave = tid >> 6, lane = tid & 63;
  const int wm = (wave >> 1) * 64, wn = (wave & 1) * 64;
  const int lr = lane & 15, lg = lane >> 4;

  f32x4 acc[4][4];
#pragma unroll
  for (int i = 0; i < 4; ++i)
#pragma unroll
    for (int j = 0; j < 4; ++j) acc[i][j] = f32x4{0.f, 0.f, 0.f, 0.f};

  const int e0 = tid * 8, e1 = 2048 + tid * 8;
  const int r0 = e0 >> 5, c0 = e0 & 31;
  const int r1 = e1 >> 5, c1 = e1 & 31;
  const size_t ar0 = (size_t)(m0 + r0) * K, ar1 = (size_t)(m0 + r1) * K;
  const size_t br0 = (size_t)(n0 + r0) * K, br1 = (size_t)(n0 + r1) * K;

  for (int k0 = 0; k0 < K; k0 += 32) {
    gload16(A + ar0 + k0 + c0, As + e0);
    gload16(A + ar1 + k0 + c1, As + e1);
    gload16(Bt + br0 + k0 + c0, Bs + e0);
    gload16(Bt + br1 + k0 + c1, Bs + e1);
    __syncthreads();
    bf16x8 af[4], bfr[4];
#pragma unroll
    for (int mi = 0; mi < 4; ++mi)
      af[mi] = *(const bf16x8*)(As + (wm + mi * 16 + lr) * 32 + lg * 8);
#pragma unroll
    for (int ni = 0; ni < 4; ++ni)
      bfr[ni] = *(const bf16x8*)(Bs + (wn + ni * 16 + lr) * 32 + lg * 8);
#pragma unroll
    for (int mi = 0; mi < 4; ++mi)
#pragma unroll
      for (int ni = 0; ni < 4; ++ni)
        acc[mi][ni] = __builtin_amdgcn_mfma_f32_16x16x32_bf16(
            af[mi], bfr[ni], acc[mi][ni], 0, 0, 0);
    __syncthreads();
  }

#pragma unroll
  for (int mi = 0; mi < 4; ++mi) {
    const int row = m0 + wm + mi * 16 + lg * 4;
#pragma unroll
    for (int ni = 0; ni < 4; ++ni) {
      const int col = n0 + wn + ni * 16 + lr;
#pragma unroll
      for (int r = 0; r < 4; ++r)
        C[(size_t)(row + r) * N + col] = f2bf(acc[mi][ni][r]);
    }
  }
}

// ---------------- GEMM 64x128 tile, bf16 delta out, 2-phase double-buffer ----
// Issue next k-tile's global_load_lds BEFORE computing current tile; the
// barrier's implicit vmcnt(0) then lands ~compute-time after issue (T3 min).
__global__ __launch_bounds__(256) void gemm_bt64(const short* __restrict__ A,
                                                 const short* __restrict__ Bt,
                                                 short* __restrict__ Cout,
                                                 int M, int N, int K) {
  __shared__ short As[2][64 * 32];
  __shared__ short Bs[2][128 * 32];
  const int tid = threadIdx.x;
  const int gx = gridDim.x;
  const int nwg = gx * gridDim.y;
  int lin = blockIdx.y * gx + blockIdx.x;
  lin = (lin & 7) * (nwg >> 3) + (lin >> 3);
  const int m0 = (lin / gx) * 64, n0 = (lin % gx) * 128;
  const int wave = tid >> 6, lane = tid & 63;
  const int wn = wave * 32;
  const int lr = lane & 15, lg = lane >> 4;

  f32x4 acc[4][2];
#pragma unroll
  for (int i = 0; i < 4; ++i)
#pragma unroll
    for (int j = 0; j < 2; ++j) acc[i][j] = f32x4{0.f, 0.f, 0.f, 0.f};

  const int ea = tid * 8;
  const int ra = ea >> 5, ca = ea & 31;
  const int e0 = tid * 8, e1 = 2048 + tid * 8;
  const int r0 = e0 >> 5, c0 = e0 & 31;
  const int r1 = e1 >> 5, c1 = e1 & 31;
  const size_t ar = (size_t)(m0 + ra) * K;
  const size_t br0 = (size_t)(n0 + r0) * K, br1 = (size_t)(n0 + r1) * K;

  auto stage = [&](int buf, int k0) {
    gload16(A + ar + k0 + ca, &As[buf][0] + ea);
    gload16(Bt + br0 + k0 + c0, &Bs[buf][0] + e0);
    gload16(Bt + br1 + k0 + c1, &Bs[buf][0] + e1);
  };

  stage(0, 0);
  __syncthreads();
  int cur = 0;
  for (int k0 = 0; k0 < K; k0 += 32) {
    if (k0 + 32 < K) stage(cur ^ 1, k0 + 32);
    const short* Ab = &As[cur][0];
    const short* Bb = &Bs[cur][0];
    bf16x8 af[4], bfr[2];
#pragma unroll
    for (int mi = 0; mi < 4; ++mi)
      af[mi] = *(const bf16x8*)(Ab + (mi * 16 + lr) * 32 + lg * 8);
#pragma unroll
    for (int ni = 0; ni < 2; ++ni)
      bfr[ni] = *(const bf16x8*)(Bb + (wn + ni * 16 + lr) * 32 + lg * 8);
#pragma unroll
    for (int mi = 0; mi < 4; ++mi)
#pragma unroll
      for (int ni = 0; ni < 2; ++ni)
        acc[mi][ni] = __builtin_amdgcn_mfma_f32_16x16x32_bf16(
            af[mi], bfr[ni], acc[mi][ni], 0, 0, 0);
    __syncthreads();
    cur ^= 1;
  }

#pragma unroll
  for (int mi = 0; mi < 4; ++mi) {
    const int row = m0 + mi * 16 + lg * 4;
#pragma unroll
    for (int ni = 0; ni < 2; ++ni) {
      const int col = n0 + wn + ni * 16 + lr;
#pragma unroll
      for (int r = 0; r < 4; ++r)
        Cout[(size_t)(row + r) * N + col] = f2bf(acc[mi][ni][r]);
    }
  }
}

// ---------------- per-head V transpose (bf16): (N x HD) -> (HD x N) ----------
__global__ __launch_bounds__(256) void vtrans(const short* __restrict__ in,
                                              short* __restrict__ out,
                                              int ldi, int N) {
  const int bh = blockIdx.z;
  const int b = bh >> 4, h = bh & 15;
  const short* ib = in + (size_t)b * N * ldi + h * HD_;
  short* ob = out + (size_t)bh * HD_ * N;
  __shared__ short t[32][33];
  const int tx = threadIdx.x, ty = threadIdx.y;
  const int n0 = blockIdx.x * 32, d0 = blockIdx.y * 32;
#pragma unroll
  for (int i = 0; i < 4; ++i)
    t[ty + i * 8][tx] = ib[(size_t)(n0 + ty + i * 8) * ldi + d0 + tx];
  __syncthreads();
#pragma unroll
  for (int i = 0; i < 4; ++i)
    ob[(size_t)(d0 + ty + i * 8) * N + n0 + tx] = t[tx][ty + i * 8];
}

// ---------------- flash attention: 64 q-rows/block, KBLK=64, 2-phase dbuf ----
// Swapped QK^T (r6-proven). K/V double-buffered: next tile's loads issue
// before current tile's compute; long compute (18 MFMA + softmax) hides HBM.
__global__ __launch_bounds__(256) void flash(const short* __restrict__ Q,
                                             const short* __restrict__ Kp,
                                             const short* __restrict__ Vt,
                                             short* __restrict__ O,
                                             int ldq, int ldk, int ldo,
                                             int NK, int causal) {
  const int bh = blockIdx.x;
  int qb = blockIdx.y;
  if (causal) qb = (qb < 16) ? (2 * qb) : (63 - 2 * qb);
  const int b = bh >> 4, h = bh & 15;
  const int q0 = qb * 64;
  const int tid = threadIdx.x, wave = tid >> 6, lane = tid & 63;
  const int lr = lane & 15, lg = lane >> 4;
  const int lx = lr & 7;

  const short* Qb = Q + (size_t)b * ND_ * ldq + h * HD_;
  const short* Kb = Kp + (size_t)b * NK * ldk + h * HD_;
  const short* Vb = Vt + (size_t)bh * HD_ * NK;
  short* Ob = O + (size_t)b * ND_ * ldo + h * HD_;

  __shared__ short Ks[2][64 * 64];
  __shared__ short Vs[2][64 * 64];
  __shared__ short Ps[4][16 * 64];   // per-wave P tile, [q][k] swizzled

  const int qrow = q0 + wave * 16 + lr;
  const bf16x8 qf0 = *(const bf16x8*)(Qb + (size_t)qrow * ldq + lg * 8);
  const bf16x8 qf1 = *(const bf16x8*)(Qb + (size_t)qrow * ldq + 32 + lg * 8);

  const bf16x8 ONES = {0x3F80, 0x3F80, 0x3F80, 0x3F80,
                       0x3F80, 0x3F80, 0x3F80, 0x3F80};  // bf16 1.0 x8

  f32x4 oacc[4];
  f32x4 lacc = f32x4{0.f, 0.f, 0.f, 0.f};
  float m_own = -1e30f;
#pragma unroll
  for (int i = 0; i < 4; ++i) oacc[i] = f32x4{0.f, 0.f, 0.f, 0.f};

  const int sr0 = tid >> 3;
  const int ssw = ((tid & 7) ^ (sr0 & 7)) * 8;
  const int e0 = tid * 8, e1 = 2048 + tid * 8;

  const float SC = 0.18033688011112042f;  // 1/sqrt(64) * log2(e)

  short* Pw = &Ps[wave][0];
  const int pbase = lr * 64 + (lg & 1) * 4;

  auto stage = [&](int buf, int k0) {
    gload16(Kb + (size_t)(k0 + sr0) * ldk + ssw, &Ks[buf][0] + e0);
    gload16(Kb + (size_t)(k0 + 32 + sr0) * ldk + ssw, &Ks[buf][0] + e1);
    gload16(Vb + (size_t)sr0 * NK + k0 + ssw, &Vs[buf][0] + e0);
    gload16(Vb + (size_t)(32 + sr0) * NK + k0 + ssw, &Vs[buf][0] + e1);
  };

  const int nkt = causal ? (qb + 1) : (NK / 64);
  stage(0, 0);
  __syncthreads();
  int cur = 0;
  for (int t = 0; t < nkt; ++t) {
    const int k0 = t * 64;
    if (t + 1 < nkt) stage(cur ^ 1, k0 + 64);
    const short* Ksb = &Ks[cur][0];
    const short* Vsb = &Vs[cur][0];

    f32x4 st[4];
#pragma unroll
    for (int kb = 0; kb < 4; ++kb) {
      const bf16x8 kf0 = *(const bf16x8*)(Ksb + (kb * 16 + lr) * 64 + ((lg ^ lx) * 8));
      const bf16x8 kf1 = *(const bf16x8*)(Ksb + (kb * 16 + lr) * 64 + (((4 + lg) ^ lx) * 8));
      st[kb] = f32x4{0.f, 0.f, 0.f, 0.f};
      st[kb] = __builtin_amdgcn_mfma_f32_16x16x32_bf16(kf0, qf0, st[kb], 0, 0, 0);
      st[kb] = __builtin_amdgcn_mfma_f32_16x16x32_bf16(kf1, qf1, st[kb], 0, 0, 0);
    }
    if (causal && t == nkt - 1) {
#pragma unroll
      for (int kb = 0; kb < 4; ++kb)
#pragma unroll
        for (int r = 0; r < 4; ++r)
          if ((k0 + kb * 16 + lg * 4 + r) > qrow) st[kb][r] = -3.0e38f;
    }

    float rm = st[0][0];
#pragma unroll
    for (int kb = 0; kb < 4; ++kb)
#pragma unroll
      for (int r = 0; r < 4; ++r)
        if (kb || r) rm = fmaxf(rm, st[kb][r]);
    rm = fmaxf(rm, __shfl_xor(rm, 16));
    rm = fmaxf(rm, __shfl_xor(rm, 32));

    if (!__all(rm - m_own <= 44.f)) {
      const float nm = fmaxf(m_own, rm);
      const float fac = EXP2((m_own - nm) * SC);
      m_own = nm;
      const float fr0 = __shfl(fac, (lg << 2) + 0);
      const float fr1 = __shfl(fac, (lg << 2) + 1);
      const float fr2 = __shfl(fac, (lg << 2) + 2);
      const float fr3 = __shfl(fac, (lg << 2) + 3);
#pragma unroll
      for (int db = 0; db < 4; ++db) {
        oacc[db][0] *= fr0; oacc[db][1] *= fr1;
        oacc[db][2] *= fr2; oacc[db][3] *= fr3;
      }
      lacc[0] *= fr0; lacc[1] *= fr1; lacc[2] *= fr2; lacc[3] *= fr3;
    }
    const float nmsc = m_own * SC;
#pragma unroll
    for (int kb = 0; kb < 4; ++kb)
#pragma unroll
      for (int r = 0; r < 4; ++r)
        st[kb][r] = EXP2(fmaf(st[kb][r], SC, -nmsc));

    // P pack via cvt_pk pairs (byte layout identical to scalar-pack path)
#pragma unroll
    for (int kb = 0; kb < 4; ++kb) {
      union { unsigned u[2]; unsigned long long ull; } pk;
      asm("v_cvt_pk_bf16_f32 %0, %1, %2"
          : "=v"(pk.u[0]) : "v"(st[kb][0]), "v"(st[kb][1]));
      asm("v_cvt_pk_bf16_f32 %0, %1, %2"
          : "=v"(pk.u[1]) : "v"(st[kb][2]), "v"(st[kb][3]));
      const int cs = kb * 2 + (lg >> 1);
      *(unsigned long long*)(Pw + pbase + ((cs ^ lx) * 8)) = pk.ull;
    }
    const bf16x8 pf0 = *(const bf16x8*)(Pw + lr * 64 + ((lg ^ lx) * 8));
    const bf16x8 pf1 = *(const bf16x8*)(Pw + lr * 64 + (((4 + lg) ^ lx) * 8));

#pragma unroll
    for (int db = 0; db < 4; ++db) {
      const bf16x8 vf0 = *(const bf16x8*)(Vsb + (db * 16 + lr) * 64 + ((lg ^ lx) * 8));
      const bf16x8 vf1 = *(const bf16x8*)(Vsb + (db * 16 + lr) * 64 + (((4 + lg) ^ lx) * 8));
      oacc[db] = __builtin_amdgcn_mfma_f32_16x16x32_bf16(pf0, vf0, oacc[db], 0, 0, 0);
      oacc[db] = __builtin_amdgcn_mfma_f32_16x16x32_bf16(pf1, vf1, oacc[db], 0, 0, 0);
    }
    lacc = __builtin_amdgcn_mfma_f32_16x16x32_bf16(pf0, ONES, lacc, 0, 0, 0);
    lacc = __builtin_amdgcn_mfma_f32_16x16x32_bf16(pf1, ONES, lacc, 0, 0, 0);
    __syncthreads();
    cur ^= 1;
  }
#pragma unroll
  for (int db = 0; db < 4; ++db)
#pragma unroll
    for (int r = 0; r < 4; ++r) {
      const int q = q0 + wave * 16 + lg * 4 + r;
      Ob[(size_t)q * ldo + db * 16 + lr] = f2bf(oacc[db][r] / lacc[r]);
    }
}

// ---------------------------------------------------------------------------
extern "C" void kernel_launch(void* const* d_in, const int* in_sizes, int n_in,
                              void* d_out, int out_size, void* d_ws, size_t ws_size,
                              hipStream_t stream) {
  const float* x      = (const float*)d_in[0];
  const float* memory = (const float*)d_in[1];
  const float* ln1_g  = (const float*)d_in[2];
  const float* ln1_b  = (const float*)d_in[3];
  const float* Wqkv   = (const float*)d_in[4];
  const float* Wo_sa  = (const float*)d_in[5];
  const float* bo_sa  = (const float*)d_in[6];
  const float* ln2_g  = (const float*)d_in[7];
  const float* ln2_b  = (const float*)d_in[8];
  const float* Wq     = (const float*)d_in[9];
  const float* Wk     = (const float*)d_in[10];
  const float* Wv     = (const float*)d_in[11];
  const float* Wo_ca  = (const float*)d_in[12];
  const float* bo_ca  = (const float*)d_in[13];
  const float* ln3_g  = (const float*)d_in[14];
  const float* ln3_b  = (const float*)d_in[15];
  const float* W1     = (const float*)d_in[16];
  const float* b1     = (const float*)d_in[17];
  const float* W2     = (const float*)d_in[18];
  const float* b2     = (const float*)d_in[19];

  char* ws = (char*)d_ws;
  size_t o = 0;
  auto alloc = [&](size_t bytes) { char* p = ws + o; o += bytes; return p; };
  short* wqkv_t = (short*)alloc((size_t)3072 * 1024 * 2);
  short* wosa_t = (short*)alloc((size_t)1024 * 1024 * 2);
  short* wq_t   = (short*)alloc((size_t)1024 * 1024 * 2);
  short* wk_t   = (short*)alloc((size_t)1024 * 1024 * 2);
  short* wv_t   = (short*)alloc((size_t)1024 * 1024 * 2);
  short* woca_t = (short*)alloc((size_t)1024 * 1024 * 2);
  short* w1_t   = (short*)alloc((size_t)4096 * 1024 * 2);
  short* w2_t   = (short*)alloc((size_t)1024 * 4096 * 2);
  short* hbf    = (short*)alloc((size_t)T_ * 1024 * 2);  // ln-out AND delta buf
  short* bufa   = (short*)alloc((size_t)T_ * 3072 * 2);
  short* vt     = (short*)alloc((size_t)32 * 64 * 2048 * 2);
  short* attn   = (short*)alloc((size_t)T_ * 1024 * 2);
  short* membf  = (short*)alloc((size_t)T_ * 1024 * 2);
  float* x1     = (float*)alloc((size_t)T_ * 1024 * 4);
  float* x2     = (float*)alloc((size_t)T_ * 1024 * 4);
  if (o > ws_size) return;

  short* ffn = bufa;  // spans bufa(24MB)+vt(8MB), both dead by then
  short* qca = bufa;
  short* kca = bufa + (size_t)T_ * 1024;
  short* vca = bufa + (size_t)2 * T_ * 1024;

  const dim3 tb(32, 8);

  // weight transposes (fp32 -> bf16, K x N -> N x K)
  wt_cast<<<dim3(3072 / 32, 1024 / 32), tb, 0, stream>>>(Wqkv, wqkv_t, 1024, 3072);
  wt_cast5<<<dim3(32, 32, 5), tb, 0, stream>>>(Wo_sa, Wq, Wk, Wv, Wo_ca,
                                               wosa_t, wq_t, wk_t, wv_t, woca_t);
  wt_cast<<<dim3(4096 / 32, 1024 / 32), tb, 0, stream>>>(W1, w1_t, 1024, 4096);
  wt_cast<<<dim3(1024 / 32, 4096 / 32), tb, 0, stream>>>(W2, w2_t, 4096, 1024);
  castf2b<<<dim3((T_ * 1024) / (256 * 4)), 256, 0, stream>>>(memory, membf);

  // --- self-attention block ---
  ln_kernel<<<dim3(T_), 256, 0, stream>>>(x, ln1_g, ln1_b, hbf);
  gemm_bt<0><<<dim3(3072 / 128, T_ / 128), 256, 0, stream>>>(
      hbf, wqkv_t, nullptr, bufa, T_, 3072, 1024);
  vtrans<<<dim3(ND_ / 32, HD_ / 32, 32), tb, 0, stream>>>(bufa + 2048, vt, 3072, ND_);
  flash<<<dim3(32, ND_ / 64), 256, 0, stream>>>(
      bufa, bufa + 1024, vt, attn, 3072, 3072, 1024, ND_, 1);
  gemm_bt64<<<dim3(1024 / 128, T_ / 64), 256, 0, stream>>>(
      attn, wosa_t, hbf, T_, 1024, 1024);                       // delta_sa -> hbf
  ln_fused<<<dim3(T_), 256, 0, stream>>>(x, hbf, bo_sa, ln2_g, ln2_b, hbf, x1);

  // --- cross-attention block ---
  gemm_bt3<<<dim3(1024 / 128, T_ / 128, 3), 256, 0, stream>>>(
      hbf, membf, membf, wq_t, wk_t, wv_t, qca, kca, vca, T_, 1024, 1024);
  vtrans<<<dim3(NE_ / 32, HD_ / 32, 32), tb, 0, stream>>>(vca, vt, 1024, NE_);
  flash<<<dim3(32, ND_ / 64), 256, 0, stream>>>(
      qca, kca, vt, attn, 1024, 1024, 1024, NE_, 0);
  gemm_bt64<<<dim3(1024 / 128, T_ / 64), 256, 0, stream>>>(
      attn, woca_t, hbf, T_, 1024, 1024);                       // delta_ca -> hbf
  ln_fused<<<dim3(T_), 256, 0, stream>>>(x1, hbf, bo_ca, ln3_g, ln3_b, hbf, x2);

  // --- FFN block ---
  gemm_bt<2><<<dim3(4096 / 128, T_ / 128), 256, 0, stream>>>(
      hbf, w1_t, b1, ffn, T_, 4096, 1024);
  gemm_bt64<<<dim3(1024 / 128, T_ / 64), 256, 0, stream>>>(
      ffn, w2_t, hbf, T_, 1024, 4096);                          // delta_ffn -> hbf
  addbias<<<dim3((T_ * 1024) / (256 * 4)), 256, 0, stream>>>(
      x2, hbf, b2, (float*)d_out);
}

// Round 9
// 387.921 us; speedup vs baseline: 1.9917x; 1.0611x over previous
//
#include <hip/hip_runtime.h>
#include <hip/hip_bf16.h>
#include <math.h>

#define B_   2
#define ND_  2048
#define NE_  2048
#define D_   1024
#define H_   16
#define HD_  64
#define DFF_ 4096
#define T_   4096   // B_*ND_ tokens

typedef __attribute__((ext_vector_type(8))) short bf16x8;
typedef __attribute__((ext_vector_type(4))) float f32x4;

#if __has_builtin(__builtin_amdgcn_exp2f)
#define EXP2(x) __builtin_amdgcn_exp2f(x)
#else
#define EXP2(x) exp2f(x)
#endif

__device__ __forceinline__ short f2bf(float f) {
  union { float f; unsigned u; } v; v.f = f;
  return (short)((v.u + 0x7FFFu + ((v.u >> 16) & 1u)) >> 16);
}
__device__ __forceinline__ float bf2f(short s) {
  union { unsigned u; float f; } v; v.u = ((unsigned)(unsigned short)s) << 16;
  return v.f;
}

typedef const __attribute__((address_space(1))) void gvoid_t;
typedef __attribute__((address_space(3))) void lvoid_t;

__device__ __forceinline__ void gload16(const void* src, void* dst) {
  __builtin_amdgcn_global_load_lds((gvoid_t*)src, (lvoid_t*)dst, 16, 0, 0);
}

// ---------------- weight transpose + cast: fp32 (K x N) -> bf16 (N x K) ------
__global__ __launch_bounds__(256) void wt_cast(const float* __restrict__ in,
                                               short* __restrict__ out,
                                               int K, int N) {
  __shared__ float t[32][33];
  const int tx = threadIdx.x, ty = threadIdx.y;
  const int n0 = blockIdx.x * 32, k0 = blockIdx.y * 32;
#pragma unroll
  for (int i = 0; i < 4; ++i)
    t[ty + i * 8][tx] = in[(size_t)(k0 + ty + i * 8) * N + n0 + tx];
  __syncthreads();
#pragma unroll
  for (int i = 0; i < 4; ++i)
    out[(size_t)(n0 + ty + i * 8) * K + k0 + tx] = f2bf(t[tx][ty + i * 8]);
}

// ---------------- batched-5 1024x1024 weight transpose + cast ----------------
__global__ __launch_bounds__(256) void wt_cast5(const float* __restrict__ i0,
                                                const float* __restrict__ i1,
                                                const float* __restrict__ i2,
                                                const float* __restrict__ i3,
                                                const float* __restrict__ i4,
                                                short* __restrict__ o0,
                                                short* __restrict__ o1,
                                                short* __restrict__ o2,
                                                short* __restrict__ o3,
                                                short* __restrict__ o4) {
  const int z = blockIdx.z;
  const float* in = z == 0 ? i0 : z == 1 ? i1 : z == 2 ? i2 : z == 3 ? i3 : i4;
  short* out      = z == 0 ? o0 : z == 1 ? o1 : z == 2 ? o2 : z == 3 ? o3 : o4;
  __shared__ float t[32][33];
  const int tx = threadIdx.x, ty = threadIdx.y;
  const int n0 = blockIdx.x * 32, k0 = blockIdx.y * 32;
#pragma unroll
  for (int i = 0; i < 4; ++i)
    t[ty + i * 8][tx] = in[(size_t)(k0 + ty + i * 8) * 1024 + n0 + tx];
  __syncthreads();
#pragma unroll
  for (int i = 0; i < 4; ++i)
    out[(size_t)(n0 + ty + i * 8) * 1024 + k0 + tx] = f2bf(t[tx][ty + i * 8]);
}

// ---------------- elementwise cast fp32 -> bf16 ------------------------------
__global__ __launch_bounds__(256) void castf2b(const float* __restrict__ in,
                                               short* __restrict__ out) {
  const int i = blockIdx.x * 256 + threadIdx.x;
  float4 v = ((const float4*)in)[i];
  short4 o;
  o.x = f2bf(v.x); o.y = f2bf(v.y); o.z = f2bf(v.z); o.w = f2bf(v.w);
  ((short4*)out)[i] = o;
}

// ---------------- LayerNorm (row of 1024) fp32 -> bf16 -----------------------
__global__ __launch_bounds__(256) void ln_kernel(const float* __restrict__ x,
                                                 const float* __restrict__ g,
                                                 const float* __restrict__ b,
                                                 short* __restrict__ out) {
  const int row = blockIdx.x;
  const int tid = threadIdx.x;
  const float* xr = x + (size_t)row * D_;
  float4 v = reinterpret_cast<const float4*>(xr)[tid];
  float s  = v.x + v.y + v.z + v.w;
  float s2 = v.x * v.x + v.y * v.y + v.z * v.z + v.w * v.w;
#pragma unroll
  for (int m = 1; m < 64; m <<= 1) {
    s  += __shfl_xor(s, m);
    s2 += __shfl_xor(s2, m);
  }
  __shared__ float ss[4], ss2[4];
  const int w = tid >> 6;
  if ((tid & 63) == 0) { ss[w] = s; ss2[w] = s2; }
  __syncthreads();
  s  = ss[0] + ss[1] + ss[2] + ss[3];
  s2 = ss2[0] + ss2[1] + ss2[2] + ss2[3];
  const float mu   = s * (1.0f / D_);
  const float var  = s2 * (1.0f / D_) - mu * mu;
  const float rstd = rsqrtf(var + 1e-5f);
  float4 gv = reinterpret_cast<const float4*>(g)[tid];
  float4 bv = reinterpret_cast<const float4*>(b)[tid];
  short4 o;
  o.x = f2bf((v.x - mu) * rstd * gv.x + bv.x);
  o.y = f2bf((v.y - mu) * rstd * gv.y + bv.y);
  o.z = f2bf((v.z - mu) * rstd * gv.z + bv.z);
  o.w = f2bf((v.w - mu) * rstd * gv.w + bv.w);
  reinterpret_cast<short4*>(out + (size_t)row * D_)[tid] = o;
}

// ---------------- fused residual + bias + LayerNorm --------------------------
// xnew = xprev + delta(bf16) + pbias; writes xnew (fp32) and LN(xnew) (bf16).
// NOTE: delta may alias out_ln (per-thread read-then-write, same address).
__global__ __launch_bounds__(256) void ln_fused(const float* __restrict__ xprev,
                                                const short* delta,
                                                const float* __restrict__ pbias,
                                                const float* __restrict__ g,
                                                const float* __restrict__ b,
                                                short* out_ln,
                                                float* __restrict__ out_x) {
  const int row = blockIdx.x;
  const int tid = threadIdx.x;
  float4 v = reinterpret_cast<const float4*>(xprev + (size_t)row * D_)[tid];
  short4 dv = reinterpret_cast<const short4*>(delta + (size_t)row * D_)[tid];
  float4 pb = reinterpret_cast<const float4*>(pbias)[tid];
  v.x += bf2f(dv.x) + pb.x;
  v.y += bf2f(dv.y) + pb.y;
  v.z += bf2f(dv.z) + pb.z;
  v.w += bf2f(dv.w) + pb.w;
  float s  = v.x + v.y + v.z + v.w;
  float s2 = v.x * v.x + v.y * v.y + v.z * v.z + v.w * v.w;
#pragma unroll
  for (int m = 1; m < 64; m <<= 1) {
    s  += __shfl_xor(s, m);
    s2 += __shfl_xor(s2, m);
  }
  __shared__ float ss[4], ss2[4];
  const int w = tid >> 6;
  if ((tid & 63) == 0) { ss[w] = s; ss2[w] = s2; }
  __syncthreads();
  s  = ss[0] + ss[1] + ss[2] + ss[3];
  s2 = ss2[0] + ss2[1] + ss2[2] + ss2[3];
  const float mu   = s * (1.0f / D_);
  const float var  = s2 * (1.0f / D_) - mu * mu;
  const float rstd = rsqrtf(var + 1e-5f);
  reinterpret_cast<float4*>(out_x + (size_t)row * D_)[tid] = v;
  float4 gv = reinterpret_cast<const float4*>(g)[tid];
  float4 bv = reinterpret_cast<const float4*>(b)[tid];
  short4 o;
  o.x = f2bf((v.x - mu) * rstd * gv.x + bv.x);
  o.y = f2bf((v.y - mu) * rstd * gv.y + bv.y);
  o.z = f2bf((v.z - mu) * rstd * gv.z + bv.z);
  o.w = f2bf((v.w - mu) * rstd * gv.w + bv.w);
  reinterpret_cast<short4*>(out_ln + (size_t)row * D_)[tid] = o;
}

// ---------------- final residual + bias add: out = x + delta + bias ----------
__global__ __launch_bounds__(256) void addbias(const float* __restrict__ x,
                                               const short* __restrict__ delta,
                                               const float* __restrict__ bias,
                                               float* __restrict__ out) {
  const int i = blockIdx.x * 256 + threadIdx.x;
  float4 v = ((const float4*)x)[i];
  short4 dv = ((const short4*)delta)[i];
  const int col = (i * 4) & (D_ - 1);
  float4 pb = *(const float4*)(bias + col);
  v.x += bf2f(dv.x) + pb.x;
  v.y += bf2f(dv.y) + pb.y;
  v.z += bf2f(dv.z) + pb.z;
  v.w += bf2f(dv.w) + pb.w;
  ((float4*)out)[i] = v;
}

// ---------------- GEMM 128x128, 2-phase double-buffer ------------------------
// MODE 0: store bf16.  MODE 2: bf16 out = gelu(acc + bias) (tanh-sigmoid).
template <int MODE>
__global__ __launch_bounds__(256) void gemm_bt(const short* __restrict__ A,
                                               const short* __restrict__ Bt,
                                               const float* __restrict__ bias,
                                               void* __restrict__ Cout,
                                               int M, int N, int K) {
  __shared__ short As[2][128 * 32];
  __shared__ short Bs[2][128 * 32];
  const int tid = threadIdx.x;
  const int gx = gridDim.x;
  const int nwg = gx * gridDim.y;
  int lin = blockIdx.y * gx + blockIdx.x;
  lin = (lin & 7) * (nwg >> 3) + (lin >> 3);
  const int m0 = (lin / gx) * 128, n0 = (lin % gx) * 128;
  const int wave = tid >> 6, lane = tid & 63;
  const int wm = (wave >> 1) * 64, wn = (wave & 1) * 64;
  const int lr = lane & 15, lg = lane >> 4;

  f32x4 acc[4][4];
#pragma unroll
  for (int i = 0; i < 4; ++i)
#pragma unroll
    for (int j = 0; j < 4; ++j) acc[i][j] = f32x4{0.f, 0.f, 0.f, 0.f};

  const int e0 = tid * 8, e1 = 2048 + tid * 8;
  const int r0 = e0 >> 5, c0 = e0 & 31;
  const int r1 = e1 >> 5, c1 = e1 & 31;
  const size_t ar0 = (size_t)(m0 + r0) * K, ar1 = (size_t)(m0 + r1) * K;
  const size_t br0 = (size_t)(n0 + r0) * K, br1 = (size_t)(n0 + r1) * K;

  auto stage = [&](int buf, int k0) {
    gload16(A + ar0 + k0 + c0, &As[buf][0] + e0);
    gload16(A + ar1 + k0 + c1, &As[buf][0] + e1);
    gload16(Bt + br0 + k0 + c0, &Bs[buf][0] + e0);
    gload16(Bt + br1 + k0 + c1, &Bs[buf][0] + e1);
  };

  stage(0, 0);
  __syncthreads();
  int cur = 0;
  for (int k0 = 0; k0 < K; k0 += 32) {
    if (k0 + 32 < K) stage(cur ^ 1, k0 + 32);
    const short* Ab = &As[cur][0];
    const short* Bb = &Bs[cur][0];
    bf16x8 af[4], bfr[4];
#pragma unroll
    for (int mi = 0; mi < 4; ++mi)
      af[mi] = *(const bf16x8*)(Ab + (wm + mi * 16 + lr) * 32 + lg * 8);
#pragma unroll
    for (int ni = 0; ni < 4; ++ni)
      bfr[ni] = *(const bf16x8*)(Bb + (wn + ni * 16 + lr) * 32 + lg * 8);
#pragma unroll
    for (int mi = 0; mi < 4; ++mi)
#pragma unroll
      for (int ni = 0; ni < 4; ++ni)
        acc[mi][ni] = __builtin_amdgcn_mfma_f32_16x16x32_bf16(
            af[mi], bfr[ni], acc[mi][ni], 0, 0, 0);
    __syncthreads();
    cur ^= 1;
  }

#pragma unroll
  for (int mi = 0; mi < 4; ++mi) {
    const int row = m0 + wm + mi * 16 + lg * 4;
#pragma unroll
    for (int ni = 0; ni < 4; ++ni) {
      const int col = n0 + wn + ni * 16 + lr;
#pragma unroll
      for (int r = 0; r < 4; ++r) {
        const size_t idx = (size_t)(row + r) * N + col;
        const float v = acc[mi][ni][r];
        if (MODE == 0) {
          ((short*)Cout)[idx] = f2bf(v);
        } else {
          const float tt = v + bias[col];
          const float yy = fmaf(tt * tt * tt, 0.044715f, tt);
          const float e = EXP2(yy * -2.3022343813918633f);
          ((short*)Cout)[idx] = f2bf(tt / (1.0f + e));
        }
      }
    }
  }
}

// ---------------- batched-3 GEMM 128x128, 2-phase dbuf (cross-attn q/k/v) ----
__global__ __launch_bounds__(256) void gemm_bt3(const short* __restrict__ A0,
                                                const short* __restrict__ A1,
                                                const short* __restrict__ A2,
                                                const short* __restrict__ B0,
                                                const short* __restrict__ B1,
                                                const short* __restrict__ B2,
                                                short* __restrict__ C0,
                                                short* __restrict__ C1,
                                                short* __restrict__ C2,
                                                int M, int N, int K) {
  const int z = blockIdx.z;
  const short* A  = z == 0 ? A0 : (z == 1 ? A1 : A2);
  const short* Bt = z == 0 ? B0 : (z == 1 ? B1 : B2);
  short* C        = z == 0 ? C0 : (z == 1 ? C1 : C2);

  __shared__ short As[2][128 * 32];
  __shared__ short Bs[2][128 * 32];
  const int tid = threadIdx.x;
  const int gx = gridDim.x;
  const int nwg = gx * gridDim.y;
  int lin = blockIdx.y * gx + blockIdx.x;
  lin = (lin & 7) * (nwg >> 3) + (lin >> 3);
  const int m0 = (lin / gx) * 128, n0 = (lin % gx) * 128;
  const int wave = tid >> 6, lane = tid & 63;
  const int wm = (wave >> 1) * 64, wn = (wave & 1) * 64;
  const int lr = lane & 15, lg = lane >> 4;

  f32x4 acc[4][4];
#pragma unroll
  for (int i = 0; i < 4; ++i)
#pragma unroll
    for (int j = 0; j < 4; ++j) acc[i][j] = f32x4{0.f, 0.f, 0.f, 0.f};

  const int e0 = tid * 8, e1 = 2048 + tid * 8;
  const int r0 = e0 >> 5, c0 = e0 & 31;
  const int r1 = e1 >> 5, c1 = e1 & 31;
  const size_t ar0 = (size_t)(m0 + r0) * K, ar1 = (size_t)(m0 + r1) * K;
  const size_t br0 = (size_t)(n0 + r0) * K, br1 = (size_t)(n0 + r1) * K;

  auto stage = [&](int buf, int k0) {
    gload16(A + ar0 + k0 + c0, &As[buf][0] + e0);
    gload16(A + ar1 + k0 + c1, &As[buf][0] + e1);
    gload16(Bt + br0 + k0 + c0, &Bs[buf][0] + e0);
    gload16(Bt + br1 + k0 + c1, &Bs[buf][0] + e1);
  };

  stage(0, 0);
  __syncthreads();
  int cur = 0;
  for (int k0 = 0; k0 < K; k0 += 32) {
    if (k0 + 32 < K) stage(cur ^ 1, k0 + 32);
    const short* Ab = &As[cur][0];
    const short* Bb = &Bs[cur][0];
    bf16x8 af[4], bfr[4];
#pragma unroll
    for (int mi = 0; mi < 4; ++mi)
      af[mi] = *(const bf16x8*)(Ab + (wm + mi * 16 + lr) * 32 + lg * 8);
#pragma unroll
    for (int ni = 0; ni < 4; ++ni)
      bfr[ni] = *(const bf16x8*)(Bb + (wn + ni * 16 + lr) * 32 + lg * 8);
#pragma unroll
    for (int mi = 0; mi < 4; ++mi)
#pragma unroll
      for (int ni = 0; ni < 4; ++ni)
        acc[mi][ni] = __builtin_amdgcn_mfma_f32_16x16x32_bf16(
            af[mi], bfr[ni], acc[mi][ni], 0, 0, 0);
    __syncthreads();
    cur ^= 1;
  }

#pragma unroll
  for (int mi = 0; mi < 4; ++mi) {
    const int row = m0 + wm + mi * 16 + lg * 4;
#pragma unroll
    for (int ni = 0; ni < 4; ++ni) {
      const int col = n0 + wn + ni * 16 + lr;
#pragma unroll
      for (int r = 0; r < 4; ++r)
        C[(size_t)(row + r) * N + col] = f2bf(acc[mi][ni][r]);
    }
  }
}

// ---------------- GEMM 64x128 tile, bf16 delta out, 2-phase double-buffer ----
__global__ __launch_bounds__(256) void gemm_bt64(const short* __restrict__ A,
                                                 const short* __restrict__ Bt,
                                                 short* __restrict__ Cout,
                                                 int M, int N, int K) {
  __shared__ short As[2][64 * 32];
  __shared__ short Bs[2][128 * 32];
  const int tid = threadIdx.x;
  const int gx = gridDim.x;
  const int nwg = gx * gridDim.y;
  int lin = blockIdx.y * gx + blockIdx.x;
  lin = (lin & 7) * (nwg >> 3) + (lin >> 3);
  const int m0 = (lin / gx) * 64, n0 = (lin % gx) * 128;
  const int wave = tid >> 6, lane = tid & 63;
  const int wn = wave * 32;
  const int lr = lane & 15, lg = lane >> 4;

  f32x4 acc[4][2];
#pragma unroll
  for (int i = 0; i < 4; ++i)
#pragma unroll
    for (int j = 0; j < 2; ++j) acc[i][j] = f32x4{0.f, 0.f, 0.f, 0.f};

  const int ea = tid * 8;
  const int ra = ea >> 5, ca = ea & 31;
  const int e0 = tid * 8, e1 = 2048 + tid * 8;
  const int r0 = e0 >> 5, c0 = e0 & 31;
  const int r1 = e1 >> 5, c1 = e1 & 31;
  const size_t ar = (size_t)(m0 + ra) * K;
  const size_t br0 = (size_t)(n0 + r0) * K, br1 = (size_t)(n0 + r1) * K;

  auto stage = [&](int buf, int k0) {
    gload16(A + ar + k0 + ca, &As[buf][0] + ea);
    gload16(Bt + br0 + k0 + c0, &Bs[buf][0] + e0);
    gload16(Bt + br1 + k0 + c1, &Bs[buf][0] + e1);
  };

  stage(0, 0);
  __syncthreads();
  int cur = 0;
  for (int k0 = 0; k0 < K; k0 += 32) {
    if (k0 + 32 < K) stage(cur ^ 1, k0 + 32);
    const short* Ab = &As[cur][0];
    const short* Bb = &Bs[cur][0];
    bf16x8 af[4], bfr[2];
#pragma unroll
    for (int mi = 0; mi < 4; ++mi)
      af[mi] = *(const bf16x8*)(Ab + (mi * 16 + lr) * 32 + lg * 8);
#pragma unroll
    for (int ni = 0; ni < 2; ++ni)
      bfr[ni] = *(const bf16x8*)(Bb + (wn + ni * 16 + lr) * 32 + lg * 8);
#pragma unroll
    for (int mi = 0; mi < 4; ++mi)
#pragma unroll
      for (int ni = 0; ni < 2; ++ni)
        acc[mi][ni] = __builtin_amdgcn_mfma_f32_16x16x32_bf16(
            af[mi], bfr[ni], acc[mi][ni], 0, 0, 0);
    __syncthreads();
    cur ^= 1;
  }

#pragma unroll
  for (int mi = 0; mi < 4; ++mi) {
    const int row = m0 + mi * 16 + lg * 4;
#pragma unroll
    for (int ni = 0; ni < 2; ++ni) {
      const int col = n0 + wn + ni * 16 + lr;
#pragma unroll
      for (int r = 0; r < 4; ++r)
        Cout[(size_t)(row + r) * N + col] = f2bf(acc[mi][ni][r]);
    }
  }
}

// ---------------- per-head V transpose (bf16): (N x HD) -> (HD x N) ----------
__global__ __launch_bounds__(256) void vtrans(const short* __restrict__ in,
                                              short* __restrict__ out,
                                              int ldi, int N) {
  const int bh = blockIdx.z;
  const int b = bh >> 4, h = bh & 15;
  const short* ib = in + (size_t)b * N * ldi + h * HD_;
  short* ob = out + (size_t)bh * HD_ * N;
  __shared__ short t[32][33];
  const int tx = threadIdx.x, ty = threadIdx.y;
  const int n0 = blockIdx.x * 32, d0 = blockIdx.y * 32;
#pragma unroll
  for (int i = 0; i < 4; ++i)
    t[ty + i * 8][tx] = ib[(size_t)(n0 + ty + i * 8) * ldi + d0 + tx];
  __syncthreads();
#pragma unroll
  for (int i = 0; i < 4; ++i)
    ob[(size_t)(d0 + ty + i * 8) * N + n0 + tx] = t[tx][ty + i * 8];
}

// ---------------- flash attention: 128 q-rows/block (8 waves), KBLK=64 -------
// Swapped QK^T (r6-proven per-wave body). One K/V tile serves 128 q-rows:
// staging = 2 gload16/thread/tile, barriers halved per q-row. 2-phase dbuf.
// Causal: grid (32,16), qb remap pairs long+short diagonals; waves skip
// fully-masked tiles (compute-only skip; barriers preserved).
__global__ __launch_bounds__(512) void flash(const short* __restrict__ Q,
                                             const short* __restrict__ Kp,
                                             const short* __restrict__ Vt,
                                             short* __restrict__ O,
                                             int ldq, int ldk, int ldo,
                                             int NK, int causal) {
  const int bh = blockIdx.x;
  int qb = blockIdx.y;
  if (causal) qb = (qb < 8) ? (2 * qb) : (31 - 2 * qb);
  const int b = bh >> 4, h = bh & 15;
  const int q0 = qb * 128;
  const int tid = threadIdx.x, wave = tid >> 6, lane = tid & 63;
  const int lr = lane & 15, lg = lane >> 4;
  const int lx = lr & 7;

  const short* Qb = Q + (size_t)b * ND_ * ldq + h * HD_;
  const short* Kb = Kp + (size_t)b * NK * ldk + h * HD_;
  const short* Vb = Vt + (size_t)bh * HD_ * NK;
  short* Ob = O + (size_t)b * ND_ * ldo + h * HD_;

  __shared__ short Ks[2][64 * 64];
  __shared__ short Vs[2][64 * 64];
  __shared__ short Ps[8][16 * 64];   // per-wave P tile, [q][k] swizzled

  const int qrow = q0 + wave * 16 + lr;
  const bf16x8 qf0 = *(const bf16x8*)(Qb + (size_t)qrow * ldq + lg * 8);
  const bf16x8 qf1 = *(const bf16x8*)(Qb + (size_t)qrow * ldq + 32 + lg * 8);

  const bf16x8 ONES = {0x3F80, 0x3F80, 0x3F80, 0x3F80,
                       0x3F80, 0x3F80, 0x3F80, 0x3F80};  // bf16 1.0 x8

  f32x4 oacc[4];
  f32x4 lacc = f32x4{0.f, 0.f, 0.f, 0.f};
  float m_own = -1e30f;
#pragma unroll
  for (int i = 0; i < 4; ++i) oacc[i] = f32x4{0.f, 0.f, 0.f, 0.f};

  const int sr0 = tid >> 3;                       // 0..63
  const int ssw = ((tid & 7) ^ (sr0 & 7)) * 8;
  const int e0 = tid * 8;                         // 0..4088

  const float SC = 0.18033688011112042f;  // 1/sqrt(64) * log2(e)

  short* Pw = &Ps[wave][0];
  const int pbase = lr * 64 + (lg & 1) * 4;

  auto stage = [&](int buf, int k0) {
    gload16(Kb + (size_t)(k0 + sr0) * ldk + ssw, &Ks[buf][0] + e0);
    gload16(Vb + (size_t)sr0 * NK + k0 + ssw, &Vs[buf][0] + e0);
  };

  const int nkt = causal ? (2 * qb + 2) : (NK / 64);
  stage(0, 0);
  __syncthreads();
  int cur = 0;
  for (int t = 0; t < nkt; ++t) {
    const int k0 = t * 64;
    if (t + 1 < nkt) stage(cur ^ 1, k0 + 64);
    // skip tiles fully above this wave's diagonal (wave-uniform)
    if (!causal || k0 <= q0 + wave * 16 + 15) {
      const short* Ksb = &Ks[cur][0];
      const short* Vsb = &Vs[cur][0];

      f32x4 st[4];
#pragma unroll
      for (int kb = 0; kb < 4; ++kb) {
        const bf16x8 kf0 = *(const bf16x8*)(Ksb + (kb * 16 + lr) * 64 + ((lg ^ lx) * 8));
        const bf16x8 kf1 = *(const bf16x8*)(Ksb + (kb * 16 + lr) * 64 + (((4 + lg) ^ lx) * 8));
        st[kb] = f32x4{0.f, 0.f, 0.f, 0.f};
        st[kb] = __builtin_amdgcn_mfma_f32_16x16x32_bf16(kf0, qf0, st[kb], 0, 0, 0);
        st[kb] = __builtin_amdgcn_mfma_f32_16x16x32_bf16(kf1, qf1, st[kb], 0, 0, 0);
      }
      if (causal && k0 + 63 > q0 + wave * 16) {  // diagonal tile for this wave
#pragma unroll
        for (int kb = 0; kb < 4; ++kb)
#pragma unroll
          for (int r = 0; r < 4; ++r)
            if ((k0 + kb * 16 + lg * 4 + r) > qrow) st[kb][r] = -3.0e38f;
      }

      float rm = st[0][0];
#pragma unroll
      for (int kb = 0; kb < 4; ++kb)
#pragma unroll
        for (int r = 0; r < 4; ++r)
          if (kb || r) rm = fmaxf(rm, st[kb][r]);
      rm = fmaxf(rm, __shfl_xor(rm, 16));
      rm = fmaxf(rm, __shfl_xor(rm, 32));

      if (!__all(rm - m_own <= 44.f)) {
        const float nm = fmaxf(m_own, rm);
        const float fac = EXP2((m_own - nm) * SC);
        m_own = nm;
        const float fr0 = __shfl(fac, (lg << 2) + 0);
        const float fr1 = __shfl(fac, (lg << 2) + 1);
        const float fr2 = __shfl(fac, (lg << 2) + 2);
        const float fr3 = __shfl(fac, (lg << 2) + 3);
#pragma unroll
        for (int db = 0; db < 4; ++db) {
          oacc[db][0] *= fr0; oacc[db][1] *= fr1;
          oacc[db][2] *= fr2; oacc[db][3] *= fr3;
        }
        lacc[0] *= fr0; lacc[1] *= fr1; lacc[2] *= fr2; lacc[3] *= fr3;
      }
      const float nmsc = m_own * SC;
#pragma unroll
      for (int kb = 0; kb < 4; ++kb)
#pragma unroll
        for (int r = 0; r < 4; ++r)
          st[kb][r] = EXP2(fmaf(st[kb][r], SC, -nmsc));

      // P pack via cvt_pk pairs (byte layout identical to scalar-pack path)
#pragma unroll
      for (int kb = 0; kb < 4; ++kb) {
        union { unsigned u[2]; unsigned long long ull; } pk;
        asm("v_cvt_pk_bf16_f32 %0, %1, %2"
            : "=v"(pk.u[0]) : "v"(st[kb][0]), "v"(st[kb][1]));
        asm("v_cvt_pk_bf16_f32 %0, %1, %2"
            : "=v"(pk.u[1]) : "v"(st[kb][2]), "v"(st[kb][3]));
        const int cs = kb * 2 + (lg >> 1);
        *(unsigned long long*)(Pw + pbase + ((cs ^ lx) * 8)) = pk.ull;
      }
      const bf16x8 pf0 = *(const bf16x8*)(Pw + lr * 64 + ((lg ^ lx) * 8));
      const bf16x8 pf1 = *(const bf16x8*)(Pw + lr * 64 + (((4 + lg) ^ lx) * 8));

#pragma unroll
      for (int db = 0; db < 4; ++db) {
        const bf16x8 vf0 = *(const bf16x8*)(Vsb + (db * 16 + lr) * 64 + ((lg ^ lx) * 8));
        const bf16x8 vf1 = *(const bf16x8*)(Vsb + (db * 16 + lr) * 64 + (((4 + lg) ^ lx) * 8));
        oacc[db] = __builtin_amdgcn_mfma_f32_16x16x32_bf16(pf0, vf0, oacc[db], 0, 0, 0);
        oacc[db] = __builtin_amdgcn_mfma_f32_16x16x32_bf16(pf1, vf1, oacc[db], 0, 0, 0);
      }
      lacc = __builtin_amdgcn_mfma_f32_16x16x32_bf16(pf0, ONES, lacc, 0, 0, 0);
      lacc = __builtin_amdgcn_mfma_f32_16x16x32_bf16(pf1, ONES, lacc, 0, 0, 0);
    }
    __syncthreads();
    cur ^= 1;
  }
#pragma unroll
  for (int db = 0; db < 4; ++db)
#pragma unroll
    for (int r = 0; r < 4; ++r) {
      const int q = q0 + wave * 16 + lg * 4 + r;
      Ob[(size_t)q * ldo + db * 16 + lr] = f2bf(oacc[db][r] / lacc[r]);
    }
}

// ---------------------------------------------------------------------------
extern "C" void kernel_launch(void* const* d_in, const int* in_sizes, int n_in,
                              void* d_out, int out_size, void* d_ws, size_t ws_size,
                              hipStream_t stream) {
  const float* x      = (const float*)d_in[0];
  const float* memory = (const float*)d_in[1];
  const float* ln1_g  = (const float*)d_in[2];
  const float* ln1_b  = (const float*)d_in[3];
  const float* Wqkv   = (const float*)d_in[4];
  const float* Wo_sa  = (const float*)d_in[5];
  const float* bo_sa  = (const float*)d_in[6];
  const float* ln2_g  = (const float*)d_in[7];
  const float* ln2_b  = (const float*)d_in[8];
  const float* Wq     = (const float*)d_in[9];
  const float* Wk     = (const float*)d_in[10];
  const float* Wv     = (const float*)d_in[11];
  const float* Wo_ca  = (const float*)d_in[12];
  const float* bo_ca  = (const float*)d_in[13];
  const float* ln3_g  = (const float*)d_in[14];
  const float* ln3_b  = (const float*)d_in[15];
  const float* W1     = (const float*)d_in[16];
  const float* b1     = (const float*)d_in[17];
  const float* W2     = (const float*)d_in[18];
  const float* b2     = (const float*)d_in[19];

  char* ws = (char*)d_ws;
  size_t o = 0;
  auto alloc = [&](size_t bytes) { char* p = ws + o; o += bytes; return p; };
  short* wqkv_t = (short*)alloc((size_t)3072 * 1024 * 2);
  short* wosa_t = (short*)alloc((size_t)1024 * 1024 * 2);
  short* wq_t   = (short*)alloc((size_t)1024 * 1024 * 2);
  short* wk_t   = (short*)alloc((size_t)1024 * 1024 * 2);
  short* wv_t   = (short*)alloc((size_t)1024 * 1024 * 2);
  short* woca_t = (short*)alloc((size_t)1024 * 1024 * 2);
  short* w1_t   = (short*)alloc((size_t)4096 * 1024 * 2);
  short* w2_t   = (short*)alloc((size_t)1024 * 4096 * 2);
  short* hbf    = (short*)alloc((size_t)T_ * 1024 * 2);  // ln-out AND delta buf
  short* bufa   = (short*)alloc((size_t)T_ * 3072 * 2);
  short* vt     = (short*)alloc((size_t)32 * 64 * 2048 * 2);
  short* attn   = (short*)alloc((size_t)T_ * 1024 * 2);
  short* membf  = (short*)alloc((size_t)T_ * 1024 * 2);
  float* x1     = (float*)alloc((size_t)T_ * 1024 * 4);
  float* x2     = (float*)alloc((size_t)T_ * 1024 * 4);
  if (o > ws_size) return;

  short* ffn = bufa;  // spans bufa(24MB)+vt(8MB), both dead by then
  short* qca = bufa;
  short* kca = bufa + (size_t)T_ * 1024;
  short* vca = bufa + (size_t)2 * T_ * 1024;

  const dim3 tb(32, 8);

  // weight transposes (fp32 -> bf16, K x N -> N x K)
  wt_cast<<<dim3(3072 / 32, 1024 / 32), tb, 0, stream>>>(Wqkv, wqkv_t, 1024, 3072);
  wt_cast5<<<dim3(32, 32, 5), tb, 0, stream>>>(Wo_sa, Wq, Wk, Wv, Wo_ca,
                                               wosa_t, wq_t, wk_t, wv_t, woca_t);
  wt_cast<<<dim3(4096 / 32, 1024 / 32), tb, 0, stream>>>(W1, w1_t, 1024, 4096);
  wt_cast<<<dim3(1024 / 32, 4096 / 32), tb, 0, stream>>>(W2, w2_t, 4096, 1024);
  castf2b<<<dim3((T_ * 1024) / (256 * 4)), 256, 0, stream>>>(memory, membf);

  // --- self-attention block ---
  ln_kernel<<<dim3(T_), 256, 0, stream>>>(x, ln1_g, ln1_b, hbf);
  gemm_bt<0><<<dim3(3072 / 128, T_ / 128), 256, 0, stream>>>(
      hbf, wqkv_t, nullptr, bufa, T_, 3072, 1024);
  vtrans<<<dim3(ND_ / 32, HD_ / 32, 32), tb, 0, stream>>>(bufa + 2048, vt, 3072, ND_);
  flash<<<dim3(32, ND_ / 128), 512, 0, stream>>>(
      bufa, bufa + 1024, vt, attn, 3072, 3072, 1024, ND_, 1);
  gemm_bt64<<<dim3(1024 / 128, T_ / 64), 256, 0, stream>>>(
      attn, wosa_t, hbf, T_, 1024, 1024);                       // delta_sa -> hbf
  ln_fused<<<dim3(T_), 256, 0, stream>>>(x, hbf, bo_sa, ln2_g, ln2_b, hbf, x1);

  // --- cross-attention block ---
  gemm_bt3<<<dim3(1024 / 128, T_ / 128, 3), 256, 0, stream>>>(
      hbf, membf, membf, wq_t, wk_t, wv_t, qca, kca, vca, T_, 1024, 1024);
  vtrans<<<dim3(NE_ / 32, HD_ / 32, 32), tb, 0, stream>>>(vca, vt, 1024, NE_);
  flash<<<dim3(32, ND_ / 128), 512, 0, stream>>>(
      qca, kca, vt, attn, 1024, 1024, 1024, NE_, 0);
  gemm_bt64<<<dim3(1024 / 128, T_ / 64), 256, 0, stream>>>(
      attn, woca_t, hbf, T_, 1024, 1024);                       // delta_ca -> hbf
  ln_fused<<<dim3(T_), 256, 0, stream>>>(x1, hbf, bo_ca, ln3_g, ln3_b, hbf, x2);

  // --- FFN block ---
  gemm_bt<2><<<dim3(4096 / 128, T_ / 128), 256, 0, stream>>>(
      hbf, w1_t, b1, ffn, T_, 4096, 1024);
  gemm_bt64<<<dim3(1024 / 128, T_ / 64), 256, 0, stream>>>(
      ffn, w2_t, hbf, T_, 1024, 4096);                          // delta_ffn -> hbf
  addbias<<<dim3((T_ * 1024) / (256 * 4)), 256, 0, stream>>>(
      x2, hbf, b2, (float*)d_out);
}

// Round 10
// 378.589 us; speedup vs baseline: 2.0408x; 1.0246x over previous
//
#include <hip/hip_runtime.h>
#include <hip/hip_bf16.h>
#include <math.h>

#define B_   2
#define ND_  2048
#define NE_  2048
#define D_   1024
#define H_   16
#define HD_  64
#define DFF_ 4096
#define T_   4096   // B_*ND_ tokens

typedef __attribute__((ext_vector_type(8))) short bf16x8;
typedef __attribute__((ext_vector_type(4))) float f32x4;

#if __has_builtin(__builtin_amdgcn_exp2f)
#define EXP2(x) __builtin_amdgcn_exp2f(x)
#else
#define EXP2(x) exp2f(x)
#endif

__device__ __forceinline__ short f2bf(float f) {
  union { float f; unsigned u; } v; v.f = f;
  return (short)((v.u + 0x7FFFu + ((v.u >> 16) & 1u)) >> 16);
}
__device__ __forceinline__ float bf2f(short s) {
  union { unsigned u; float f; } v; v.u = ((unsigned)(unsigned short)s) << 16;
  return v.f;
}

typedef const __attribute__((address_space(1))) void gvoid_t;
typedef __attribute__((address_space(3))) void lvoid_t;

__device__ __forceinline__ void gload16(const void* src, void* dst) {
  __builtin_amdgcn_global_load_lds((gvoid_t*)src, (lvoid_t*)dst, 16, 0, 0);
}

// ---------------- weight transpose + cast: fp32 (K x N) -> bf16 (N x K) ------
__global__ __launch_bounds__(256) void wt_cast(const float* __restrict__ in,
                                               short* __restrict__ out,
                                               int K, int N) {
  __shared__ float t[32][33];
  const int tx = threadIdx.x, ty = threadIdx.y;
  const int n0 = blockIdx.x * 32, k0 = blockIdx.y * 32;
#pragma unroll
  for (int i = 0; i < 4; ++i)
    t[ty + i * 8][tx] = in[(size_t)(k0 + ty + i * 8) * N + n0 + tx];
  __syncthreads();
#pragma unroll
  for (int i = 0; i < 4; ++i)
    out[(size_t)(n0 + ty + i * 8) * K + k0 + tx] = f2bf(t[tx][ty + i * 8]);
}

// ---------------- batched-5 1024x1024 weight transpose + cast ----------------
__global__ __launch_bounds__(256) void wt_cast5(const float* __restrict__ i0,
                                                const float* __restrict__ i1,
                                                const float* __restrict__ i2,
                                                const float* __restrict__ i3,
                                                const float* __restrict__ i4,
                                                short* __restrict__ o0,
                                                short* __restrict__ o1,
                                                short* __restrict__ o2,
                                                short* __restrict__ o3,
                                                short* __restrict__ o4) {
  const int z = blockIdx.z;
  const float* in = z == 0 ? i0 : z == 1 ? i1 : z == 2 ? i2 : z == 3 ? i3 : i4;
  short* out      = z == 0 ? o0 : z == 1 ? o1 : z == 2 ? o2 : z == 3 ? o3 : o4;
  __shared__ float t[32][33];
  const int tx = threadIdx.x, ty = threadIdx.y;
  const int n0 = blockIdx.x * 32, k0 = blockIdx.y * 32;
#pragma unroll
  for (int i = 0; i < 4; ++i)
    t[ty + i * 8][tx] = in[(size_t)(k0 + ty + i * 8) * 1024 + n0 + tx];
  __syncthreads();
#pragma unroll
  for (int i = 0; i < 4; ++i)
    out[(size_t)(n0 + ty + i * 8) * 1024 + k0 + tx] = f2bf(t[tx][ty + i * 8]);
}

// ---------------- elementwise cast fp32 -> bf16 ------------------------------
__global__ __launch_bounds__(256) void castf2b(const float* __restrict__ in,
                                               short* __restrict__ out) {
  const int i = blockIdx.x * 256 + threadIdx.x;
  float4 v = ((const float4*)in)[i];
  short4 o;
  o.x = f2bf(v.x); o.y = f2bf(v.y); o.z = f2bf(v.z); o.w = f2bf(v.w);
  ((short4*)out)[i] = o;
}

// ---------------- LayerNorm (row of 1024) fp32 -> bf16 -----------------------
__global__ __launch_bounds__(256) void ln_kernel(const float* __restrict__ x,
                                                 const float* __restrict__ g,
                                                 const float* __restrict__ b,
                                                 short* __restrict__ out) {
  const int row = blockIdx.x;
  const int tid = threadIdx.x;
  const float* xr = x + (size_t)row * D_;
  float4 v = reinterpret_cast<const float4*>(xr)[tid];
  float s  = v.x + v.y + v.z + v.w;
  float s2 = v.x * v.x + v.y * v.y + v.z * v.z + v.w * v.w;
#pragma unroll
  for (int m = 1; m < 64; m <<= 1) {
    s  += __shfl_xor(s, m);
    s2 += __shfl_xor(s2, m);
  }
  __shared__ float ss[4], ss2[4];
  const int w = tid >> 6;
  if ((tid & 63) == 0) { ss[w] = s; ss2[w] = s2; }
  __syncthreads();
  s  = ss[0] + ss[1] + ss[2] + ss[3];
  s2 = ss2[0] + ss2[1] + ss2[2] + ss2[3];
  const float mu   = s * (1.0f / D_);
  const float var  = s2 * (1.0f / D_) - mu * mu;
  const float rstd = rsqrtf(var + 1e-5f);
  float4 gv = reinterpret_cast<const float4*>(g)[tid];
  float4 bv = reinterpret_cast<const float4*>(b)[tid];
  short4 o;
  o.x = f2bf((v.x - mu) * rstd * gv.x + bv.x);
  o.y = f2bf((v.y - mu) * rstd * gv.y + bv.y);
  o.z = f2bf((v.z - mu) * rstd * gv.z + bv.z);
  o.w = f2bf((v.w - mu) * rstd * gv.w + bv.w);
  reinterpret_cast<short4*>(out + (size_t)row * D_)[tid] = o;
}

// ---------------- fused residual + bias + LayerNorm --------------------------
// xnew = xprev + delta(bf16) + pbias; writes xnew (fp32) and LN(xnew) (bf16).
// NOTE: delta may alias out_ln (per-thread read-then-write, same address).
__global__ __launch_bounds__(256) void ln_fused(const float* __restrict__ xprev,
                                                const short* delta,
                                                const float* __restrict__ pbias,
                                                const float* __restrict__ g,
                                                const float* __restrict__ b,
                                                short* out_ln,
                                                float* __restrict__ out_x) {
  const int row = blockIdx.x;
  const int tid = threadIdx.x;
  float4 v = reinterpret_cast<const float4*>(xprev + (size_t)row * D_)[tid];
  short4 dv = reinterpret_cast<const short4*>(delta + (size_t)row * D_)[tid];
  float4 pb = reinterpret_cast<const float4*>(pbias)[tid];
  v.x += bf2f(dv.x) + pb.x;
  v.y += bf2f(dv.y) + pb.y;
  v.z += bf2f(dv.z) + pb.z;
  v.w += bf2f(dv.w) + pb.w;
  float s  = v.x + v.y + v.z + v.w;
  float s2 = v.x * v.x + v.y * v.y + v.z * v.z + v.w * v.w;
#pragma unroll
  for (int m = 1; m < 64; m <<= 1) {
    s  += __shfl_xor(s, m);
    s2 += __shfl_xor(s2, m);
  }
  __shared__ float ss[4], ss2[4];
  const int w = tid >> 6;
  if ((tid & 63) == 0) { ss[w] = s; ss2[w] = s2; }
  __syncthreads();
  s  = ss[0] + ss[1] + ss[2] + ss[3];
  s2 = ss2[0] + ss2[1] + ss2[2] + ss2[3];
  const float mu   = s * (1.0f / D_);
  const float var  = s2 * (1.0f / D_) - mu * mu;
  const float rstd = rsqrtf(var + 1e-5f);
  reinterpret_cast<float4*>(out_x + (size_t)row * D_)[tid] = v;
  float4 gv = reinterpret_cast<const float4*>(g)[tid];
  float4 bv = reinterpret_cast<const float4*>(b)[tid];
  short4 o;
  o.x = f2bf((v.x - mu) * rstd * gv.x + bv.x);
  o.y = f2bf((v.y - mu) * rstd * gv.y + bv.y);
  o.z = f2bf((v.z - mu) * rstd * gv.z + bv.z);
  o.w = f2bf((v.w - mu) * rstd * gv.w + bv.w);
  reinterpret_cast<short4*>(out_ln + (size_t)row * D_)[tid] = o;
}

// ---------------- final residual + bias add: out = x + delta + bias ----------
__global__ __launch_bounds__(256) void addbias(const float* __restrict__ x,
                                               const short* __restrict__ delta,
                                               const float* __restrict__ bias,
                                               float* __restrict__ out) {
  const int i = blockIdx.x * 256 + threadIdx.x;
  float4 v = ((const float4*)x)[i];
  short4 dv = ((const short4*)delta)[i];
  const int col = (i * 4) & (D_ - 1);
  float4 pb = *(const float4*)(bias + col);
  v.x += bf2f(dv.x) + pb.x;
  v.y += bf2f(dv.y) + pb.y;
  v.z += bf2f(dv.z) + pb.z;
  v.w += bf2f(dv.w) + pb.w;
  ((float4*)out)[i] = v;
}

// ---------------- GEMM 128x128, BK=64, XOR-swizzled LDS, 2-phase dbuf --------
// LDS rows are 128B (full 32-bank span); slot ^= row&7 balances banks exactly
// (8 dwords/bank, the HW minimum). Staging: linear gload_lds dest + source
// col pre-swizzled by the same involution (rule #21; flash-proven pattern).
// MODE 0: store bf16.  MODE 2: bf16 out = gelu(acc + bias) (tanh-sigmoid).
template <int MODE>
__global__ __launch_bounds__(256) void gemm_bt(const short* __restrict__ A,
                                               const short* __restrict__ Bt,
                                               const float* __restrict__ bias,
                                               void* __restrict__ Cout,
                                               int M, int N, int K) {
  __shared__ short As[2][128 * 64];
  __shared__ short Bs[2][128 * 64];
  const int tid = threadIdx.x;
  const int gx = gridDim.x;
  const int nwg = gx * gridDim.y;
  int lin = blockIdx.y * gx + blockIdx.x;
  lin = (lin & 7) * (nwg >> 3) + (lin >> 3);
  const int m0 = (lin / gx) * 128, n0 = (lin % gx) * 128;
  const int wave = tid >> 6, lane = tid & 63;
  const int wm = (wave >> 1) * 64, wn = (wave & 1) * 64;
  const int lr = lane & 15, lg = lane >> 4;
  const int lx = lr & 7;

  f32x4 acc[4][4];
#pragma unroll
  for (int i = 0; i < 4; ++i)
#pragma unroll
    for (int j = 0; j < 4; ++j) acc[i][j] = f32x4{0.f, 0.f, 0.f, 0.f};

  const int sr = tid >> 3;                         // 0..31 (row within pass)
  const int scs = ((tid & 7) ^ (sr & 7)) * 8;      // swizzled source col
  const size_t arow = (size_t)(m0 + sr) * K + scs;
  const size_t brow = (size_t)(n0 + sr) * K + scs;

  auto stage = [&](int buf, int k0) {
#pragma unroll
    for (int p = 0; p < 4; ++p) {
      gload16(A + arow + (size_t)(p * 32) * K + k0, &As[buf][p * 2048 + tid * 8]);
      gload16(Bt + brow + (size_t)(p * 32) * K + k0, &Bs[buf][p * 2048 + tid * 8]);
    }
  };

  stage(0, 0);
  __syncthreads();
  int cur = 0;
  for (int k0 = 0; k0 < K; k0 += 64) {
    if (k0 + 64 < K) stage(cur ^ 1, k0 + 64);
    const short* Ab = &As[cur][0];
    const short* Bb = &Bs[cur][0];
#pragma unroll
    for (int kk = 0; kk < 2; ++kk) {
      bf16x8 af[4], bfr[4];
#pragma unroll
      for (int mi = 0; mi < 4; ++mi)
        af[mi] = *(const bf16x8*)(Ab + (wm + mi * 16 + lr) * 64 +
                                  (((kk * 4 + lg) ^ lx) * 8));
#pragma unroll
      for (int ni = 0; ni < 4; ++ni)
        bfr[ni] = *(const bf16x8*)(Bb + (wn + ni * 16 + lr) * 64 +
                                   (((kk * 4 + lg) ^ lx) * 8));
#pragma unroll
      for (int mi = 0; mi < 4; ++mi)
#pragma unroll
        for (int ni = 0; ni < 4; ++ni)
          acc[mi][ni] = __builtin_amdgcn_mfma_f32_16x16x32_bf16(
              af[mi], bfr[ni], acc[mi][ni], 0, 0, 0);
    }
    __syncthreads();
    cur ^= 1;
  }

#pragma unroll
  for (int mi = 0; mi < 4; ++mi) {
    const int row = m0 + wm + mi * 16 + lg * 4;
#pragma unroll
    for (int ni = 0; ni < 4; ++ni) {
      const int col = n0 + wn + ni * 16 + lr;
#pragma unroll
      for (int r = 0; r < 4; ++r) {
        const size_t idx = (size_t)(row + r) * N + col;
        const float v = acc[mi][ni][r];
        if (MODE == 0) {
          ((short*)Cout)[idx] = f2bf(v);
        } else {
          const float tt = v + bias[col];
          const float yy = fmaf(tt * tt * tt, 0.044715f, tt);
          const float e = EXP2(yy * -2.3022343813918633f);
          ((short*)Cout)[idx] = f2bf(tt / (1.0f + e));
        }
      }
    }
  }
}

// ---------------- batched-3 GEMM 128x128, BK=64 swizzled (cross-attn q/k/v) --
__global__ __launch_bounds__(256) void gemm_bt3(const short* __restrict__ A0,
                                                const short* __restrict__ A1,
                                                const short* __restrict__ A2,
                                                const short* __restrict__ B0,
                                                const short* __restrict__ B1,
                                                const short* __restrict__ B2,
                                                short* __restrict__ C0,
                                                short* __restrict__ C1,
                                                short* __restrict__ C2,
                                                int M, int N, int K) {
  const int z = blockIdx.z;
  const short* A  = z == 0 ? A0 : (z == 1 ? A1 : A2);
  const short* Bt = z == 0 ? B0 : (z == 1 ? B1 : B2);
  short* C        = z == 0 ? C0 : (z == 1 ? C1 : C2);

  __shared__ short As[2][128 * 64];
  __shared__ short Bs[2][128 * 64];
  const int tid = threadIdx.x;
  const int gx = gridDim.x;
  const int nwg = gx * gridDim.y;
  int lin = blockIdx.y * gx + blockIdx.x;
  lin = (lin & 7) * (nwg >> 3) + (lin >> 3);
  const int m0 = (lin / gx) * 128, n0 = (lin % gx) * 128;
  const int wave = tid >> 6, lane = tid & 63;
  const int wm = (wave >> 1) * 64, wn = (wave & 1) * 64;
  const int lr = lane & 15, lg = lane >> 4;
  const int lx = lr & 7;

  f32x4 acc[4][4];
#pragma unroll
  for (int i = 0; i < 4; ++i)
#pragma unroll
    for (int j = 0; j < 4; ++j) acc[i][j] = f32x4{0.f, 0.f, 0.f, 0.f};

  const int sr = tid >> 3;
  const int scs = ((tid & 7) ^ (sr & 7)) * 8;
  const size_t arow = (size_t)(m0 + sr) * K + scs;
  const size_t brow = (size_t)(n0 + sr) * K + scs;

  auto stage = [&](int buf, int k0) {
#pragma unroll
    for (int p = 0; p < 4; ++p) {
      gload16(A + arow + (size_t)(p * 32) * K + k0, &As[buf][p * 2048 + tid * 8]);
      gload16(Bt + brow + (size_t)(p * 32) * K + k0, &Bs[buf][p * 2048 + tid * 8]);
    }
  };

  stage(0, 0);
  __syncthreads();
  int cur = 0;
  for (int k0 = 0; k0 < K; k0 += 64) {
    if (k0 + 64 < K) stage(cur ^ 1, k0 + 64);
    const short* Ab = &As[cur][0];
    const short* Bb = &Bs[cur][0];
#pragma unroll
    for (int kk = 0; kk < 2; ++kk) {
      bf16x8 af[4], bfr[4];
#pragma unroll
      for (int mi = 0; mi < 4; ++mi)
        af[mi] = *(const bf16x8*)(Ab + (wm + mi * 16 + lr) * 64 +
                                  (((kk * 4 + lg) ^ lx) * 8));
#pragma unroll
      for (int ni = 0; ni < 4; ++ni)
        bfr[ni] = *(const bf16x8*)(Bb + (wn + ni * 16 + lr) * 64 +
                                   (((kk * 4 + lg) ^ lx) * 8));
#pragma unroll
      for (int mi = 0; mi < 4; ++mi)
#pragma unroll
        for (int ni = 0; ni < 4; ++ni)
          acc[mi][ni] = __builtin_amdgcn_mfma_f32_16x16x32_bf16(
              af[mi], bfr[ni], acc[mi][ni], 0, 0, 0);
    }
    __syncthreads();
    cur ^= 1;
  }

#pragma unroll
  for (int mi = 0; mi < 4; ++mi) {
    const int row = m0 + wm + mi * 16 + lg * 4;
#pragma unroll
    for (int ni = 0; ni < 4; ++ni) {
      const int col = n0 + wn + ni * 16 + lr;
#pragma unroll
      for (int r = 0; r < 4; ++r)
        C[(size_t)(row + r) * N + col] = f2bf(acc[mi][ni][r]);
    }
  }
}

// ---------------- GEMM 64x128 tile, BK=64 swizzled, bf16 delta out -----------
__global__ __launch_bounds__(256) void gemm_bt64(const short* __restrict__ A,
                                                 const short* __restrict__ Bt,
                                                 short* __restrict__ Cout,
                                                 int M, int N, int K) {
  __shared__ short As[2][64 * 64];
  __shared__ short Bs[2][128 * 64];
  const int tid = threadIdx.x;
  const int gx = gridDim.x;
  const int nwg = gx * gridDim.y;
  int lin = blockIdx.y * gx + blockIdx.x;
  lin = (lin & 7) * (nwg >> 3) + (lin >> 3);
  const int m0 = (lin / gx) * 64, n0 = (lin % gx) * 128;
  const int wave = tid >> 6, lane = tid & 63;
  const int wn = wave * 32;
  const int lr = lane & 15, lg = lane >> 4;
  const int lx = lr & 7;

  f32x4 acc[4][2];
#pragma unroll
  for (int i = 0; i < 4; ++i)
#pragma unroll
    for (int j = 0; j < 2; ++j) acc[i][j] = f32x4{0.f, 0.f, 0.f, 0.f};

  const int sr = tid >> 3;
  const int scs = ((tid & 7) ^ (sr & 7)) * 8;
  const size_t arow = (size_t)(m0 + sr) * K + scs;
  const size_t brow = (size_t)(n0 + sr) * K + scs;

  auto stage = [&](int buf, int k0) {
#pragma unroll
    for (int p = 0; p < 2; ++p)
      gload16(A + arow + (size_t)(p * 32) * K + k0, &As[buf][p * 2048 + tid * 8]);
#pragma unroll
    for (int p = 0; p < 4; ++p)
      gload16(Bt + brow + (size_t)(p * 32) * K + k0, &Bs[buf][p * 2048 + tid * 8]);
  };

  stage(0, 0);
  __syncthreads();
  int cur = 0;
  for (int k0 = 0; k0 < K; k0 += 64) {
    if (k0 + 64 < K) stage(cur ^ 1, k0 + 64);
    const short* Ab = &As[cur][0];
    const short* Bb = &Bs[cur][0];
#pragma unroll
    for (int kk = 0; kk < 2; ++kk) {
      bf16x8 af[4], bfr[2];
#pragma unroll
      for (int mi = 0; mi < 4; ++mi)
        af[mi] = *(const bf16x8*)(Ab + (mi * 16 + lr) * 64 +
                                  (((kk * 4 + lg) ^ lx) * 8));
#pragma unroll
      for (int ni = 0; ni < 2; ++ni)
        bfr[ni] = *(const bf16x8*)(Bb + (wn + ni * 16 + lr) * 64 +
                                   (((kk * 4 + lg) ^ lx) * 8));
#pragma unroll
      for (int mi = 0; mi < 4; ++mi)
#pragma unroll
        for (int ni = 0; ni < 2; ++ni)
          acc[mi][ni] = __builtin_amdgcn_mfma_f32_16x16x32_bf16(
              af[mi], bfr[ni], acc[mi][ni], 0, 0, 0);
    }
    __syncthreads();
    cur ^= 1;
  }

#pragma unroll
  for (int mi = 0; mi < 4; ++mi) {
    const int row = m0 + mi * 16 + lg * 4;
#pragma unroll
    for (int ni = 0; ni < 2; ++ni) {
      const int col = n0 + wn + ni * 16 + lr;
#pragma unroll
      for (int r = 0; r < 4; ++r)
        Cout[(size_t)(row + r) * N + col] = f2bf(acc[mi][ni][r]);
    }
  }
}

// ---------------- per-head V transpose (bf16): (N x HD) -> (HD x N) ----------
__global__ __launch_bounds__(256) void vtrans(const short* __restrict__ in,
                                              short* __restrict__ out,
                                              int ldi, int N) {
  const int bh = blockIdx.z;
  const int b = bh >> 4, h = bh & 15;
  const short* ib = in + (size_t)b * N * ldi + h * HD_;
  short* ob = out + (size_t)bh * HD_ * N;
  __shared__ short t[32][33];
  const int tx = threadIdx.x, ty = threadIdx.y;
  const int n0 = blockIdx.x * 32, d0 = blockIdx.y * 32;
#pragma unroll
  for (int i = 0; i < 4; ++i)
    t[ty + i * 8][tx] = ib[(size_t)(n0 + ty + i * 8) * ldi + d0 + tx];
  __syncthreads();
#pragma unroll
  for (int i = 0; i < 4; ++i)
    ob[(size_t)(d0 + ty + i * 8) * N + n0 + tx] = t[tx][ty + i * 8];
}

// ---------------- flash attention: 128 q-rows/block (8 waves), KBLK=64 -------
// Swapped QK^T (r6-proven per-wave body). One K/V tile serves 128 q-rows:
// staging = 2 gload16/thread/tile, barriers halved per q-row. 2-phase dbuf.
// Causal: grid (32,16), qb remap pairs long+short diagonals; waves skip
// fully-masked tiles (compute-only skip; barriers preserved).
__global__ __launch_bounds__(512) void flash(const short* __restrict__ Q,
                                             const short* __restrict__ Kp,
                                             const short* __restrict__ Vt,
                                             short* __restrict__ O,
                                             int ldq, int ldk, int ldo,
                                             int NK, int causal) {
  const int bh = blockIdx.x;
  int qb = blockIdx.y;
  if (causal) qb = (qb < 8) ? (2 * qb) : (31 - 2 * qb);
  const int b = bh >> 4, h = bh & 15;
  const int q0 = qb * 128;
  const int tid = threadIdx.x, wave = tid >> 6, lane = tid & 63;
  const int lr = lane & 15, lg = lane >> 4;
  const int lx = lr & 7;

  const short* Qb = Q + (size_t)b * ND_ * ldq + h * HD_;
  const short* Kb = Kp + (size_t)b * NK * ldk + h * HD_;
  const short* Vb = Vt + (size_t)bh * HD_ * NK;
  short* Ob = O + (size_t)b * ND_ * ldo + h * HD_;

  __shared__ short Ks[2][64 * 64];
  __shared__ short Vs[2][64 * 64];
  __shared__ short Ps[8][16 * 64];   // per-wave P tile, [q][k] swizzled

  const int qrow = q0 + wave * 16 + lr;
  const bf16x8 qf0 = *(const bf16x8*)(Qb + (size_t)qrow * ldq + lg * 8);
  const bf16x8 qf1 = *(const bf16x8*)(Qb + (size_t)qrow * ldq + 32 + lg * 8);

  const bf16x8 ONES = {0x3F80, 0x3F80, 0x3F80, 0x3F80,
                       0x3F80, 0x3F80, 0x3F80, 0x3F80};  // bf16 1.0 x8

  f32x4 oacc[4];
  f32x4 lacc = f32x4{0.f, 0.f, 0.f, 0.f};
  float m_own = -1e30f;
#pragma unroll
  for (int i = 0; i < 4; ++i) oacc[i] = f32x4{0.f, 0.f, 0.f, 0.f};

  const int sr0 = tid >> 3;                       // 0..63
  const int ssw = ((tid & 7) ^ (sr0 & 7)) * 8;
  const int e0 = tid * 8;                         // 0..4088

  const float SC = 0.18033688011112042f;  // 1/sqrt(64) * log2(e)

  short* Pw = &Ps[wave][0];
  const int pbase = lr * 64 + (lg & 1) * 4;

  auto stage = [&](int buf, int k0) {
    gload16(Kb + (size_t)(k0 + sr0) * ldk + ssw, &Ks[buf][0] + e0);
    gload16(Vb + (size_t)sr0 * NK + k0 + ssw, &Vs[buf][0] + e0);
  };

  const int nkt = causal ? (2 * qb + 2) : (NK / 64);
  stage(0, 0);
  __syncthreads();
  int cur = 0;
  for (int t = 0; t < nkt; ++t) {
    const int k0 = t * 64;
    if (t + 1 < nkt) stage(cur ^ 1, k0 + 64);
    // skip tiles fully above this wave's diagonal (wave-uniform)
    if (!causal || k0 <= q0 + wave * 16 + 15) {
      const short* Ksb = &Ks[cur][0];
      const short* Vsb = &Vs[cur][0];

      f32x4 st[4];
#pragma unroll
      for (int kb = 0; kb < 4; ++kb) {
        const bf16x8 kf0 = *(const bf16x8*)(Ksb + (kb * 16 + lr) * 64 + ((lg ^ lx) * 8));
        const bf16x8 kf1 = *(const bf16x8*)(Ksb + (kb * 16 + lr) * 64 + (((4 + lg) ^ lx) * 8));
        st[kb] = f32x4{0.f, 0.f, 0.f, 0.f};
        st[kb] = __builtin_amdgcn_mfma_f32_16x16x32_bf16(kf0, qf0, st[kb], 0, 0, 0);
        st[kb] = __builtin_amdgcn_mfma_f32_16x16x32_bf16(kf1, qf1, st[kb], 0, 0, 0);
      }
      if (causal && k0 + 63 > q0 + wave * 16) {  // diagonal tile for this wave
#pragma unroll
        for (int kb = 0; kb < 4; ++kb)
#pragma unroll
          for (int r = 0; r < 4; ++r)
            if ((k0 + kb * 16 + lg * 4 + r) > qrow) st[kb][r] = -3.0e38f;
      }

      float rm = st[0][0];
#pragma unroll
      for (int kb = 0; kb < 4; ++kb)
#pragma unroll
        for (int r = 0; r < 4; ++r)
          if (kb || r) rm = fmaxf(rm, st[kb][r]);
      rm = fmaxf(rm, __shfl_xor(rm, 16));
      rm = fmaxf(rm, __shfl_xor(rm, 32));

      if (!__all(rm - m_own <= 44.f)) {
        const float nm = fmaxf(m_own, rm);
        const float fac = EXP2((m_own - nm) * SC);
        m_own = nm;
        const float fr0 = __shfl(fac, (lg << 2) + 0);
        const float fr1 = __shfl(fac, (lg << 2) + 1);
        const float fr2 = __shfl(fac, (lg << 2) + 2);
        const float fr3 = __shfl(fac, (lg << 2) + 3);
#pragma unroll
        for (int db = 0; db < 4; ++db) {
          oacc[db][0] *= fr0; oacc[db][1] *= fr1;
          oacc[db][2] *= fr2; oacc[db][3] *= fr3;
        }
        lacc[0] *= fr0; lacc[1] *= fr1; lacc[2] *= fr2; lacc[3] *= fr3;
      }
      const float nmsc = m_own * SC;
#pragma unroll
      for (int kb = 0; kb < 4; ++kb)
#pragma unroll
        for (int r = 0; r < 4; ++r)
          st[kb][r] = EXP2(fmaf(st[kb][r], SC, -nmsc));

      // P pack via cvt_pk pairs (byte layout identical to scalar-pack path)
#pragma unroll
      for (int kb = 0; kb < 4; ++kb) {
        union { unsigned u[2]; unsigned long long ull; } pk;
        asm("v_cvt_pk_bf16_f32 %0, %1, %2"
            : "=v"(pk.u[0]) : "v"(st[kb][0]), "v"(st[kb][1]));
        asm("v_cvt_pk_bf16_f32 %0, %1, %2"
            : "=v"(pk.u[1]) : "v"(st[kb][2]), "v"(st[kb][3]));
        const int cs = kb * 2 + (lg >> 1);
        *(unsigned long long*)(Pw + pbase + ((cs ^ lx) * 8)) = pk.ull;
      }
      const bf16x8 pf0 = *(const bf16x8*)(Pw + lr * 64 + ((lg ^ lx) * 8));
      const bf16x8 pf1 = *(const bf16x8*)(Pw + lr * 64 + (((4 + lg) ^ lx) * 8));

#pragma unroll
      for (int db = 0; db < 4; ++db) {
        const bf16x8 vf0 = *(const bf16x8*)(Vsb + (db * 16 + lr) * 64 + ((lg ^ lx) * 8));
        const bf16x8 vf1 = *(const bf16x8*)(Vsb + (db * 16 + lr) * 64 + (((4 + lg) ^ lx) * 8));
        oacc[db] = __builtin_amdgcn_mfma_f32_16x16x32_bf16(pf0, vf0, oacc[db], 0, 0, 0);
        oacc[db] = __builtin_amdgcn_mfma_f32_16x16x32_bf16(pf1, vf1, oacc[db], 0, 0, 0);
      }
      lacc = __builtin_amdgcn_mfma_f32_16x16x32_bf16(pf0, ONES, lacc, 0, 0, 0);
      lacc = __builtin_amdgcn_mfma_f32_16x16x32_bf16(pf1, ONES, lacc, 0, 0, 0);
    }
    __syncthreads();
    cur ^= 1;
  }
#pragma unroll
  for (int db = 0; db < 4; ++db)
#pragma unroll
    for (int r = 0; r < 4; ++r) {
      const int q = q0 + wave * 16 + lg * 4 + r;
      Ob[(size_t)q * ldo + db * 16 + lr] = f2bf(oacc[db][r] / lacc[r]);
    }
}

// ---------------------------------------------------------------------------
extern "C" void kernel_launch(void* const* d_in, const int* in_sizes, int n_in,
                              void* d_out, int out_size, void* d_ws, size_t ws_size,
                              hipStream_t stream) {
  const float* x      = (const float*)d_in[0];
  const float* memory = (const float*)d_in[1];
  const float* ln1_g  = (const float*)d_in[2];
  const float* ln1_b  = (const float*)d_in[3];
  const float* Wqkv   = (const float*)d_in[4];
  const float* Wo_sa  = (const float*)d_in[5];
  const float* bo_sa  = (const float*)d_in[6];
  const float* ln2_g  = (const float*)d_in[7];
  const float* ln2_b  = (const float*)d_in[8];
  const float* Wq     = (const float*)d_in[9];
  const float* Wk     = (const float*)d_in[10];
  const float* Wv     = (const float*)d_in[11];
  const float* Wo_ca  = (const float*)d_in[12];
  const float* bo_ca  = (const float*)d_in[13];
  const float* ln3_g  = (const float*)d_in[14];
  const float* ln3_b  = (const float*)d_in[15];
  const float* W1     = (const float*)d_in[16];
  const float* b1     = (const float*)d_in[17];
  const float* W2     = (const float*)d_in[18];
  const float* b2     = (const float*)d_in[19];

  char* ws = (char*)d_ws;
  size_t o = 0;
  auto alloc = [&](size_t bytes) { char* p = ws + o; o += bytes; return p; };
  short* wqkv_t = (short*)alloc((size_t)3072 * 1024 * 2);
  short* wosa_t = (short*)alloc((size_t)1024 * 1024 * 2);
  short* wq_t   = (short*)alloc((size_t)1024 * 1024 * 2);
  short* wk_t   = (short*)alloc((size_t)1024 * 1024 * 2);
  short* wv_t   = (short*)alloc((size_t)1024 * 1024 * 2);
  short* woca_t = (short*)alloc((size_t)1024 * 1024 * 2);
  short* w1_t   = (short*)alloc((size_t)4096 * 1024 * 2);
  short* w2_t   = (short*)alloc((size_t)1024 * 4096 * 2);
  short* hbf    = (short*)alloc((size_t)T_ * 1024 * 2);  // ln-out AND delta buf
  short* bufa   = (short*)alloc((size_t)T_ * 3072 * 2);
  short* vt     = (short*)alloc((size_t)32 * 64 * 2048 * 2);
  short* attn   = (short*)alloc((size_t)T_ * 1024 * 2);
  short* membf  = (short*)alloc((size_t)T_ * 1024 * 2);
  float* x1     = (float*)alloc((size_t)T_ * 1024 * 4);
  float* x2     = (float*)alloc((size_t)T_ * 1024 * 4);
  if (o > ws_size) return;

  short* ffn = bufa;  // spans bufa(24MB)+vt(8MB), both dead by then
  short* qca = bufa;
  short* kca = bufa + (size_t)T_ * 1024;
  short* vca = bufa + (size_t)2 * T_ * 1024;

  const dim3 tb(32, 8);

  // weight transposes (fp32 -> bf16, K x N -> N x K)
  wt_cast<<<dim3(3072 / 32, 1024 / 32), tb, 0, stream>>>(Wqkv, wqkv_t, 1024, 3072);
  wt_cast5<<<dim3(32, 32, 5), tb, 0, stream>>>(Wo_sa, Wq, Wk, Wv, Wo_ca,
                                               wosa_t, wq_t, wk_t, wv_t, woca_t);
  wt_cast<<<dim3(4096 / 32, 1024 / 32), tb, 0, stream>>>(W1, w1_t, 1024, 4096);
  wt_cast<<<dim3(1024 / 32, 4096 / 32), tb, 0, stream>>>(W2, w2_t, 4096, 1024);
  castf2b<<<dim3((T_ * 1024) / (256 * 4)), 256, 0, stream>>>(memory, membf);

  // --- self-attention block ---
  ln_kernel<<<dim3(T_), 256, 0, stream>>>(x, ln1_g, ln1_b, hbf);
  gemm_bt<0><<<dim3(3072 / 128, T_ / 128), 256, 0, stream>>>(
      hbf, wqkv_t, nullptr, bufa, T_, 3072, 1024);
  vtrans<<<dim3(ND_ / 32, HD_ / 32, 32), tb, 0, stream>>>(bufa + 2048, vt, 3072, ND_);
  flash<<<dim3(32, ND_ / 128), 512, 0, stream>>>(
      bufa, bufa + 1024, vt, attn, 3072, 3072, 1024, ND_, 1);
  gemm_bt64<<<dim3(1024 / 128, T_ / 64), 256, 0, stream>>>(
      attn, wosa_t, hbf, T_, 1024, 1024);                       // delta_sa -> hbf
  ln_fused<<<dim3(T_), 256, 0, stream>>>(x, hbf, bo_sa, ln2_g, ln2_b, hbf, x1);

  // --- cross-attention block ---
  gemm_bt3<<<dim3(1024 / 128, T_ / 128, 3), 256, 0, stream>>>(
      hbf, membf, membf, wq_t, wk_t, wv_t, qca, kca, vca, T_, 1024, 1024);
  vtrans<<<dim3(NE_ / 32, HD_ / 32, 32), tb, 0, stream>>>(vca, vt, 1024, NE_);
  flash<<<dim3(32, ND_ / 128), 512, 0, stream>>>(
      qca, kca, vt, attn, 1024, 1024, 1024, NE_, 0);
  gemm_bt64<<<dim3(1024 / 128, T_ / 64), 256, 0, stream>>>(
      attn, woca_t, hbf, T_, 1024, 1024);                       // delta_ca -> hbf
  ln_fused<<<dim3(T_), 256, 0, stream>>>(x1, hbf, bo_ca, ln3_g, ln3_b, hbf, x2);

  // --- FFN block ---
  gemm_bt<2><<<dim3(4096 / 128, T_ / 128), 256, 0, stream>>>(
      hbf, w1_t, b1, ffn, T_, 4096, 1024);
  gemm_bt64<<<dim3(1024 / 128, T_ / 64), 256, 0, stream>>>(
      ffn, w2_t, hbf, T_, 1024, 4096);                          // delta_ffn -> hbf
  addbias<<<dim3((T_ * 1024) / (256 * 4)), 256, 0, stream>>>(
      x2, hbf, b2, (float*)d_out);
}

// Round 11
// 369.320 us; speedup vs baseline: 2.0920x; 1.0251x over previous
//
#include <hip/hip_runtime.h>
#include <hip/hip_bf16.h>
#include <math.h>

#define B_   2
#define ND_  2048
#define NE_  2048
#define D_   1024
#define H_   16
#define HD_  64
#define DFF_ 4096
#define T_   4096   // B_*ND_ tokens

typedef __attribute__((ext_vector_type(8))) short bf16x8;
typedef __attribute__((ext_vector_type(4))) float f32x4;

#if __has_builtin(__builtin_amdgcn_exp2f)
#define EXP2(x) __builtin_amdgcn_exp2f(x)
#else
#define EXP2(x) exp2f(x)
#endif

__device__ __forceinline__ short f2bf(float f) {
  union { float f; unsigned u; } v; v.f = f;
  return (short)((v.u + 0x7FFFu + ((v.u >> 16) & 1u)) >> 16);
}
__device__ __forceinline__ float bf2f(short s) {
  union { unsigned u; float f; } v; v.u = ((unsigned)(unsigned short)s) << 16;
  return v.f;
}

typedef const __attribute__((address_space(1))) void gvoid_t;
typedef __attribute__((address_space(3))) void lvoid_t;

__device__ __forceinline__ void gload16(const void* src, void* dst) {
  __builtin_amdgcn_global_load_lds((gvoid_t*)src, (lvoid_t*)dst, 16, 0, 0);
}

// ---------------- merged weight-prep: all transposes + memory cast -----------
// 1-D grid, job dispatch by block id:
//   [0,3072)      Wqkv  (K=1024,N=3072)  96x32 tiles
//   [3072,7168)   W1    (K=1024,N=4096)  128x32
//   [7168,11264)  W2    (K=4096,N=1024)  32x128
//   [11264,16384) five 1024^2 weights    5 x 32x32
//   [16384,20480) memory fp32->bf16 cast
__global__ __launch_bounds__(256) void prep(
    const float* __restrict__ Wqkv, short* __restrict__ wqkv_t,
    const float* __restrict__ W1, short* __restrict__ w1_t,
    const float* __restrict__ W2, short* __restrict__ w2_t,
    const float* __restrict__ i0, const float* __restrict__ i1,
    const float* __restrict__ i2, const float* __restrict__ i3,
    const float* __restrict__ i4,
    short* __restrict__ o0, short* __restrict__ o1, short* __restrict__ o2,
    short* __restrict__ o3, short* __restrict__ o4,
    const float* __restrict__ mem, short* __restrict__ membf) {
  const int id = blockIdx.x;
  const int tid = threadIdx.x;
  if (id >= 16384) {  // memory cast
    const int i = (id - 16384) * 256 + tid;
    float4 v = ((const float4*)mem)[i];
    short4 o;
    o.x = f2bf(v.x); o.y = f2bf(v.y); o.z = f2bf(v.z); o.w = f2bf(v.w);
    ((short4*)membf)[i] = o;
    return;
  }
  const float* in; short* out; int K, N, bx, by;
  if (id < 3072) {
    in = Wqkv; out = wqkv_t; K = 1024; N = 3072; bx = id % 96; by = id / 96;
  } else if (id < 7168) {
    const int t = id - 3072;
    in = W1; out = w1_t; K = 1024; N = 4096; bx = t % 128; by = t / 128;
  } else if (id < 11264) {
    const int t = id - 7168;
    in = W2; out = w2_t; K = 4096; N = 1024; bx = t % 32; by = t / 32;
  } else {
    const int t = id - 11264;
    const int z = t >> 10, r = t & 1023;
    bx = r % 32; by = r / 32; K = 1024; N = 1024;
    in  = z == 0 ? i0 : z == 1 ? i1 : z == 2 ? i2 : z == 3 ? i3 : i4;
    out = z == 0 ? o0 : z == 1 ? o1 : z == 2 ? o2 : z == 3 ? o3 : o4;
  }
  __shared__ float tb[32][33];
  const int tx = tid & 31, ty = tid >> 5;
  const int n0 = bx * 32, k0 = by * 32;
#pragma unroll
  for (int i = 0; i < 4; ++i)
    tb[ty + i * 8][tx] = in[(size_t)(k0 + ty + i * 8) * N + n0 + tx];
  __syncthreads();
#pragma unroll
  for (int i = 0; i < 4; ++i)
    out[(size_t)(n0 + ty + i * 8) * K + k0 + tx] = f2bf(tb[tx][ty + i * 8]);
}

// ---------------- LayerNorm (row of 1024) fp32 -> bf16 -----------------------
__global__ __launch_bounds__(256) void ln_kernel(const float* __restrict__ x,
                                                 const float* __restrict__ g,
                                                 const float* __restrict__ b,
                                                 short* __restrict__ out) {
  const int row = blockIdx.x;
  const int tid = threadIdx.x;
  const float* xr = x + (size_t)row * D_;
  float4 v = reinterpret_cast<const float4*>(xr)[tid];
  float s  = v.x + v.y + v.z + v.w;
  float s2 = v.x * v.x + v.y * v.y + v.z * v.z + v.w * v.w;
#pragma unroll
  for (int m = 1; m < 64; m <<= 1) {
    s  += __shfl_xor(s, m);
    s2 += __shfl_xor(s2, m);
  }
  __shared__ float ss[4], ss2[4];
  const int w = tid >> 6;
  if ((tid & 63) == 0) { ss[w] = s; ss2[w] = s2; }
  __syncthreads();
  s  = ss[0] + ss[1] + ss[2] + ss[3];
  s2 = ss2[0] + ss2[1] + ss2[2] + ss2[3];
  const float mu   = s * (1.0f / D_);
  const float var  = s2 * (1.0f / D_) - mu * mu;
  const float rstd = rsqrtf(var + 1e-5f);
  float4 gv = reinterpret_cast<const float4*>(g)[tid];
  float4 bv = reinterpret_cast<const float4*>(b)[tid];
  short4 o;
  o.x = f2bf((v.x - mu) * rstd * gv.x + bv.x);
  o.y = f2bf((v.y - mu) * rstd * gv.y + bv.y);
  o.z = f2bf((v.z - mu) * rstd * gv.z + bv.z);
  o.w = f2bf((v.w - mu) * rstd * gv.w + bv.w);
  reinterpret_cast<short4*>(out + (size_t)row * D_)[tid] = o;
}

// ---------------- fused residual + bias + LayerNorm --------------------------
__global__ __launch_bounds__(256) void ln_fused(const float* __restrict__ xprev,
                                                const short* delta,
                                                const float* __restrict__ pbias,
                                                const float* __restrict__ g,
                                                const float* __restrict__ b,
                                                short* out_ln,
                                                float* __restrict__ out_x) {
  const int row = blockIdx.x;
  const int tid = threadIdx.x;
  float4 v = reinterpret_cast<const float4*>(xprev + (size_t)row * D_)[tid];
  short4 dv = reinterpret_cast<const short4*>(delta + (size_t)row * D_)[tid];
  float4 pb = reinterpret_cast<const float4*>(pbias)[tid];
  v.x += bf2f(dv.x) + pb.x;
  v.y += bf2f(dv.y) + pb.y;
  v.z += bf2f(dv.z) + pb.z;
  v.w += bf2f(dv.w) + pb.w;
  float s  = v.x + v.y + v.z + v.w;
  float s2 = v.x * v.x + v.y * v.y + v.z * v.z + v.w * v.w;
#pragma unroll
  for (int m = 1; m < 64; m <<= 1) {
    s  += __shfl_xor(s, m);
    s2 += __shfl_xor(s2, m);
  }
  __shared__ float ss[4], ss2[4];
  const int w = tid >> 6;
  if ((tid & 63) == 0) { ss[w] = s; ss2[w] = s2; }
  __syncthreads();
  s  = ss[0] + ss[1] + ss[2] + ss[3];
  s2 = ss2[0] + ss2[1] + ss2[2] + ss2[3];
  const float mu   = s * (1.0f / D_);
  const float var  = s2 * (1.0f / D_) - mu * mu;
  const float rstd = rsqrtf(var + 1e-5f);
  reinterpret_cast<float4*>(out_x + (size_t)row * D_)[tid] = v;
  float4 gv = reinterpret_cast<const float4*>(g)[tid];
  float4 bv = reinterpret_cast<const float4*>(b)[tid];
  short4 o;
  o.x = f2bf((v.x - mu) * rstd * gv.x + bv.x);
  o.y = f2bf((v.y - mu) * rstd * gv.y + bv.y);
  o.z = f2bf((v.z - mu) * rstd * gv.z + bv.z);
  o.w = f2bf((v.w - mu) * rstd * gv.w + bv.w);
  reinterpret_cast<short4*>(out_ln + (size_t)row * D_)[tid] = o;
}

// ---------------- final residual + bias add: out = x + delta + bias ----------
__global__ __launch_bounds__(256) void addbias(const float* __restrict__ x,
                                               const short* __restrict__ delta,
                                               const float* __restrict__ bias,
                                               float* __restrict__ out) {
  const int i = blockIdx.x * 256 + threadIdx.x;
  float4 v = ((const float4*)x)[i];
  short4 dv = ((const short4*)delta)[i];
  const int col = (i * 4) & (D_ - 1);
  float4 pb = *(const float4*)(bias + col);
  v.x += bf2f(dv.x) + pb.x;
  v.y += bf2f(dv.y) + pb.y;
  v.z += bf2f(dv.z) + pb.z;
  v.w += bf2f(dv.w) + pb.w;
  ((float4*)out)[i] = v;
}

// ---------------- GEMM 128x128, BK=64, XOR-swizzled LDS, 2-phase dbuf --------
template <int MODE>
__global__ __launch_bounds__(256) void gemm_bt(const short* __restrict__ A,
                                               const short* __restrict__ Bt,
                                               const float* __restrict__ bias,
                                               void* __restrict__ Cout,
                                               int M, int N, int K) {
  __shared__ short As[2][128 * 64];
  __shared__ short Bs[2][128 * 64];
  const int tid = threadIdx.x;
  const int gx = gridDim.x;
  const int nwg = gx * gridDim.y;
  int lin = blockIdx.y * gx + blockIdx.x;
  lin = (lin & 7) * (nwg >> 3) + (lin >> 3);
  const int m0 = (lin / gx) * 128, n0 = (lin % gx) * 128;
  const int wave = tid >> 6, lane = tid & 63;
  const int wm = (wave >> 1) * 64, wn = (wave & 1) * 64;
  const int lr = lane & 15, lg = lane >> 4;
  const int lx = lr & 7;

  f32x4 acc[4][4];
#pragma unroll
  for (int i = 0; i < 4; ++i)
#pragma unroll
    for (int j = 0; j < 4; ++j) acc[i][j] = f32x4{0.f, 0.f, 0.f, 0.f};

  const int sr = tid >> 3;
  const int scs = ((tid & 7) ^ (sr & 7)) * 8;
  const size_t arow = (size_t)(m0 + sr) * K + scs;
  const size_t brow = (size_t)(n0 + sr) * K + scs;

  auto stage = [&](int buf, int k0) {
#pragma unroll
    for (int p = 0; p < 4; ++p) {
      gload16(A + arow + (size_t)(p * 32) * K + k0, &As[buf][p * 2048 + tid * 8]);
      gload16(Bt + brow + (size_t)(p * 32) * K + k0, &Bs[buf][p * 2048 + tid * 8]);
    }
  };

  stage(0, 0);
  __syncthreads();
  int cur = 0;
  for (int k0 = 0; k0 < K; k0 += 64) {
    if (k0 + 64 < K) stage(cur ^ 1, k0 + 64);
    const short* Ab = &As[cur][0];
    const short* Bb = &Bs[cur][0];
#pragma unroll
    for (int kk = 0; kk < 2; ++kk) {
      bf16x8 af[4], bfr[4];
#pragma unroll
      for (int mi = 0; mi < 4; ++mi)
        af[mi] = *(const bf16x8*)(Ab + (wm + mi * 16 + lr) * 64 +
                                  (((kk * 4 + lg) ^ lx) * 8));
#pragma unroll
      for (int ni = 0; ni < 4; ++ni)
        bfr[ni] = *(const bf16x8*)(Bb + (wn + ni * 16 + lr) * 64 +
                                   (((kk * 4 + lg) ^ lx) * 8));
#pragma unroll
      for (int mi = 0; mi < 4; ++mi)
#pragma unroll
        for (int ni = 0; ni < 4; ++ni)
          acc[mi][ni] = __builtin_amdgcn_mfma_f32_16x16x32_bf16(
              af[mi], bfr[ni], acc[mi][ni], 0, 0, 0);
    }
    __syncthreads();
    cur ^= 1;
  }

#pragma unroll
  for (int mi = 0; mi < 4; ++mi) {
    const int row = m0 + wm + mi * 16 + lg * 4;
#pragma unroll
    for (int ni = 0; ni < 4; ++ni) {
      const int col = n0 + wn + ni * 16 + lr;
#pragma unroll
      for (int r = 0; r < 4; ++r) {
        const size_t idx = (size_t)(row + r) * N + col;
        const float v = acc[mi][ni][r];
        if (MODE == 0) {
          ((short*)Cout)[idx] = f2bf(v);
        } else {
          const float tt = v + bias[col];
          const float yy = fmaf(tt * tt * tt, 0.044715f, tt);
          const float e = EXP2(yy * -2.3022343813918633f);
          ((short*)Cout)[idx] = f2bf(tt / (1.0f + e));
        }
      }
    }
  }
}

// ---------------- batched-3 GEMM 128x128, BK=64 swizzled (cross-attn q/k/v) --
__global__ __launch_bounds__(256) void gemm_bt3(const short* __restrict__ A0,
                                                const short* __restrict__ A1,
                                                const short* __restrict__ A2,
                                                const short* __restrict__ B0,
                                                const short* __restrict__ B1,
                                                const short* __restrict__ B2,
                                                short* __restrict__ C0,
                                                short* __restrict__ C1,
                                                short* __restrict__ C2,
                                                int M, int N, int K) {
  const int z = blockIdx.z;
  const short* A  = z == 0 ? A0 : (z == 1 ? A1 : A2);
  const short* Bt = z == 0 ? B0 : (z == 1 ? B1 : B2);
  short* C        = z == 0 ? C0 : (z == 1 ? C1 : C2);

  __shared__ short As[2][128 * 64];
  __shared__ short Bs[2][128 * 64];
  const int tid = threadIdx.x;
  const int gx = gridDim.x;
  const int nwg = gx * gridDim.y;
  int lin = blockIdx.y * gx + blockIdx.x;
  lin = (lin & 7) * (nwg >> 3) + (lin >> 3);
  const int m0 = (lin / gx) * 128, n0 = (lin % gx) * 128;
  const int wave = tid >> 6, lane = tid & 63;
  const int wm = (wave >> 1) * 64, wn = (wave & 1) * 64;
  const int lr = lane & 15, lg = lane >> 4;
  const int lx = lr & 7;

  f32x4 acc[4][4];
#pragma unroll
  for (int i = 0; i < 4; ++i)
#pragma unroll
    for (int j = 0; j < 4; ++j) acc[i][j] = f32x4{0.f, 0.f, 0.f, 0.f};

  const int sr = tid >> 3;
  const int scs = ((tid & 7) ^ (sr & 7)) * 8;
  const size_t arow = (size_t)(m0 + sr) * K + scs;
  const size_t brow = (size_t)(n0 + sr) * K + scs;

  auto stage = [&](int buf, int k0) {
#pragma unroll
    for (int p = 0; p < 4; ++p) {
      gload16(A + arow + (size_t)(p * 32) * K + k0, &As[buf][p * 2048 + tid * 8]);
      gload16(Bt + brow + (size_t)(p * 32) * K + k0, &Bs[buf][p * 2048 + tid * 8]);
    }
  };

  stage(0, 0);
  __syncthreads();
  int cur = 0;
  for (int k0 = 0; k0 < K; k0 += 64) {
    if (k0 + 64 < K) stage(cur ^ 1, k0 + 64);
    const short* Ab = &As[cur][0];
    const short* Bb = &Bs[cur][0];
#pragma unroll
    for (int kk = 0; kk < 2; ++kk) {
      bf16x8 af[4], bfr[4];
#pragma unroll
      for (int mi = 0; mi < 4; ++mi)
        af[mi] = *(const bf16x8*)(Ab + (wm + mi * 16 + lr) * 64 +
                                  (((kk * 4 + lg) ^ lx) * 8));
#pragma unroll
      for (int ni = 0; ni < 4; ++ni)
        bfr[ni] = *(const bf16x8*)(Bb + (wn + ni * 16 + lr) * 64 +
                                   (((kk * 4 + lg) ^ lx) * 8));
#pragma unroll
      for (int mi = 0; mi < 4; ++mi)
#pragma unroll
        for (int ni = 0; ni < 4; ++ni)
          acc[mi][ni] = __builtin_amdgcn_mfma_f32_16x16x32_bf16(
              af[mi], bfr[ni], acc[mi][ni], 0, 0, 0);
    }
    __syncthreads();
    cur ^= 1;
  }

#pragma unroll
  for (int mi = 0; mi < 4; ++mi) {
    const int row = m0 + wm + mi * 16 + lg * 4;
#pragma unroll
    for (int ni = 0; ni < 4; ++ni) {
      const int col = n0 + wn + ni * 16 + lr;
#pragma unroll
      for (int r = 0; r < 4; ++r)
        C[(size_t)(row + r) * N + col] = f2bf(acc[mi][ni][r]);
    }
  }
}

// ---------------- GEMM 64x128 tile, BK=64 swizzled, bf16 delta out -----------
__global__ __launch_bounds__(256) void gemm_bt64(const short* __restrict__ A,
                                                 const short* __restrict__ Bt,
                                                 short* __restrict__ Cout,
                                                 int M, int N, int K) {
  __shared__ short As[2][64 * 64];
  __shared__ short Bs[2][128 * 64];
  const int tid = threadIdx.x;
  const int gx = gridDim.x;
  const int nwg = gx * gridDim.y;
  int lin = blockIdx.y * gx + blockIdx.x;
  lin = (lin & 7) * (nwg >> 3) + (lin >> 3);
  const int m0 = (lin / gx) * 64, n0 = (lin % gx) * 128;
  const int wave = tid >> 6, lane = tid & 63;
  const int wn = wave * 32;
  const int lr = lane & 15, lg = lane >> 4;
  const int lx = lr & 7;

  f32x4 acc[4][2];
#pragma unroll
  for (int i = 0; i < 4; ++i)
#pragma unroll
    for (int j = 0; j < 2; ++j) acc[i][j] = f32x4{0.f, 0.f, 0.f, 0.f};

  const int sr = tid >> 3;
  const int scs = ((tid & 7) ^ (sr & 7)) * 8;
  const size_t arow = (size_t)(m0 + sr) * K + scs;
  const size_t brow = (size_t)(n0 + sr) * K + scs;

  auto stage = [&](int buf, int k0) {
#pragma unroll
    for (int p = 0; p < 2; ++p)
      gload16(A + arow + (size_t)(p * 32) * K + k0, &As[buf][p * 2048 + tid * 8]);
#pragma unroll
    for (int p = 0; p < 4; ++p)
      gload16(Bt + brow + (size_t)(p * 32) * K + k0, &Bs[buf][p * 2048 + tid * 8]);
  };

  stage(0, 0);
  __syncthreads();
  int cur = 0;
  for (int k0 = 0; k0 < K; k0 += 64) {
    if (k0 + 64 < K) stage(cur ^ 1, k0 + 64);
    const short* Ab = &As[cur][0];
    const short* Bb = &Bs[cur][0];
#pragma unroll
    for (int kk = 0; kk < 2; ++kk) {
      bf16x8 af[4], bfr[2];
#pragma unroll
      for (int mi = 0; mi < 4; ++mi)
        af[mi] = *(const bf16x8*)(Ab + (mi * 16 + lr) * 64 +
                                  (((kk * 4 + lg) ^ lx) * 8));
#pragma unroll
      for (int ni = 0; ni < 2; ++ni)
        bfr[ni] = *(const bf16x8*)(Bb + (wn + ni * 16 + lr) * 64 +
                                   (((kk * 4 + lg) ^ lx) * 8));
#pragma unroll
      for (int mi = 0; mi < 4; ++mi)
#pragma unroll
        for (int ni = 0; ni < 2; ++ni)
          acc[mi][ni] = __builtin_amdgcn_mfma_f32_16x16x32_bf16(
              af[mi], bfr[ni], acc[mi][ni], 0, 0, 0);
    }
    __syncthreads();
    cur ^= 1;
  }

#pragma unroll
  for (int mi = 0; mi < 4; ++mi) {
    const int row = m0 + mi * 16 + lg * 4;
#pragma unroll
    for (int ni = 0; ni < 2; ++ni) {
      const int col = n0 + wn + ni * 16 + lr;
#pragma unroll
      for (int r = 0; r < 4; ++r)
        Cout[(size_t)(row + r) * N + col] = f2bf(acc[mi][ni][r]);
    }
  }
}

// ---------------- per-head V transpose (bf16): (N x HD) -> (HD x N) ----------
__global__ __launch_bounds__(256) void vtrans(const short* __restrict__ in,
                                              short* __restrict__ out,
                                              int ldi, int N) {
  const int bh = blockIdx.z;
  const int b = bh >> 4, h = bh & 15;
  const short* ib = in + (size_t)b * N * ldi + h * HD_;
  short* ob = out + (size_t)bh * HD_ * N;
  __shared__ short t[32][33];
  const int tx = threadIdx.x, ty = threadIdx.y;
  const int n0 = blockIdx.x * 32, d0 = blockIdx.y * 32;
#pragma unroll
  for (int i = 0; i < 4; ++i)
    t[ty + i * 8][tx] = ib[(size_t)(n0 + ty + i * 8) * ldi + d0 + tx];
  __syncthreads();
#pragma unroll
  for (int i = 0; i < 4; ++i)
    ob[(size_t)(d0 + ty + i * 8) * N + n0 + tx] = t[tx][ty + i * 8];
}

// ---------------- flash attention: 128 q-rows/block (8 waves), KBLK=64 -------
// r10 structure + T5 setprio around MFMA clusters + T17 v_max3 row-max tree.
__global__ __launch_bounds__(512) void flash(const short* __restrict__ Q,
                                             const short* __restrict__ Kp,
                                             const short* __restrict__ Vt,
                                             short* __restrict__ O,
                                             int ldq, int ldk, int ldo,
                                             int NK, int causal) {
  const int bh = blockIdx.x;
  int qb = blockIdx.y;
  if (causal) qb = (qb < 8) ? (2 * qb) : (31 - 2 * qb);
  const int b = bh >> 4, h = bh & 15;
  const int q0 = qb * 128;
  const int tid = threadIdx.x, wave = tid >> 6, lane = tid & 63;
  const int lr = lane & 15, lg = lane >> 4;
  const int lx = lr & 7;

  const short* Qb = Q + (size_t)b * ND_ * ldq + h * HD_;
  const short* Kb = Kp + (size_t)b * NK * ldk + h * HD_;
  const short* Vb = Vt + (size_t)bh * HD_ * NK;
  short* Ob = O + (size_t)b * ND_ * ldo + h * HD_;

  __shared__ short Ks[2][64 * 64];
  __shared__ short Vs[2][64 * 64];
  __shared__ short Ps[8][16 * 64];

  const int qrow = q0 + wave * 16 + lr;
  const bf16x8 qf0 = *(const bf16x8*)(Qb + (size_t)qrow * ldq + lg * 8);
  const bf16x8 qf1 = *(const bf16x8*)(Qb + (size_t)qrow * ldq + 32 + lg * 8);

  const bf16x8 ONES = {0x3F80, 0x3F80, 0x3F80, 0x3F80,
                       0x3F80, 0x3F80, 0x3F80, 0x3F80};

  f32x4 oacc[4];
  f32x4 lacc = f32x4{0.f, 0.f, 0.f, 0.f};
  float m_own = -1e30f;
#pragma unroll
  for (int i = 0; i < 4; ++i) oacc[i] = f32x4{0.f, 0.f, 0.f, 0.f};

  const int sr0 = tid >> 3;
  const int ssw = ((tid & 7) ^ (sr0 & 7)) * 8;
  const int e0 = tid * 8;

  const float SC = 0.18033688011112042f;  // 1/sqrt(64) * log2(e)

  short* Pw = &Ps[wave][0];
  const int pbase = lr * 64 + (lg & 1) * 4;

  auto stage = [&](int buf, int k0) {
    gload16(Kb + (size_t)(k0 + sr0) * ldk + ssw, &Ks[buf][0] + e0);
    gload16(Vb + (size_t)sr0 * NK + k0 + ssw, &Vs[buf][0] + e0);
  };

  const int nkt = causal ? (2 * qb + 2) : (NK / 64);
  stage(0, 0);
  __syncthreads();
  int cur = 0;
  for (int t = 0; t < nkt; ++t) {
    const int k0 = t * 64;
    if (t + 1 < nkt) stage(cur ^ 1, k0 + 64);
    if (!causal || k0 <= q0 + wave * 16 + 15) {
      const short* Ksb = &Ks[cur][0];
      const short* Vsb = &Vs[cur][0];

      f32x4 st[4];
      __builtin_amdgcn_s_setprio(1);
#pragma unroll
      for (int kb = 0; kb < 4; ++kb) {
        const bf16x8 kf0 = *(const bf16x8*)(Ksb + (kb * 16 + lr) * 64 + ((lg ^ lx) * 8));
        const bf16x8 kf1 = *(const bf16x8*)(Ksb + (kb * 16 + lr) * 64 + (((4 + lg) ^ lx) * 8));
        st[kb] = f32x4{0.f, 0.f, 0.f, 0.f};
        st[kb] = __builtin_amdgcn_mfma_f32_16x16x32_bf16(kf0, qf0, st[kb], 0, 0, 0);
        st[kb] = __builtin_amdgcn_mfma_f32_16x16x32_bf16(kf1, qf1, st[kb], 0, 0, 0);
      }
      __builtin_amdgcn_s_setprio(0);
      if (causal && k0 + 63 > q0 + wave * 16) {
#pragma unroll
        for (int kb = 0; kb < 4; ++kb)
#pragma unroll
          for (int r = 0; r < 4; ++r)
            if ((k0 + kb * 16 + lg * 4 + r) > qrow) st[kb][r] = -3.0e38f;
      }

      // row max: v_max3 tree (8 ops, depth 8) + 2 cross-lane reduces
      float rm = fmaxf(st[0][0], st[0][1]);
      asm("v_max3_f32 %0, %1, %2, %3" : "=v"(rm) : "v"(rm), "v"(st[0][2]), "v"(st[0][3]));
      asm("v_max3_f32 %0, %1, %2, %3" : "=v"(rm) : "v"(rm), "v"(st[1][0]), "v"(st[1][1]));
      asm("v_max3_f32 %0, %1, %2, %3" : "=v"(rm) : "v"(rm), "v"(st[1][2]), "v"(st[1][3]));
      asm("v_max3_f32 %0, %1, %2, %3" : "=v"(rm) : "v"(rm), "v"(st[2][0]), "v"(st[2][1]));
      asm("v_max3_f32 %0, %1, %2, %3" : "=v"(rm) : "v"(rm), "v"(st[2][2]), "v"(st[2][3]));
      asm("v_max3_f32 %0, %1, %2, %3" : "=v"(rm) : "v"(rm), "v"(st[3][0]), "v"(st[3][1]));
      asm("v_max3_f32 %0, %1, %2, %3" : "=v"(rm) : "v"(rm), "v"(st[3][2]), "v"(st[3][3]));
      rm = fmaxf(rm, __shfl_xor(rm, 16));
      rm = fmaxf(rm, __shfl_xor(rm, 32));

      if (!__all(rm - m_own <= 44.f)) {
        const float nm = fmaxf(m_own, rm);
        const float fac = EXP2((m_own - nm) * SC);
        m_own = nm;
        const float fr0 = __shfl(fac, (lg << 2) + 0);
        const float fr1 = __shfl(fac, (lg << 2) + 1);
        const float fr2 = __shfl(fac, (lg << 2) + 2);
        const float fr3 = __shfl(fac, (lg << 2) + 3);
#pragma unroll
        for (int db = 0; db < 4; ++db) {
          oacc[db][0] *= fr0; oacc[db][1] *= fr1;
          oacc[db][2] *= fr2; oacc[db][3] *= fr3;
        }
        lacc[0] *= fr0; lacc[1] *= fr1; lacc[2] *= fr2; lacc[3] *= fr3;
      }
      const float nmsc = m_own * SC;
#pragma unroll
      for (int kb = 0; kb < 4; ++kb)
#pragma unroll
        for (int r = 0; r < 4; ++r)
          st[kb][r] = EXP2(fmaf(st[kb][r], SC, -nmsc));

#pragma unroll
      for (int kb = 0; kb < 4; ++kb) {
        union { unsigned u[2]; unsigned long long ull; } pk;
        asm("v_cvt_pk_bf16_f32 %0, %1, %2"
            : "=v"(pk.u[0]) : "v"(st[kb][0]), "v"(st[kb][1]));
        asm("v_cvt_pk_bf16_f32 %0, %1, %2"
            : "=v"(pk.u[1]) : "v"(st[kb][2]), "v"(st[kb][3]));
        const int cs = kb * 2 + (lg >> 1);
        *(unsigned long long*)(Pw + pbase + ((cs ^ lx) * 8)) = pk.ull;
      }
      const bf16x8 pf0 = *(const bf16x8*)(Pw + lr * 64 + ((lg ^ lx) * 8));
      const bf16x8 pf1 = *(const bf16x8*)(Pw + lr * 64 + (((4 + lg) ^ lx) * 8));

      __builtin_amdgcn_s_setprio(1);
#pragma unroll
      for (int db = 0; db < 4; ++db) {
        const bf16x8 vf0 = *(const bf16x8*)(Vsb + (db * 16 + lr) * 64 + ((lg ^ lx) * 8));
        const bf16x8 vf1 = *(const bf16x8*)(Vsb + (db * 16 + lr) * 64 + (((4 + lg) ^ lx) * 8));
        oacc[db] = __builtin_amdgcn_mfma_f32_16x16x32_bf16(pf0, vf0, oacc[db], 0, 0, 0);
        oacc[db] = __builtin_amdgcn_mfma_f32_16x16x32_bf16(pf1, vf1, oacc[db], 0, 0, 0);
      }
      lacc = __builtin_amdgcn_mfma_f32_16x16x32_bf16(pf0, ONES, lacc, 0, 0, 0);
      lacc = __builtin_amdgcn_mfma_f32_16x16x32_bf16(pf1, ONES, lacc, 0, 0, 0);
      __builtin_amdgcn_s_setprio(0);
    }
    __syncthreads();
    cur ^= 1;
  }
#pragma unroll
  for (int db = 0; db < 4; ++db)
#pragma unroll
    for (int r = 0; r < 4; ++r) {
      const int q = q0 + wave * 16 + lg * 4 + r;
      Ob[(size_t)q * ldo + db * 16 + lr] = f2bf(oacc[db][r] / lacc[r]);
    }
}

// ---------------------------------------------------------------------------
extern "C" void kernel_launch(void* const* d_in, const int* in_sizes, int n_in,
                              void* d_out, int out_size, void* d_ws, size_t ws_size,
                              hipStream_t stream) {
  const float* x      = (const float*)d_in[0];
  const float* memory = (const float*)d_in[1];
  const float* ln1_g  = (const float*)d_in[2];
  const float* ln1_b  = (const float*)d_in[3];
  const float* Wqkv   = (const float*)d_in[4];
  const float* Wo_sa  = (const float*)d_in[5];
  const float* bo_sa  = (const float*)d_in[6];
  const float* ln2_g  = (const float*)d_in[7];
  const float* ln2_b  = (const float*)d_in[8];
  const float* Wq     = (const float*)d_in[9];
  const float* Wk     = (const float*)d_in[10];
  const float* Wv     = (const float*)d_in[11];
  const float* Wo_ca  = (const float*)d_in[12];
  const float* bo_ca  = (const float*)d_in[13];
  const float* ln3_g  = (const float*)d_in[14];
  const float* ln3_b  = (const float*)d_in[15];
  const float* W1     = (const float*)d_in[16];
  const float* b1     = (const float*)d_in[17];
  const float* W2     = (const float*)d_in[18];
  const float* b2     = (const float*)d_in[19];

  char* ws = (char*)d_ws;
  size_t o = 0;
  auto alloc = [&](size_t bytes) { char* p = ws + o; o += bytes; return p; };
  short* wqkv_t = (short*)alloc((size_t)3072 * 1024 * 2);
  short* wosa_t = (short*)alloc((size_t)1024 * 1024 * 2);
  short* wq_t   = (short*)alloc((size_t)1024 * 1024 * 2);
  short* wk_t   = (short*)alloc((size_t)1024 * 1024 * 2);
  short* wv_t   = (short*)alloc((size_t)1024 * 1024 * 2);
  short* woca_t = (short*)alloc((size_t)1024 * 1024 * 2);
  short* w1_t   = (short*)alloc((size_t)4096 * 1024 * 2);
  short* w2_t   = (short*)alloc((size_t)1024 * 4096 * 2);
  short* hbf    = (short*)alloc((size_t)T_ * 1024 * 2);  // ln-out AND delta buf
  short* bufa   = (short*)alloc((size_t)T_ * 3072 * 2);
  short* vt     = (short*)alloc((size_t)32 * 64 * 2048 * 2);
  short* attn   = (short*)alloc((size_t)T_ * 1024 * 2);
  short* membf  = (short*)alloc((size_t)T_ * 1024 * 2);
  float* x1     = (float*)alloc((size_t)T_ * 1024 * 4);
  float* x2     = (float*)alloc((size_t)T_ * 1024 * 4);
  if (o > ws_size) return;

  short* ffn = bufa;  // spans bufa(24MB)+vt(8MB), both dead by then
  short* qca = bufa;
  short* kca = bufa + (size_t)T_ * 1024;
  short* vca = bufa + (size_t)2 * T_ * 1024;

  const dim3 tb(32, 8);

  // merged weight prep (all transposes + memory cast) — one launch
  prep<<<dim3(20480), 256, 0, stream>>>(Wqkv, wqkv_t, W1, w1_t, W2, w2_t,
                                        Wo_sa, Wq, Wk, Wv, Wo_ca,
                                        wosa_t, wq_t, wk_t, wv_t, woca_t,
                                        memory, membf);

  // --- self-attention block ---
  ln_kernel<<<dim3(T_), 256, 0, stream>>>(x, ln1_g, ln1_b, hbf);
  gemm_bt<0><<<dim3(3072 / 128, T_ / 128), 256, 0, stream>>>(
      hbf, wqkv_t, nullptr, bufa, T_, 3072, 1024);
  vtrans<<<dim3(ND_ / 32, HD_ / 32, 32), tb, 0, stream>>>(bufa + 2048, vt, 3072, ND_);
  flash<<<dim3(32, ND_ / 128), 512, 0, stream>>>(
      bufa, bufa + 1024, vt, attn, 3072, 3072, 1024, ND_, 1);
  gemm_bt64<<<dim3(1024 / 128, T_ / 64), 256, 0, stream>>>(
      attn, wosa_t, hbf, T_, 1024, 1024);                       // delta_sa -> hbf
  ln_fused<<<dim3(T_), 256, 0, stream>>>(x, hbf, bo_sa, ln2_g, ln2_b, hbf, x1);

  // --- cross-attention block ---
  gemm_bt3<<<dim3(1024 / 128, T_ / 128, 3), 256, 0, stream>>>(
      hbf, membf, membf, wq_t, wk_t, wv_t, qca, kca, vca, T_, 1024, 1024);
  vtrans<<<dim3(NE_ / 32, HD_ / 32, 32), tb, 0, stream>>>(vca, vt, 1024, NE_);
  flash<<<dim3(32, ND_ / 128), 512, 0, stream>>>(
      qca, kca, vt, attn, 1024, 1024, 1024, NE_, 0);
  gemm_bt64<<<dim3(1024 / 128, T_ / 64), 256, 0, stream>>>(
      attn, woca_t, hbf, T_, 1024, 1024);                       // delta_ca -> hbf
  ln_fused<<<dim3(T_), 256, 0, stream>>>(x1, hbf, bo_ca, ln3_g, ln3_b, hbf, x2);

  // --- FFN block ---
  gemm_bt<2><<<dim3(4096 / 128, T_ / 128), 256, 0, stream>>>(
      hbf, w1_t, b1, ffn, T_, 4096, 1024);
  gemm_bt64<<<dim3(1024 / 128, T_ / 64), 256, 0, stream>>>(
      ffn, w2_t, hbf, T_, 1024, 4096);                          // delta_ffn -> hbf
  addbias<<<dim3((T_ * 1024) / (256 * 4)), 256, 0, stream>>>(
      x2, hbf, b2, (float*)d_out);
}